// Round 1
// 471.714 us; speedup vs baseline: 1.0368x; 1.0368x over previous
//
#include <hip/hip_runtime.h>
#include <cstdint>
#include <cstddef>

#pragma clang fp contract(off)

#define BATCH    8
#define NANCH    261888
#define PRE_NMS  6000
#define PROP     1000
#define SORTN    8192
#define NSLOT    6144          /* 6 * 1024 */
#define MROW     96            /* u64 words per suppression row (94 used + 2 pad) */
#define NW       94            /* suppression words per batch (6000/64 rounded up) */
#define NPAIR    130944        /* NANCH / 2 */
#define CBLK     32            /* blocks per batch for hist/compact */
#define CPAIR    4092          /* NPAIR / CBLK */
#define KCAP     1024          /* compact LDS staging capacity */
#define SCORE_THRES_BITS 0x3F000000u   /* bits of 0.5f */
#define EPS_F    1e-8f
/* midpoint between pred(0.7f) and 0.7f = 23488101 * 2^-25, exact in double.
   RN(inter/denom) >= 0.7f  <=>  inter > M_D * denom  (exact: 25b x 24b product;
   tie rounds to even = pred(0.7f), so strict > is correct). */
#define M_D      0.6999999582767486572265625

typedef unsigned long long ull;
typedef unsigned int u32;

// ---------------------------------------------------------------------------
// Kernel A (fused hist + findT): fine histogram of scores >= 0.5 into 129
// bins; the LAST block per batch (done-counter) computes the coarse threshold.
// grid (32, BATCH) x 256.
// ---------------------------------------------------------------------------
__global__ __launch_bounds__(256)
void hist_kernel(const float* __restrict__ rpn_probs, u32* __restrict__ ghist,
                 u32* __restrict__ done, u32* __restrict__ Tc)
{
    __shared__ u32 h[129];
    __shared__ u32 s_old;
    const int t = threadIdx.x;
    const int b = blockIdx.y;
    if (t < 129) h[t] = 0u;
    __syncthreads();

    const float4* p4 = reinterpret_cast<const float4*>(rpn_probs + (size_t)b * NANCH * 2);
    const int p0 = blockIdx.x * CPAIR;
    for (int i = t; i < CPAIR; i += 256) {
        float4 v = p4[p0 + i];                 // scores of anchors 2p, 2p+1 in .y/.w
        u32 k0 = __float_as_uint(v.y);
        u32 k1 = __float_as_uint(v.w);
        if (k0 >= 0x3F000000u) atomicAdd(&h[min((k0 >> 16) - 0x3F00u, 128u)], 1u);
        if (k1 >= 0x3F000000u) atomicAdd(&h[min((k1 >> 16) - 0x3F00u, 128u)], 1u);
    }
    __syncthreads();
    if (t < 129 && h[t]) atomicAdd(&ghist[(b << 8) + t], h[t]);

    __threadfence();
    if (t == 0) s_old = atomicAdd(&done[b], 1u);
    __syncthreads();
    if (s_old == CBLK - 1) {
        // last block for this batch: all flushes are globally visible
        if (t < 129) h[t] = atomicAdd(&ghist[(b << 8) + t], 0u);   // coherent read
        __syncthreads();
        if (t == 0) {
            u32 run = 0; int bin = -1;
            for (int i = 128; i >= 0; --i) {
                run += h[i];
                if (run >= PRE_NMS) { bin = i; break; }
            }
            u32 T;
            if (bin < 0)         T = 0x3F000000u;   // unreachable (~131k scores >= 0.5)
            else if (bin == 128) T = 0x3F800000u;
            else                 T = 0x3F000000u + ((u32)bin << 16);
            Tc[b] = T;
        }
    }
}

// ---------------------------------------------------------------------------
// Kernel C: compact keys >= Tc[b] into selbuf. Block-local LDS staging +
// ONE padded global atomic per block. grid (32, BATCH) x 256.
// ---------------------------------------------------------------------------
__global__ __launch_bounds__(256)
void compact_kernel(const float* __restrict__ rpn_probs,
                    const u32* __restrict__ Tc,
                    ull* __restrict__ selbuf, u32* __restrict__ cntp)
{
    __shared__ ull kbuf[KCAP];
    __shared__ u32 s_n;
    __shared__ u32 s_base;
    const int t    = threadIdx.x;
    const int lane = t & 63;
    const int b    = blockIdx.y;
    const u32 T = Tc[b];
    if (t == 0) s_n = 0u;
    __syncthreads();

    const float4* p4 = reinterpret_cast<const float4*>(rpn_probs + (size_t)b * NANCH * 2);
    ull* sb = selbuf + (size_t)b * SORTN;
    const int p0 = blockIdx.x * CPAIR;

    for (int i = t; i < CPAIR; i += 256) {
        float4 v = p4[p0 + i];
        const int n0 = (p0 + i) << 1;
        #pragma unroll
        for (int e = 0; e < 2; ++e) {
            u32 k = __float_as_uint(e ? v.w : v.y);
            bool s0 = (k >= T);
            ull m = __ballot(s0 ? 1 : 0);
            if (!m) continue;                                  // wave-uniform
            int ldr = __ffsll(m) - 1;
            u32 base = 0;
            if (lane == ldr) base = atomicAdd(&s_n, (u32)__popcll(m));
            base = __shfl(base, ldr);
            u32 off = base + (u32)__popcll(m & ((1ull << lane) - 1ull));
            bool fit = s0 && (off < KCAP);
            if (fit) kbuf[off] = ((ull)(~k) << 32) | (ull)(u32)(n0 + e);
            ull sp = __ballot((s0 && !fit) ? 1 : 0);           // exact spill (unreachable)
            if (sp) {
                int l2 = __ffsll(sp) - 1;
                u32 gb = 0;
                if (lane == l2) gb = atomicAdd(&cntp[b << 6], (u32)__popcll(sp));
                gb = __shfl(gb, l2);
                if (s0 && !fit) {
                    u32 go = gb + (u32)__popcll(sp & ((1ull << lane) - 1ull));
                    if (go < SORTN) sb[go] = ((ull)(~k) << 32) | (ull)(u32)(n0 + e);
                }
            }
        }
    }
    __syncthreads();
    const u32 nn = min(s_n, (u32)KCAP);
    if (t == 0) s_base = atomicAdd(&cntp[b << 6], nn);
    __syncthreads();
    const u32 bs = s_base;
    for (u32 j = t; j < nn; j += 256) {
        u32 off = bs + j;
        if (off < SORTN) sb[off] = kbuf[j];
    }
}

// ---------------------------------------------------------------------------
// Kernel D: rank-scatter. slot(i) = #{j : comp_j < comp_i} — identical to
// ascending sort of the unique composite keys. Decode + scatter + area +
// alive atomicOr fused. grid (32, BATCH) x 256.
// ---------------------------------------------------------------------------
__global__ __launch_bounds__(256)
void rank_decode_kernel(const float* __restrict__ rpn_bbox,
                        const float* __restrict__ anchors,
                        const ull* __restrict__ selbuf,
                        const u32* __restrict__ cntp,
                        float4* __restrict__ boxes_ws,
                        float* __restrict__ area_ws,
                        ull* __restrict__ alive_ws)
{
    __shared__ ull tile[2048];   // 16 KB
    const int t = threadIdx.x;
    const int b = blockIdx.y;
    const u32 C = min(cntp[b << 6], (u32)SORTN);
    const ull* sb = selbuf + (size_t)b * SORTN;

    const int i = (blockIdx.x << 8) + t;
    const ull mykey = (i < (int)C) ? sb[i] : ~0ull;

    int rank = 0;
    for (u32 tb = 0; tb < C; tb += 2048) {
        const int m = (int)min((u32)2048, C - tb);
        __syncthreads();
        for (int j = t; j < m; j += 256) tile[j] = sb[tb + j];
        __syncthreads();
        int j = 0;
        for (; j + 8 <= m; j += 8) {
            #pragma unroll
            for (int u = 0; u < 8; ++u) rank += (tile[j + u] < mykey) ? 1 : 0;
        }
        for (; j < m; ++j) rank += (tile[j] < mykey) ? 1 : 0;
    }

    if (i < (int)C && rank < PRE_NMS) {
        const u32 key = ~(u32)(mykey >> 32);
        const u32 n   = (u32)(mykey & 0xFFFFFFFFull);
        const float4* bbox4 = reinterpret_cast<const float4*>(rpn_bbox + (size_t)b * NANCH * 4);
        const float4* anc4  = reinterpret_cast<const float4*>(anchors  + (size_t)b * NANCH * 4);
        float4 a = anc4[n];
        float4 d = bbox4[n];
        float dy = d.x * 0.1f, dx = d.y * 0.1f, dh = d.z * 0.2f, dw = d.w * 0.2f;
        float h  = a.z - a.x;
        float w  = a.w - a.y;
        float cy = a.x + 0.5f * h;
        float cx = a.y + 0.5f * w;
        cy = cy + dy * h;
        cx = cx + dx * w;
        h  = h * expf(dh);
        w  = w * expf(dw);
        float y1 = cy - 0.5f * h;
        float x1 = cx - 0.5f * w;
        float y2 = y1 + h;
        float x2 = x1 + w;
        y1 = fminf(fmaxf(y1, 0.f), 1.f);
        x1 = fminf(fmaxf(x1, 0.f), 1.f);
        y2 = fminf(fmaxf(y2, 0.f), 1.f);
        x2 = fminf(fmaxf(x2, 0.f), 1.f);
        boxes_ws[(size_t)b * NSLOT + rank] = make_float4(y1, x1, y2, x2);
        area_ws[(size_t)b * NSLOT + rank]  = (y2 - y1) * (x2 - x1);
        if (key >= SCORE_THRES_BITS) {
            atomicOr(&alive_ws[(size_t)b * MROW + (rank >> 6)], 1ull << (rank & 63));
        }
    }
}

// ---------------------------------------------------------------------------
// Kernel E: suppression bit-matrix, wave-balanced pair version (R8, kept).
// grid (188, BATCH) x 1024 (16 waves = 16 pairs = 32 rows/block).
// ---------------------------------------------------------------------------
__device__ __forceinline__ void iou_row(const float4* sbox, const float* sarea,
                                        int r, int lane, int b, ull* __restrict__ mat)
{
    const float4 p  = sbox[r];
    const float  pa = sarea[r];
    const int    k0 = r >> 6;
    ull* row = mat + ((size_t)b * PRE_NMS + r) * MROW;

    // diagonal word (mask away c <= r)
    {
        int c = (k0 << 6) + lane;
        float4 q = sbox[c];
        float qa  = sarea[c];
        float yy1 = fmaxf(p.x, q.x);
        float xx1 = fmaxf(p.y, q.y);
        float yy2 = fminf(p.z, q.z);
        float xx2 = fminf(p.w, q.w);
        float inter = fmaxf(yy2 - yy1, 0.f) * fmaxf(xx2 - xx1, 0.f);
        float denom = ((pa + qa) - inter) + EPS_F;
        ull m = __ballot(((double)inter > M_D * (double)denom) ? 1 : 0);
        int sh = r & 63;
        ull keep = (sh == 63) ? 0ull : ((~0ull) << (sh + 1));
        if (lane == 0) row[k0] = m & keep;
    }
    for (int k = k0 + 1; k < 94; ++k) {
        int c = (k << 6) + lane;
        float4 q = sbox[c];
        float qa  = sarea[c];
        float yy1 = fmaxf(p.x, q.x);
        float xx1 = fmaxf(p.y, q.y);
        float yy2 = fminf(p.z, q.z);
        float xx2 = fminf(p.w, q.w);
        float inter = fmaxf(yy2 - yy1, 0.f) * fmaxf(xx2 - xx1, 0.f);
        float denom = ((pa + qa) - inter) + EPS_F;
        ull m = __ballot(((double)inter > M_D * (double)denom) ? 1 : 0);
        if (lane == 0) row[k] = m;
    }
}

__global__ __launch_bounds__(1024)
void iou_matrix_kernel(const float4* __restrict__ boxes_ws,
                       const float* __restrict__ area_ws,
                       ull* __restrict__ mat)
{
    __shared__ float4 sbox[NSLOT];    // 96 KB
    __shared__ float  sarea[NSLOT];   // 24 KB
    const int b    = blockIdx.y;
    const int t    = threadIdx.x;
    const int lane = t & 63;
    const int wv   = t >> 6;

    const float4* bws = boxes_ws + (size_t)b * NSLOT;
    const float*  aws = area_ws  + (size_t)b * NSLOT;
    #pragma unroll
    for (int i = 0; i < 6; ++i) sbox[(i << 10) + t]  = bws[(i << 10) + t];
    #pragma unroll
    for (int i = 0; i < 6; ++i) sarea[(i << 10) + t] = aws[(i << 10) + t];
    __syncthreads();

    const int i = (blockIdx.x << 4) + wv;     // pair index 0..3007
    if (i >= PRE_NMS / 2) return;             // 3000 pairs
    iou_row(sbox, sarea, i,            lane, b, mat);
    iou_row(sbox, sarea, PRE_NMS - 1 - i, lane, b, mat);
}

// ---------------------------------------------------------------------------
// Kernel F (R10): word-walk greedy scan with LDS STREAMING PREFETCH.
//
// The scan consumes suppression words in strictly ascending order, and word
// g's 64 candidate rows are a CONTIGUOUS 48 KB block of mat (rows g*64..
// g*64+63, 768 B each). The stream is therefore fully predictable: triple-
// buffer it through LDS with 2-word lookahead via global_load_lds (48 x 1 KB
// per word; 36 for the ragged last word) and counted s_waitcnt vmcnt(48)
// (T3/T4 pattern). This removes the per-word global-memory round trip
// (~1-2k cy to dirty remote-XCD L2 lines) from the critical path:
//   - diag words come from the prefetched buffer (ds_read, no global load)
//   - picked-row ORs come from the prefetched buffer (ds_read_b128)
// vmcnt accounting: exactly ONE load group is issued per loop iteration and
// there is NO other VMEM in the loop body, so at iteration k's wait the
// instructions newer than P(k) are exactly P(k+1) (48, or 36 when k==92,
// 0 when k==93). In-order vmcnt completion makes vmcnt(48/36/0) exact.
// ---------------------------------------------------------------------------
template<int NLOAD>
__device__ __forceinline__ void stream_word_n(const char* gbase, char* dst, int g, int lane)
{
    // rows g*64 .. g*64+63 are contiguous: 48 KB starting at gbase + g*49152.
    const char* src = gbase + (size_t)g * 49152 + (unsigned)(lane << 4);
    #pragma unroll
    for (int i = 0; i < NLOAD; ++i) {
        __builtin_amdgcn_global_load_lds(
            (const __attribute__((address_space(1))) void*)(src + (i << 10)),
            (__attribute__((address_space(3))) void*)(dst + (i << 10)),
            16, 0, 0);
    }
}

__global__ __launch_bounds__(64)
__attribute__((amdgpu_waves_per_eu(1, 1)))
void nms_scan_kernel(const float4* __restrict__ boxes_ws,
                     const ull* __restrict__ alive_ws,
                     const ull* __restrict__ mat,
                     float* __restrict__ out)
{
    const int b    = blockIdx.x;
    const int lane = threadIdx.x;
    const int lc   = min(lane, 47);

    __shared__ ull sbuf[3][6144];    // 3 x 48 KB stream buffers
    __shared__ int picks[PROP];      // 4 KB   (total 147.9 KB < 160 KB)

    // lane l (<48) holds alive words 2l, 2l+1 (words 94,95 zero by construction)
    ull aw0 = 0, aw1 = 0;
    if (lane < 48) {
        const ull* aw = alive_ws + (size_t)b * MROW + 2 * lane;
        aw0 = aw[0]; aw1 = aw[1];
    }

    const ull* mb = mat + (size_t)b * PRE_NMS * MROW;
    const char* gbase = (const char*)mb;

    // prologue: stream words 0 and 1
    stream_word_n<48>(gbase, (char*)&sbuf[0][0], 0, lane);
    stream_word_n<48>(gbase, (char*)&sbuf[1][0], 1, lane);

    int cnt = 0;
    for (int k = 0; k < NW; ++k) {
        // wait for buffer k (exact count: newer-than-P(k) = P(k+1) only)
        if (k == NW - 1)      asm volatile("s_waitcnt vmcnt(0)" ::: "memory");
        else if (k == NW - 2) asm volatile("s_waitcnt vmcnt(36)" ::: "memory");
        else                  asm volatile("s_waitcnt vmcnt(48)" ::: "memory");
        __builtin_amdgcn_sched_barrier(0);

        const ull* dbuf = &sbuf[k % 3][0];

        // diag word for row k*64+lane, from the prefetched buffer (LDS).
        // lanes >= valid-row-count read stale/garbage; only consumed via
        // readlane(p) with p from wval, whose high bits are never set.
        ull diag_cur = dbuf[lane * 96 + k];

        // issue stream for word k+2 (the ONLY VMEM in the loop body)
        if (k + 2 < NW) {
            char* dst = (char*)&sbuf[(k + 2) % 3][0];
            if (k + 2 == NW - 1) stream_word_n<36>(gbase, dst, k + 2, lane);
            else                 stream_word_n<48>(gbase, dst, k + 2, lane);
        }

        const int src = k >> 1;
        const ull awk = (k & 1) ? aw1 : aw0;
        u32 wlo = (u32)__builtin_amdgcn_readlane((int)(u32)awk, src);
        u32 whi = (u32)__builtin_amdgcn_readlane((int)(u32)(awk >> 32), src);
        ull wval = ((ull)whi << 32) | (ull)wlo;

        if (wval != 0ull) {
            // ---- resolve picks within word k (scalar chain, register diag)
            ull m = wval;
            ull pickedm = 0ull;
            while (m) {
                int p = __ffsll(m) - 1;
                u32 lo = (u32)__builtin_amdgcn_readlane((int)(u32)diag_cur, p);
                u32 hi = (u32)__builtin_amdgcn_readlane((int)(u32)(diag_cur >> 32), p);
                ull sup = ((ull)hi << 32) | (ull)lo;
                if (lane == 0) picks[cnt] = (k << 6) + p;
                ++cnt;
                pickedm |= (1ull << p);
                m &= ~(sup | (1ull << p));
                if (cnt == PROP) break;
            }

            // ---- OR picked rows into alive regs, reading from the LDS buffer.
            // (skipped when cnt hit PROP: alive state is never used again)
            if (cnt < PROP) {
                const ulonglong2* bufv = reinterpret_cast<const ulonglong2*>(dbuf);
                ull tm = pickedm;
                const int p0 = __ffsll(tm) - 1;     // pad slot (idempotent OR)
                while (tm) {
                    int idx[16];
                    #pragma unroll
                    for (int q = 0; q < 16; ++q) {
                        if (tm) { int p = __ffsll(tm) - 1; tm &= tm - 1ull; idx[q] = p; }
                        else idx[q] = p0;
                    }
                    ulonglong2 v[16];
                    #pragma unroll
                    for (int q = 0; q < 16; ++q) v[q] = bufv[idx[q] * 48 + lc];
                    ull rx = 0, ry = 0;
                    #pragma unroll
                    for (int q = 0; q < 16; ++q) { rx |= v[q].x; ry |= v[q].y; }
                    aw0 &= ~rx; aw1 &= ~ry;
                }
            }
        }

        // word k fully consumed
        if (lane == (k >> 1)) { if (k & 1) aw1 = 0ull; else aw0 = 0ull; }
        if (cnt == PROP) break;
    }

    // drain any outstanding LDS-DMA before workgroup teardown
    asm volatile("s_waitcnt vmcnt(0)" ::: "memory");

    __syncthreads();
    const float4* bws = boxes_ws + (size_t)b * NSLOT;
    float4* ob = reinterpret_cast<float4*>(out + (size_t)b * PROP * 4);
    for (int i = lane; i < PROP; i += 64) {
        float4 v = make_float4(0.f, 0.f, 0.f, 0.f);
        if (i < cnt) v = bws[picks[i]];
        ob[i] = v;
    }
}

// ---------------------------------------------------------------------------
// Fallback: round-1 monolithic kernel (used if ws too small). Verified exact.
// ---------------------------------------------------------------------------
__device__ __forceinline__ void hist_add_f(unsigned int* hist, unsigned int bin, bool valid) {
    const int lane = threadIdx.x & 63;
    ull todo = __ballot(valid ? 1 : 0);
    #pragma unroll
    for (int it = 0; it < 3; ++it) {
        if (!todo) return;
        int leader = __ffsll(todo) - 1;
        unsigned int lbin = __shfl(bin, leader);
        ull grp = __ballot((valid && (bin == lbin)) ? 1 : 0);
        if (lane == leader) atomicAdd(&hist[lbin], (unsigned int)__popcll(grp));
        todo &= ~grp;
    }
    if ((todo >> lane) & 1ull) atomicAdd(&hist[bin], 1u);
}

__global__ __launch_bounds__(1024)
void proposal_fallback(const float* __restrict__ rpn_probs,
                       const float* __restrict__ rpn_bbox,
                       const float* __restrict__ anchors,
                       float* __restrict__ out)
{
    const int b    = blockIdx.x;
    const int t    = threadIdx.x;
    const int lane = t & 63;
    const int wv   = t >> 6;

    const float2* __restrict__ probs2 = reinterpret_cast<const float2*>(rpn_probs + (size_t)b * NANCH * 2);
    const float4* __restrict__ bbox4  = reinterpret_cast<const float4*>(rpn_bbox  + (size_t)b * NANCH * 4);
    const float4* __restrict__ anc4   = reinterpret_cast<const float4*>(anchors   + (size_t)b * NANCH * 4);
    float* __restrict__ outb = out + (size_t)b * PROP * 4;

    __shared__ __align__(16) char s_big[NSLOT * 16];
    __shared__ ull          s_alive[96];
    __shared__ unsigned int s_hist[256];
    __shared__ unsigned int s_pref;
    __shared__ unsigned int s_targ;
    __shared__ unsigned int s_cnt;

    ull*    sel   = reinterpret_cast<ull*>(s_big);
    float4* boxes = reinterpret_cast<float4*>(s_big);

    const int ITER = (NANCH + 1023) >> 10;

    if (t == 0) { s_pref = 0u; s_targ = PRE_NMS; s_cnt = 0u; }

    for (int p = 0; p < 4; ++p) {
        if (t < 256) s_hist[t] = 0u;
        __syncthreads();
        const unsigned int pref  = s_pref;
        const int          shift = 8 * (3 - p);
        const unsigned int pmask = (p == 0) ? 0u : (0xFFFFFFFFu << (shift + 8));
        for (int i = 0; i < ITER; ++i) {
            int  n     = (i << 10) + t;
            bool valid = (n < NANCH);
            unsigned int key = 0u;
            if (valid) key = __float_as_uint(probs2[n].y);
            bool match = valid && ((key & pmask) == (pref & pmask));
            hist_add_f(s_hist, (key >> shift) & 0xFFu, match);
        }
        __syncthreads();
        if (t == 0) {
            unsigned int target = s_targ;
            unsigned int acc = 0u;
            int v = 255;
            for (; v >= 0; --v) {
                unsigned int h = s_hist[v];
                if (acc + h >= target) break;
                acc += h;
            }
            if (v < 0) v = 0;
            s_pref = pref | ((unsigned int)v << shift);
            s_targ = target - acc;
        }
        __syncthreads();
    }

    const unsigned int T = s_pref;
    __syncthreads();

    for (int i = 0; i < ITER; ++i) {
        int  n     = (i << 10) + t;
        bool valid = (n < NANCH);
        unsigned int key = 0u;
        if (valid) key = __float_as_uint(probs2[n].y);
        bool selp = valid && (key >= T);
        ull  m    = __ballot(selp ? 1 : 0);
        if (m) {
            int leader = __ffsll(m) - 1;
            unsigned int base = 0u;
            if (lane == leader) base = atomicAdd(&s_cnt, (unsigned int)__popcll(m));
            base = __shfl(base, leader);
            if (selp) {
                unsigned int off = base + (unsigned int)__popcll(m & ((1ull << lane) - 1ull));
                if (off < SORTN) sel[off] = ((ull)(~key) << 32) | (ull)(unsigned int)n;
            }
        }
    }
    __syncthreads();
    const unsigned int C = s_cnt;
    for (int s = (int)C + t; s < SORTN; s += 1024) sel[s] = ~0ull;
    __syncthreads();

    for (unsigned int k = 2; k <= SORTN; k <<= 1) {
        for (unsigned int j = k >> 1; j > 0; j >>= 1) {
            #pragma unroll
            for (int r = 0; r < SORTN / 1024; ++r) {
                int i = (r << 10) + t;
                int l = i ^ (int)j;
                if (l > i) {
                    ull a  = sel[i];
                    ull bq = sel[l];
                    bool up = ((i & (int)k) == 0);
                    if ((a > bq) == up) { sel[i] = bq; sel[l] = a; }
                }
            }
            __syncthreads();
        }
    }

    ull ss[6];
    #pragma unroll
    for (int e = 0; e < 6; ++e) ss[e] = sel[(e << 10) + t];
    __syncthreads();

    float4 rbox[6];
    float  rarea[6];
    #pragma unroll
    for (int e = 0; e < 6; ++e) {
        int s = (e << 10) + t;
        float4 bx = make_float4(0.f, 0.f, 0.f, 0.f);
        bool ok = false;
        if (s < PRE_NMS) {
            unsigned int key = ~(unsigned int)(ss[e] >> 32);
            unsigned int n   = (unsigned int)(ss[e] & 0xFFFFFFFFull);
            float4 a = anc4[n];
            float4 d = bbox4[n];
            float dy = d.x * 0.1f, dx = d.y * 0.1f, dh = d.z * 0.2f, dw = d.w * 0.2f;
            float h  = a.z - a.x;
            float w  = a.w - a.y;
            float cy = a.x + 0.5f * h;
            float cx = a.y + 0.5f * w;
            cy = cy + dy * h;
            cx = cx + dx * w;
            h  = h * expf(dh);
            w  = w * expf(dw);
            float y1 = cy - 0.5f * h;
            float x1 = cx - 0.5f * w;
            float y2 = y1 + h;
            float x2 = x1 + w;
            y1 = fminf(fmaxf(y1, 0.f), 1.f);
            x1 = fminf(fmaxf(x1, 0.f), 1.f);
            y2 = fminf(fmaxf(y2, 0.f), 1.f);
            x2 = fminf(fmaxf(x2, 0.f), 1.f);
            bx = make_float4(y1, x1, y2, x2);
            ok = (key >= SCORE_THRES_BITS);
        }
        rbox[e]  = bx;
        rarea[e] = (bx.z - bx.x) * (bx.w - bx.y);
        boxes[s] = bx;
        ull am = __ballot(ok ? 1 : 0);
        if (lane == 0) s_alive[wv + (e << 4)] = am;
    }

    int emitted = 0;
    for (;;) {
        __syncthreads();
        if (emitted == PROP) break;
        ull w0 = s_alive[lane];
        ull w1 = (lane < 32) ? s_alive[64 + lane] : 0ull;
        ull nz0 = __ballot(w0 != 0ull ? 1 : 0);
        ull nz1 = __ballot(w1 != 0ull ? 1 : 0);
        int pick = -1;
        if (nz0) {
            int wd = __ffsll(nz0) - 1;
            ull wvv = __shfl(w0, wd);
            pick = (wd << 6) + __ffsll(wvv) - 1;
        } else if (nz1) {
            int wd = __ffsll(nz1) - 1;
            ull wvv = __shfl(w1, wd);
            pick = ((wd + 64) << 6) + __ffsll(wvv) - 1;
        }
        if (pick < 0) break;
        __syncthreads();

        if (t < 4) outb[(emitted << 2) + t] = reinterpret_cast<const float*>(s_big)[(pick << 2) + t];

        float4 p = boxes[pick];
        float parea = (p.z - p.x) * (p.w - p.y);
        #pragma unroll
        for (int e = 0; e < 6; ++e) {
            float4 bb  = rbox[e];
            float yy1 = fmaxf(p.x, bb.x);
            float xx1 = fmaxf(p.y, bb.y);
            float yy2 = fminf(p.z, bb.z);
            float xx2 = fminf(p.w, bb.w);
            float ih  = fmaxf(yy2 - yy1, 0.f);
            float iw  = fmaxf(xx2 - xx1, 0.f);
            float inter = ih * iw;
            float denom = ((parea + rarea[e]) - inter) + EPS_F;
            bool  sup   = ((double)inter > M_D * (double)denom);
            ull m = __ballot(sup ? 1 : 0);
            int word = wv + (e << 4);
            if (word == (pick >> 6)) m |= (1ull << (pick & 63));
            if (lane == 0) s_alive[word] &= ~m;
        }
        ++emitted;
    }

    for (int i = (emitted << 2) + t; i < PROP * 4; i += 1024) outb[i] = 0.f;
}

extern "C" void kernel_launch(void* const* d_in, const int* in_sizes, int n_in,
                              void* d_out, int out_size, void* d_ws, size_t ws_size,
                              hipStream_t stream) {
    const float* rpn_probs = (const float*)d_in[0];
    const float* rpn_bbox  = (const float*)d_in[1];
    const float* anchors   = (const float*)d_in[2];
    float* out = (float*)d_out;

    // ws layout:
    //   [0)        boxes   8*6144*16 = 786432
    //   [786432)   areas   8*6144*4  = 196608   -> ends 983040
    //   [983040)   ZERO region (one memset to MAT_OFF):
    //       alive  8*96*8 = 6144   @983040
    //       Tc     32 B            @989184
    //       done   32 B            @989440
    //       cntp   8*64*4 = 2048   @989696
    //       ghist  8*256*4 = 8192  @991744   -> ends 999936
    //   [1MiB)     mat (selbuf aliased at its head, consumed before mat write)
    const size_t BOX_OFF   = 0;
    const size_t AREA_OFF  = 786432;
    const size_t ZERO_OFF  = 983040;
    const size_t ALIVE_OFF = 983040;
    const size_t TC_OFF    = 989184;
    const size_t DONE_OFF  = 989440;
    const size_t CNT_OFF   = 989696;
    const size_t GHIST_OFF = 991744;
    const size_t MAT_OFF   = 1u << 20;
    const size_t SELB_OFF  = MAT_OFF;
    const size_t WS_NEED   = MAT_OFF + (size_t)BATCH * PRE_NMS * MROW * 8;     // ~37.9 MB

    if (d_ws != nullptr && ws_size >= WS_NEED) {
        char* ws = (char*)d_ws;
        float4* boxes_ws = (float4*)(ws + BOX_OFF);
        float*  area_ws  = (float*)(ws + AREA_OFF);
        ull*    alive_ws = (ull*)(ws + ALIVE_OFF);
        u32*    Tc       = (u32*)(ws + TC_OFF);
        u32*    done     = (u32*)(ws + DONE_OFF);
        u32*    cntp     = (u32*)(ws + CNT_OFF);
        u32*    ghist    = (u32*)(ws + GHIST_OFF);
        ull*    selbuf   = (ull*)(ws + SELB_OFF);
        ull*    mat      = (ull*)(ws + MAT_OFF);

        hipMemsetAsync(ws + ZERO_OFF, 0, MAT_OFF - ZERO_OFF, stream);  // alive..ghist
        hipLaunchKernelGGL(hist_kernel, dim3(CBLK, BATCH), dim3(256), 0, stream,
                           rpn_probs, ghist, done, Tc);
        hipLaunchKernelGGL(compact_kernel, dim3(CBLK, BATCH), dim3(256), 0, stream,
                           rpn_probs, Tc, selbuf, cntp);
        hipLaunchKernelGGL(rank_decode_kernel, dim3(SORTN / 256, BATCH), dim3(256), 0, stream,
                           rpn_bbox, anchors, selbuf, cntp, boxes_ws, area_ws, alive_ws);
        hipLaunchKernelGGL(iou_matrix_kernel, dim3(188, BATCH), dim3(1024), 0, stream,
                           boxes_ws, area_ws, mat);
        hipLaunchKernelGGL(nms_scan_kernel, dim3(BATCH), dim3(64), 0, stream,
                           boxes_ws, alive_ws, mat, out);
    } else {
        hipLaunchKernelGGL(proposal_fallback, dim3(BATCH), dim3(1024), 0, stream,
                           rpn_probs, rpn_bbox, anchors, out);
    }
}

// Round 2
// 401.596 us; speedup vs baseline: 1.2178x; 1.1746x over previous
//
#include <hip/hip_runtime.h>
#include <cstdint>
#include <cstddef>

#pragma clang fp contract(off)

#define BATCH    8
#define NANCH    261888
#define PRE_NMS  6000
#define PROP     1000
#define SORTN    8192
#define NSLOT    6144          /* 6 * 1024 */
#define MROW     96            /* u64 words per suppression row (94 used + 2 pad) */
#define NW       94            /* suppression words per batch (6000/64 rounded up) */
#define NPAIR    130944        /* NANCH / 2 */
#define CBLK     32            /* blocks per batch for hist/compact */
#define CPAIR    4092          /* NPAIR / CBLK */
#define KCAP     1024          /* compact LDS staging capacity */
#define SCORE_THRES_BITS 0x3F000000u   /* bits of 0.5f */
#define EPS_F    1e-8f
/* midpoint between pred(0.7f) and 0.7f = 23488101 * 2^-25, exact in double.
   RN(inter/denom) >= 0.7f  <=>  inter > M_D * denom  (exact: 25b x 24b product;
   tie rounds to even = pred(0.7f), so strict > is correct). */
#define M_D      0.6999999582767486572265625

typedef unsigned long long ull;
typedef unsigned int u32;

// ---------------------------------------------------------------------------
// Kernel A (fused hist + findT): fine histogram of scores >= 0.5 into 129
// bins; the LAST block per batch (done-counter) computes the coarse threshold.
// grid (32, BATCH) x 256.
// ---------------------------------------------------------------------------
__global__ __launch_bounds__(256)
void hist_kernel(const float* __restrict__ rpn_probs, u32* __restrict__ ghist,
                 u32* __restrict__ done, u32* __restrict__ Tc)
{
    __shared__ u32 h[129];
    __shared__ u32 s_old;
    const int t = threadIdx.x;
    const int b = blockIdx.y;
    if (t < 129) h[t] = 0u;
    __syncthreads();

    const float4* p4 = reinterpret_cast<const float4*>(rpn_probs + (size_t)b * NANCH * 2);
    const int p0 = blockIdx.x * CPAIR;
    for (int i = t; i < CPAIR; i += 256) {
        float4 v = p4[p0 + i];                 // scores of anchors 2p, 2p+1 in .y/.w
        u32 k0 = __float_as_uint(v.y);
        u32 k1 = __float_as_uint(v.w);
        if (k0 >= 0x3F000000u) atomicAdd(&h[min((k0 >> 16) - 0x3F00u, 128u)], 1u);
        if (k1 >= 0x3F000000u) atomicAdd(&h[min((k1 >> 16) - 0x3F00u, 128u)], 1u);
    }
    __syncthreads();
    if (t < 129 && h[t]) atomicAdd(&ghist[(b << 8) + t], h[t]);

    __threadfence();
    if (t == 0) s_old = atomicAdd(&done[b], 1u);
    __syncthreads();
    if (s_old == CBLK - 1) {
        // last block for this batch: all flushes are globally visible
        if (t < 129) h[t] = atomicAdd(&ghist[(b << 8) + t], 0u);   // coherent read
        __syncthreads();
        if (t == 0) {
            u32 run = 0; int bin = -1;
            for (int i = 128; i >= 0; --i) {
                run += h[i];
                if (run >= PRE_NMS) { bin = i; break; }
            }
            u32 T;
            if (bin < 0)         T = 0x3F000000u;   // unreachable (~131k scores >= 0.5)
            else if (bin == 128) T = 0x3F800000u;
            else                 T = 0x3F000000u + ((u32)bin << 16);
            Tc[b] = T;
        }
    }
}

// ---------------------------------------------------------------------------
// Kernel C: compact keys >= Tc[b] into selbuf. Block-local LDS staging +
// ONE padded global atomic per block. grid (32, BATCH) x 256.
// ---------------------------------------------------------------------------
__global__ __launch_bounds__(256)
void compact_kernel(const float* __restrict__ rpn_probs,
                    const u32* __restrict__ Tc,
                    ull* __restrict__ selbuf, u32* __restrict__ cntp)
{
    __shared__ ull kbuf[KCAP];
    __shared__ u32 s_n;
    __shared__ u32 s_base;
    const int t    = threadIdx.x;
    const int lane = t & 63;
    const int b    = blockIdx.y;
    const u32 T = Tc[b];
    if (t == 0) s_n = 0u;
    __syncthreads();

    const float4* p4 = reinterpret_cast<const float4*>(rpn_probs + (size_t)b * NANCH * 2);
    ull* sb = selbuf + (size_t)b * SORTN;
    const int p0 = blockIdx.x * CPAIR;

    for (int i = t; i < CPAIR; i += 256) {
        float4 v = p4[p0 + i];
        const int n0 = (p0 + i) << 1;
        #pragma unroll
        for (int e = 0; e < 2; ++e) {
            u32 k = __float_as_uint(e ? v.w : v.y);
            bool s0 = (k >= T);
            ull m = __ballot(s0 ? 1 : 0);
            if (!m) continue;                                  // wave-uniform
            int ldr = __ffsll(m) - 1;
            u32 base = 0;
            if (lane == ldr) base = atomicAdd(&s_n, (u32)__popcll(m));
            base = __shfl(base, ldr);
            u32 off = base + (u32)__popcll(m & ((1ull << lane) - 1ull));
            bool fit = s0 && (off < KCAP);
            if (fit) kbuf[off] = ((ull)(~k) << 32) | (ull)(u32)(n0 + e);
            ull sp = __ballot((s0 && !fit) ? 1 : 0);           // exact spill (unreachable)
            if (sp) {
                int l2 = __ffsll(sp) - 1;
                u32 gb = 0;
                if (lane == l2) gb = atomicAdd(&cntp[b << 6], (u32)__popcll(sp));
                gb = __shfl(gb, l2);
                if (s0 && !fit) {
                    u32 go = gb + (u32)__popcll(sp & ((1ull << lane) - 1ull));
                    if (go < SORTN) sb[go] = ((ull)(~k) << 32) | (ull)(u32)(n0 + e);
                }
            }
        }
    }
    __syncthreads();
    const u32 nn = min(s_n, (u32)KCAP);
    if (t == 0) s_base = atomicAdd(&cntp[b << 6], nn);
    __syncthreads();
    const u32 bs = s_base;
    for (u32 j = t; j < nn; j += 256) {
        u32 off = bs + j;
        if (off < SORTN) sb[off] = kbuf[j];
    }
}

// ---------------------------------------------------------------------------
// Kernel D: rank-scatter. slot(i) = #{j : comp_j < comp_i} — identical to
// ascending sort of the unique composite keys. Decode + scatter + area +
// alive atomicOr fused. grid (32, BATCH) x 256.
// ---------------------------------------------------------------------------
__global__ __launch_bounds__(256)
void rank_decode_kernel(const float* __restrict__ rpn_bbox,
                        const float* __restrict__ anchors,
                        const ull* __restrict__ selbuf,
                        const u32* __restrict__ cntp,
                        float4* __restrict__ boxes_ws,
                        float* __restrict__ area_ws,
                        ull* __restrict__ alive_ws)
{
    __shared__ ull tile[2048];   // 16 KB
    const int t = threadIdx.x;
    const int b = blockIdx.y;
    const u32 C = min(cntp[b << 6], (u32)SORTN);
    const ull* sb = selbuf + (size_t)b * SORTN;

    const int i = (blockIdx.x << 8) + t;
    const ull mykey = (i < (int)C) ? sb[i] : ~0ull;

    int rank = 0;
    for (u32 tb = 0; tb < C; tb += 2048) {
        const int m = (int)min((u32)2048, C - tb);
        __syncthreads();
        for (int j = t; j < m; j += 256) tile[j] = sb[tb + j];
        __syncthreads();
        int j = 0;
        for (; j + 8 <= m; j += 8) {
            #pragma unroll
            for (int u = 0; u < 8; ++u) rank += (tile[j + u] < mykey) ? 1 : 0;
        }
        for (; j < m; ++j) rank += (tile[j] < mykey) ? 1 : 0;
    }

    if (i < (int)C && rank < PRE_NMS) {
        const u32 key = ~(u32)(mykey >> 32);
        const u32 n   = (u32)(mykey & 0xFFFFFFFFull);
        const float4* bbox4 = reinterpret_cast<const float4*>(rpn_bbox + (size_t)b * NANCH * 4);
        const float4* anc4  = reinterpret_cast<const float4*>(anchors  + (size_t)b * NANCH * 4);
        float4 a = anc4[n];
        float4 d = bbox4[n];
        float dy = d.x * 0.1f, dx = d.y * 0.1f, dh = d.z * 0.2f, dw = d.w * 0.2f;
        float h  = a.z - a.x;
        float w  = a.w - a.y;
        float cy = a.x + 0.5f * h;
        float cx = a.y + 0.5f * w;
        cy = cy + dy * h;
        cx = cx + dx * w;
        h  = h * expf(dh);
        w  = w * expf(dw);
        float y1 = cy - 0.5f * h;
        float x1 = cx - 0.5f * w;
        float y2 = y1 + h;
        float x2 = x1 + w;
        y1 = fminf(fmaxf(y1, 0.f), 1.f);
        x1 = fminf(fmaxf(x1, 0.f), 1.f);
        y2 = fminf(fmaxf(y2, 0.f), 1.f);
        x2 = fminf(fmaxf(x2, 0.f), 1.f);
        boxes_ws[(size_t)b * NSLOT + rank] = make_float4(y1, x1, y2, x2);
        area_ws[(size_t)b * NSLOT + rank]  = (y2 - y1) * (x2 - x1);
        if (key >= SCORE_THRES_BITS) {
            atomicOr(&alive_ws[(size_t)b * MROW + (rank >> 6)], 1ull << (rank & 63));
        }
    }
}

// ---------------------------------------------------------------------------
// Kernel E: suppression bit-matrix, wave-balanced pair version (R8, kept).
// grid (188, BATCH) x 1024 (16 waves = 16 pairs = 32 rows/block).
// ---------------------------------------------------------------------------
__device__ __forceinline__ void iou_row(const float4* sbox, const float* sarea,
                                        int r, int lane, int b, ull* __restrict__ mat)
{
    const float4 p  = sbox[r];
    const float  pa = sarea[r];
    const int    k0 = r >> 6;
    ull* row = mat + ((size_t)b * PRE_NMS + r) * MROW;

    // diagonal word (mask away c <= r)
    {
        int c = (k0 << 6) + lane;
        float4 q = sbox[c];
        float qa  = sarea[c];
        float yy1 = fmaxf(p.x, q.x);
        float xx1 = fmaxf(p.y, q.y);
        float yy2 = fminf(p.z, q.z);
        float xx2 = fminf(p.w, q.w);
        float inter = fmaxf(yy2 - yy1, 0.f) * fmaxf(xx2 - xx1, 0.f);
        float denom = ((pa + qa) - inter) + EPS_F;
        ull m = __ballot(((double)inter > M_D * (double)denom) ? 1 : 0);
        int sh = r & 63;
        ull keep = (sh == 63) ? 0ull : ((~0ull) << (sh + 1));
        if (lane == 0) row[k0] = m & keep;
    }
    for (int k = k0 + 1; k < 94; ++k) {
        int c = (k << 6) + lane;
        float4 q = sbox[c];
        float qa  = sarea[c];
        float yy1 = fmaxf(p.x, q.x);
        float xx1 = fmaxf(p.y, q.y);
        float yy2 = fminf(p.z, q.z);
        float xx2 = fminf(p.w, q.w);
        float inter = fmaxf(yy2 - yy1, 0.f) * fmaxf(xx2 - xx1, 0.f);
        float denom = ((pa + qa) - inter) + EPS_F;
        ull m = __ballot(((double)inter > M_D * (double)denom) ? 1 : 0);
        if (lane == 0) row[k] = m;
    }
}

__global__ __launch_bounds__(1024)
void iou_matrix_kernel(const float4* __restrict__ boxes_ws,
                       const float* __restrict__ area_ws,
                       ull* __restrict__ mat)
{
    __shared__ float4 sbox[NSLOT];    // 96 KB
    __shared__ float  sarea[NSLOT];   // 24 KB
    const int b    = blockIdx.y;
    const int t    = threadIdx.x;
    const int lane = t & 63;
    const int wv   = t >> 6;

    const float4* bws = boxes_ws + (size_t)b * NSLOT;
    const float*  aws = area_ws  + (size_t)b * NSLOT;
    #pragma unroll
    for (int i = 0; i < 6; ++i) sbox[(i << 10) + t]  = bws[(i << 10) + t];
    #pragma unroll
    for (int i = 0; i < 6; ++i) sarea[(i << 10) + t] = aws[(i << 10) + t];
    __syncthreads();

    const int i = (blockIdx.x << 4) + wv;     // pair index 0..3007
    if (i >= PRE_NMS / 2) return;             // 3000 pairs
    iou_row(sbox, sarea, i,            lane, b, mat);
    iou_row(sbox, sarea, PRE_NMS - 1 - i, lane, b, mat);
}

// ---------------------------------------------------------------------------
// Kernel F (R11): word-walk greedy scan, LANE-PARALLEL pick resolution.
//
// R10 post-mortem: LDS prefetch changed nothing (135.3 -> 134.9 us) => the
// critical path was never the row loads. With random boxes IoU>=0.7 is rare,
// so ~every candidate is picked; the scan terminates after ~17 words and its
// time was ~1000 serial iterations of the per-pick readlane chain (~130 cy
// each). This version resolves a whole 64-candidate word in parallel:
//   fast path: if no alive candidate suppresses another alive candidate
//     (1 ballot), accept the whole word at once (ranks via popc).
//   slow path: 6-step in-wave 64x64 bit transpose (lane c holds "who
//     suppresses c"), then iterative closure: each round accepts ALL
//     candidates with no live suppressor and kills their victims. Rounds =
//     suppression chain depth (~1-2). Exact same greedy set as the serial
//     chain (suppression is strictly lower-triangular after transpose).
// PROP cap: truncating to the lowest-rank picks of the word is exact because
// picks only ever suppress later candidates.
// LDS streaming (R10) kept: diag + picked-row ORs come from prefetched LDS.
// vmcnt accounting unchanged: exactly ONE load group per iteration, no other
// VMEM in the loop (ballot/shfl are DS/SALU -> lgkmcnt).
// ---------------------------------------------------------------------------
template<int NLOAD>
__device__ __forceinline__ void stream_word_n(const char* gbase, char* dst, int g, int lane)
{
    // rows g*64 .. g*64+63 are contiguous: 48 KB starting at gbase + g*49152.
    const char* src = gbase + (size_t)g * 49152 + (unsigned)(lane << 4);
    #pragma unroll
    for (int i = 0; i < NLOAD; ++i) {
        __builtin_amdgcn_global_load_lds(
            (const __attribute__((address_space(1))) void*)(src + (i << 10)),
            (__attribute__((address_space(3))) void*)(dst + (i << 10)),
            16, 0, 0);
    }
}

__device__ __forceinline__ ull shfl_xor64(ull x, int s)
{
    return (ull)__shfl_xor((long long)x, s, 64);
}

__global__ __launch_bounds__(64)
__attribute__((amdgpu_waves_per_eu(1, 1)))
void nms_scan_kernel(const float4* __restrict__ boxes_ws,
                     const ull* __restrict__ alive_ws,
                     const ull* __restrict__ mat,
                     float* __restrict__ out)
{
    const int b    = blockIdx.x;
    const int lane = threadIdx.x;
    const int lc   = min(lane, 47);

    __shared__ ull sbuf[3][6144];    // 3 x 48 KB stream buffers
    __shared__ int picks[PROP];      // 4 KB   (total 147.9 KB < 160 KB)

    // lane l (<48) holds alive words 2l, 2l+1 (words 94,95 zero by construction)
    ull aw0 = 0, aw1 = 0;
    if (lane < 48) {
        const ull* aw = alive_ws + (size_t)b * MROW + 2 * lane;
        aw0 = aw[0]; aw1 = aw[1];
    }

    const ull* mb = mat + (size_t)b * PRE_NMS * MROW;
    const char* gbase = (const char*)mb;

    // prologue: stream words 0 and 1
    stream_word_n<48>(gbase, (char*)&sbuf[0][0], 0, lane);
    stream_word_n<48>(gbase, (char*)&sbuf[1][0], 1, lane);

    int cnt = 0;
    for (int k = 0; k < NW; ++k) {
        // wait for buffer k (exact count: newer-than-P(k) = P(k+1) only)
        if (k == NW - 1)      asm volatile("s_waitcnt vmcnt(0)" ::: "memory");
        else if (k == NW - 2) asm volatile("s_waitcnt vmcnt(36)" ::: "memory");
        else                  asm volatile("s_waitcnt vmcnt(48)" ::: "memory");
        __builtin_amdgcn_sched_barrier(0);

        const ull* dbuf = &sbuf[k % 3][0];

        // diag word for row k*64+lane, from the prefetched buffer (LDS).
        // Rows that were never written (rank >= C) contribute garbage bits,
        // but only at positions of never-alive candidates: every use below
        // masks with the alive set (A, D subsets of wval), so garbage is dead.
        ull diag_cur = dbuf[lane * 96 + k];

        // issue stream for word k+2 (the ONLY VMEM in the loop body)
        if (k + 2 < NW) {
            char* dst = (char*)&sbuf[(k + 2) % 3][0];
            if (k + 2 == NW - 1) stream_word_n<36>(gbase, dst, k + 2, lane);
            else                 stream_word_n<48>(gbase, dst, k + 2, lane);
        }

        const int src = k >> 1;
        const ull awk = (k & 1) ? aw1 : aw0;
        u32 wlo = (u32)__builtin_amdgcn_readlane((int)(u32)awk, src);
        u32 whi = (u32)__builtin_amdgcn_readlane((int)(u32)(awk >> 32), src);
        ull wval = ((ull)whi << 32) | (ull)wlo;

        if (wval != 0ull) {
            // ---- lane-parallel pick resolution for word k
            const bool rowAlive = (wval >> lane) & 1ull;
            ull P;  // picked set (uniform)
            // fast path: no alive candidate suppresses another alive candidate
            ull conflict = __ballot((rowAlive && ((diag_cur & wval) != 0ull)) ? 1 : 0);
            if (conflict == 0ull) {
                P = wval;
            } else {
                // transpose the 64x64 intra tile: T = "who suppresses me"
                // (strictly lower bits only: diag rows mask away c <= r)
                ull T = diag_cur;
                {
                    ull y;
                    y = shfl_xor64(T, 32);
                    T = (lane & 32) ? ((T & 0xFFFFFFFF00000000ull) | ((y & 0xFFFFFFFF00000000ull) >> 32))
                                    : ((T & 0x00000000FFFFFFFFull) | ((y & 0x00000000FFFFFFFFull) << 32));
                    y = shfl_xor64(T, 16);
                    T = (lane & 16) ? ((T & 0xFFFF0000FFFF0000ull) | ((y & 0xFFFF0000FFFF0000ull) >> 16))
                                    : ((T & 0x0000FFFF0000FFFFull) | ((y & 0x0000FFFF0000FFFFull) << 16));
                    y = shfl_xor64(T, 8);
                    T = (lane & 8)  ? ((T & 0xFF00FF00FF00FF00ull) | ((y & 0xFF00FF00FF00FF00ull) >> 8))
                                    : ((T & 0x00FF00FF00FF00FFull) | ((y & 0x00FF00FF00FF00FFull) << 8));
                    y = shfl_xor64(T, 4);
                    T = (lane & 4)  ? ((T & 0xF0F0F0F0F0F0F0F0ull) | ((y & 0xF0F0F0F0F0F0F0F0ull) >> 4))
                                    : ((T & 0x0F0F0F0F0F0F0F0Full) | ((y & 0x0F0F0F0F0F0F0F0Full) << 4));
                    y = shfl_xor64(T, 2);
                    T = (lane & 2)  ? ((T & 0xCCCCCCCCCCCCCCCCull) | ((y & 0xCCCCCCCCCCCCCCCCull) >> 2))
                                    : ((T & 0x3333333333333333ull) | ((y & 0x3333333333333333ull) << 2));
                    y = shfl_xor64(T, 1);
                    T = (lane & 1)  ? ((T & 0xAAAAAAAAAAAAAAAAull) | ((y & 0xAAAAAAAAAAAAAAAAull) >> 1))
                                    : ((T & 0x5555555555555555ull) | ((y & 0x5555555555555555ull) << 1));
                }
                // iterative closure: accept all with no live suppressor,
                // kill their victims; repeat. Equals sequential greedy.
                ull A = wval;
                P = 0ull;
                while (A) {
                    const bool inA = (A >> lane) & 1ull;
                    ull D = __ballot((inA && ((T & A) == 0ull)) ? 1 : 0);
                    P |= D;
                    ull kill = __ballot((inA && ((T & D) != 0ull)) ? 1 : 0);
                    A &= ~(D | kill);
                }
            }

            // ---- ordered, PROP-capped parallel pick write
            const int total = __popcll(P);
            const int room  = PROP - cnt;
            const bool lanePicked = (P >> lane) & 1ull;
            const int myrank = __popcll(P & ((1ull << lane) - 1ull));
            if (lanePicked && myrank < room) picks[cnt + myrank] = (k << 6) + lane;
            cnt = (total >= room) ? PROP : (cnt + total);

            // ---- OR picked rows into alive regs, reading from the LDS buffer.
            // (skipped when cnt hit PROP: alive state is never used again)
            if (cnt < PROP) {
                const ulonglong2* bufv = reinterpret_cast<const ulonglong2*>(dbuf);
                ull tm = P;
                const int p0 = __ffsll(tm) - 1;     // pad slot (idempotent OR)
                while (tm) {
                    int idx[16];
                    #pragma unroll
                    for (int q = 0; q < 16; ++q) {
                        if (tm) { int p = __ffsll(tm) - 1; tm &= tm - 1ull; idx[q] = p; }
                        else idx[q] = p0;
                    }
                    ulonglong2 v[16];
                    #pragma unroll
                    for (int q = 0; q < 16; ++q) v[q] = bufv[idx[q] * 48 + lc];
                    ull rx = 0, ry = 0;
                    #pragma unroll
                    for (int q = 0; q < 16; ++q) { rx |= v[q].x; ry |= v[q].y; }
                    aw0 &= ~rx; aw1 &= ~ry;
                }
            }
        }

        // word k fully consumed
        if (lane == (k >> 1)) { if (k & 1) aw1 = 0ull; else aw0 = 0ull; }
        if (cnt == PROP) break;
    }

    // drain any outstanding LDS-DMA before workgroup teardown
    asm volatile("s_waitcnt vmcnt(0)" ::: "memory");

    __syncthreads();
    const float4* bws = boxes_ws + (size_t)b * NSLOT;
    float4* ob = reinterpret_cast<float4*>(out + (size_t)b * PROP * 4);
    for (int i = lane; i < PROP; i += 64) {
        float4 v = make_float4(0.f, 0.f, 0.f, 0.f);
        if (i < cnt) v = bws[picks[i]];
        ob[i] = v;
    }
}

// ---------------------------------------------------------------------------
// Fallback: round-1 monolithic kernel (used if ws too small). Verified exact.
// ---------------------------------------------------------------------------
__device__ __forceinline__ void hist_add_f(unsigned int* hist, unsigned int bin, bool valid) {
    const int lane = threadIdx.x & 63;
    ull todo = __ballot(valid ? 1 : 0);
    #pragma unroll
    for (int it = 0; it < 3; ++it) {
        if (!todo) return;
        int leader = __ffsll(todo) - 1;
        unsigned int lbin = __shfl(bin, leader);
        ull grp = __ballot((valid && (bin == lbin)) ? 1 : 0);
        if (lane == leader) atomicAdd(&hist[lbin], (unsigned int)__popcll(grp));
        todo &= ~grp;
    }
    if ((todo >> lane) & 1ull) atomicAdd(&hist[bin], 1u);
}

__global__ __launch_bounds__(1024)
void proposal_fallback(const float* __restrict__ rpn_probs,
                       const float* __restrict__ rpn_bbox,
                       const float* __restrict__ anchors,
                       float* __restrict__ out)
{
    const int b    = blockIdx.x;
    const int t    = threadIdx.x;
    const int lane = t & 63;
    const int wv   = t >> 6;

    const float2* __restrict__ probs2 = reinterpret_cast<const float2*>(rpn_probs + (size_t)b * NANCH * 2);
    const float4* __restrict__ bbox4  = reinterpret_cast<const float4*>(rpn_bbox  + (size_t)b * NANCH * 4);
    const float4* __restrict__ anc4   = reinterpret_cast<const float4*>(anchors   + (size_t)b * NANCH * 4);
    float* __restrict__ outb = out + (size_t)b * PROP * 4;

    __shared__ __align__(16) char s_big[NSLOT * 16];
    __shared__ ull          s_alive[96];
    __shared__ unsigned int s_hist[256];
    __shared__ unsigned int s_pref;
    __shared__ unsigned int s_targ;
    __shared__ unsigned int s_cnt;

    ull*    sel   = reinterpret_cast<ull*>(s_big);
    float4* boxes = reinterpret_cast<float4*>(s_big);

    const int ITER = (NANCH + 1023) >> 10;

    if (t == 0) { s_pref = 0u; s_targ = PRE_NMS; s_cnt = 0u; }

    for (int p = 0; p < 4; ++p) {
        if (t < 256) s_hist[t] = 0u;
        __syncthreads();
        const unsigned int pref  = s_pref;
        const int          shift = 8 * (3 - p);
        const unsigned int pmask = (p == 0) ? 0u : (0xFFFFFFFFu << (shift + 8));
        for (int i = 0; i < ITER; ++i) {
            int  n     = (i << 10) + t;
            bool valid = (n < NANCH);
            unsigned int key = 0u;
            if (valid) key = __float_as_uint(probs2[n].y);
            bool match = valid && ((key & pmask) == (pref & pmask));
            hist_add_f(s_hist, (key >> shift) & 0xFFu, match);
        }
        __syncthreads();
        if (t == 0) {
            unsigned int target = s_targ;
            unsigned int acc = 0u;
            int v = 255;
            for (; v >= 0; --v) {
                unsigned int h = s_hist[v];
                if (acc + h >= target) break;
                acc += h;
            }
            if (v < 0) v = 0;
            s_pref = pref | ((unsigned int)v << shift);
            s_targ = target - acc;
        }
        __syncthreads();
    }

    const unsigned int T = s_pref;
    __syncthreads();

    for (int i = 0; i < ITER; ++i) {
        int  n     = (i << 10) + t;
        bool valid = (n < NANCH);
        unsigned int key = 0u;
        if (valid) key = __float_as_uint(probs2[n].y);
        bool selp = valid && (key >= T);
        ull  m    = __ballot(selp ? 1 : 0);
        if (m) {
            int leader = __ffsll(m) - 1;
            unsigned int base = 0u;
            if (lane == leader) base = atomicAdd(&s_cnt, (unsigned int)__popcll(m));
            base = __shfl(base, leader);
            if (selp) {
                unsigned int off = base + (unsigned int)__popcll(m & ((1ull << lane) - 1ull));
                if (off < SORTN) sel[off] = ((ull)(~key) << 32) | (ull)(unsigned int)n;
            }
        }
    }
    __syncthreads();
    const unsigned int C = s_cnt;
    for (int s = (int)C + t; s < SORTN; s += 1024) sel[s] = ~0ull;
    __syncthreads();

    for (unsigned int k = 2; k <= SORTN; k <<= 1) {
        for (unsigned int j = k >> 1; j > 0; j >>= 1) {
            #pragma unroll
            for (int r = 0; r < SORTN / 1024; ++r) {
                int i = (r << 10) + t;
                int l = i ^ (int)j;
                if (l > i) {
                    ull a  = sel[i];
                    ull bq = sel[l];
                    bool up = ((i & (int)k) == 0);
                    if ((a > bq) == up) { sel[i] = bq; sel[l] = a; }
                }
            }
            __syncthreads();
        }
    }

    ull ss[6];
    #pragma unroll
    for (int e = 0; e < 6; ++e) ss[e] = sel[(e << 10) + t];
    __syncthreads();

    float4 rbox[6];
    float  rarea[6];
    #pragma unroll
    for (int e = 0; e < 6; ++e) {
        int s = (e << 10) + t;
        float4 bx = make_float4(0.f, 0.f, 0.f, 0.f);
        bool ok = false;
        if (s < PRE_NMS) {
            unsigned int key = ~(unsigned int)(ss[e] >> 32);
            unsigned int n   = (unsigned int)(ss[e] & 0xFFFFFFFFull);
            float4 a = anc4[n];
            float4 d = bbox4[n];
            float dy = d.x * 0.1f, dx = d.y * 0.1f, dh = d.z * 0.2f, dw = d.w * 0.2f;
            float h  = a.z - a.x;
            float w  = a.w - a.y;
            float cy = a.x + 0.5f * h;
            float cx = a.y + 0.5f * w;
            cy = cy + dy * h;
            cx = cx + dx * w;
            h  = h * expf(dh);
            w  = w * expf(dw);
            float y1 = cy - 0.5f * h;
            float x1 = cx - 0.5f * w;
            float y2 = y1 + h;
            float x2 = x1 + w;
            y1 = fminf(fmaxf(y1, 0.f), 1.f);
            x1 = fminf(fmaxf(x1, 0.f), 1.f);
            y2 = fminf(fmaxf(y2, 0.f), 1.f);
            x2 = fminf(fmaxf(x2, 0.f), 1.f);
            bx = make_float4(y1, x1, y2, x2);
            ok = (key >= SCORE_THRES_BITS);
        }
        rbox[e]  = bx;
        rarea[e] = (bx.z - bx.x) * (bx.w - bx.y);
        boxes[s] = bx;
        ull am = __ballot(ok ? 1 : 0);
        if (lane == 0) s_alive[wv + (e << 4)] = am;
    }

    int emitted = 0;
    for (;;) {
        __syncthreads();
        if (emitted == PROP) break;
        ull w0 = s_alive[lane];
        ull w1 = (lane < 32) ? s_alive[64 + lane] : 0ull;
        ull nz0 = __ballot(w0 != 0ull ? 1 : 0);
        ull nz1 = __ballot(w1 != 0ull ? 1 : 0);
        int pick = -1;
        if (nz0) {
            int wd = __ffsll(nz0) - 1;
            ull wvv = __shfl(w0, wd);
            pick = (wd << 6) + __ffsll(wvv) - 1;
        } else if (nz1) {
            int wd = __ffsll(nz1) - 1;
            ull wvv = __shfl(w1, wd);
            pick = ((wd + 64) << 6) + __ffsll(wvv) - 1;
        }
        if (pick < 0) break;
        __syncthreads();

        if (t < 4) outb[(emitted << 2) + t] = reinterpret_cast<const float*>(s_big)[(pick << 2) + t];

        float4 p = boxes[pick];
        float parea = (p.z - p.x) * (p.w - p.y);
        #pragma unroll
        for (int e = 0; e < 6; ++e) {
            float4 bb  = rbox[e];
            float yy1 = fmaxf(p.x, bb.x);
            float xx1 = fmaxf(p.y, bb.y);
            float yy2 = fminf(p.z, bb.z);
            float xx2 = fminf(p.w, bb.w);
            float ih  = fmaxf(yy2 - yy1, 0.f);
            float iw  = fmaxf(xx2 - xx1, 0.f);
            float inter = ih * iw;
            float denom = ((parea + rarea[e]) - inter) + EPS_F;
            bool  sup   = ((double)inter > M_D * (double)denom);
            ull m = __ballot(sup ? 1 : 0);
            int word = wv + (e << 4);
            if (word == (pick >> 6)) m |= (1ull << (pick & 63));
            if (lane == 0) s_alive[word] &= ~m;
        }
        ++emitted;
    }

    for (int i = (emitted << 2) + t; i < PROP * 4; i += 1024) outb[i] = 0.f;
}

extern "C" void kernel_launch(void* const* d_in, const int* in_sizes, int n_in,
                              void* d_out, int out_size, void* d_ws, size_t ws_size,
                              hipStream_t stream) {
    const float* rpn_probs = (const float*)d_in[0];
    const float* rpn_bbox  = (const float*)d_in[1];
    const float* anchors   = (const float*)d_in[2];
    float* out = (float*)d_out;

    // ws layout:
    //   [0)        boxes   8*6144*16 = 786432
    //   [786432)   areas   8*6144*4  = 196608   -> ends 983040
    //   [983040)   ZERO region (one memset to MAT_OFF):
    //       alive  8*96*8 = 6144   @983040
    //       Tc     32 B            @989184
    //       done   32 B            @989440
    //       cntp   8*64*4 = 2048   @989696
    //       ghist  8*256*4 = 8192  @991744   -> ends 999936
    //   [1MiB)     mat (selbuf aliased at its head, consumed before mat write)
    const size_t BOX_OFF   = 0;
    const size_t AREA_OFF  = 786432;
    const size_t ZERO_OFF  = 983040;
    const size_t ALIVE_OFF = 983040;
    const size_t TC_OFF    = 989184;
    const size_t DONE_OFF  = 989440;
    const size_t CNT_OFF   = 989696;
    const size_t GHIST_OFF = 991744;
    const size_t MAT_OFF   = 1u << 20;
    const size_t SELB_OFF  = MAT_OFF;
    const size_t WS_NEED   = MAT_OFF + (size_t)BATCH * PRE_NMS * MROW * 8;     // ~37.9 MB

    if (d_ws != nullptr && ws_size >= WS_NEED) {
        char* ws = (char*)d_ws;
        float4* boxes_ws = (float4*)(ws + BOX_OFF);
        float*  area_ws  = (float*)(ws + AREA_OFF);
        ull*    alive_ws = (ull*)(ws + ALIVE_OFF);
        u32*    Tc       = (u32*)(ws + TC_OFF);
        u32*    done     = (u32*)(ws + DONE_OFF);
        u32*    cntp     = (u32*)(ws + CNT_OFF);
        u32*    ghist    = (u32*)(ws + GHIST_OFF);
        ull*    selbuf   = (ull*)(ws + SELB_OFF);
        ull*    mat      = (ull*)(ws + MAT_OFF);

        hipMemsetAsync(ws + ZERO_OFF, 0, MAT_OFF - ZERO_OFF, stream);  // alive..ghist
        hipLaunchKernelGGL(hist_kernel, dim3(CBLK, BATCH), dim3(256), 0, stream,
                           rpn_probs, ghist, done, Tc);
        hipLaunchKernelGGL(compact_kernel, dim3(CBLK, BATCH), dim3(256), 0, stream,
                           rpn_probs, Tc, selbuf, cntp);
        hipLaunchKernelGGL(rank_decode_kernel, dim3(SORTN / 256, BATCH), dim3(256), 0, stream,
                           rpn_bbox, anchors, selbuf, cntp, boxes_ws, area_ws, alive_ws);
        hipLaunchKernelGGL(iou_matrix_kernel, dim3(188, BATCH), dim3(1024), 0, stream,
                           boxes_ws, area_ws, mat);
        hipLaunchKernelGGL(nms_scan_kernel, dim3(BATCH), dim3(64), 0, stream,
                           boxes_ws, alive_ws, mat, out);
    } else {
        hipLaunchKernelGGL(proposal_fallback, dim3(BATCH), dim3(1024), 0, stream,
                           rpn_probs, rpn_bbox, anchors, out);
    }
}

// Round 3
// 307.228 us; speedup vs baseline: 1.5919x; 1.3072x over previous
//
#include <hip/hip_runtime.h>
#include <cstdint>
#include <cstddef>

#pragma clang fp contract(off)

#define BATCH    8
#define NANCH    261888
#define PRE_NMS  6000
#define PROP     1000
#define SORTN    8192
#define NSLOT    6144          /* 6 * 1024 */
#define MROW     96            /* u64 words per suppression row (94 used + 2 pad) */
#define NW       94            /* suppression words per batch (6000/64 rounded up) */
#define CHUNK_W  32            /* words computed+scanned in the fast first pass */
#define NPAIR    130944        /* NANCH / 2 */
#define CBLK     32            /* blocks per batch for hist/compact */
#define CPAIR    4092          /* NPAIR / CBLK */
#define KCAP     1024          /* compact LDS staging capacity */
#define SCORE_THRES_BITS 0x3F000000u   /* bits of 0.5f */
#define EPS_F    1e-8f
/* midpoint between pred(0.7f) and 0.7f = 23488101 * 2^-25, exact in double.
   RN(inter/denom) >= 0.7f  <=>  inter > M_D * denom  (exact: 25b x 24b product;
   tie rounds to even = pred(0.7f), so strict > is correct). */
#define M_D      0.6999999582767486572265625

typedef unsigned long long ull;
typedef unsigned int u32;

// ---------------------------------------------------------------------------
// Kernel A (fused hist + findT): fine histogram of scores >= 0.5 into 129
// bins; the LAST block per batch (done-counter) computes the coarse threshold.
// grid (32, BATCH) x 256.
// ---------------------------------------------------------------------------
__global__ __launch_bounds__(256)
void hist_kernel(const float* __restrict__ rpn_probs, u32* __restrict__ ghist,
                 u32* __restrict__ done, u32* __restrict__ Tc)
{
    __shared__ u32 h[129];
    __shared__ u32 s_old;
    const int t = threadIdx.x;
    const int b = blockIdx.y;
    if (t < 129) h[t] = 0u;
    __syncthreads();

    const float4* p4 = reinterpret_cast<const float4*>(rpn_probs + (size_t)b * NANCH * 2);
    const int p0 = blockIdx.x * CPAIR;
    for (int i = t; i < CPAIR; i += 256) {
        float4 v = p4[p0 + i];                 // scores of anchors 2p, 2p+1 in .y/.w
        u32 k0 = __float_as_uint(v.y);
        u32 k1 = __float_as_uint(v.w);
        if (k0 >= 0x3F000000u) atomicAdd(&h[min((k0 >> 16) - 0x3F00u, 128u)], 1u);
        if (k1 >= 0x3F000000u) atomicAdd(&h[min((k1 >> 16) - 0x3F00u, 128u)], 1u);
    }
    __syncthreads();
    if (t < 129 && h[t]) atomicAdd(&ghist[(b << 8) + t], h[t]);

    __threadfence();
    if (t == 0) s_old = atomicAdd(&done[b], 1u);
    __syncthreads();
    if (s_old == CBLK - 1) {
        // last block for this batch: all flushes are globally visible
        if (t < 129) h[t] = atomicAdd(&ghist[(b << 8) + t], 0u);   // coherent read
        __syncthreads();
        if (t == 0) {
            u32 run = 0; int bin = -1;
            for (int i = 128; i >= 0; --i) {
                run += h[i];
                if (run >= PRE_NMS) { bin = i; break; }
            }
            u32 T;
            if (bin < 0)         T = 0x3F000000u;   // unreachable (~131k scores >= 0.5)
            else if (bin == 128) T = 0x3F800000u;
            else                 T = 0x3F000000u + ((u32)bin << 16);
            Tc[b] = T;
        }
    }
}

// ---------------------------------------------------------------------------
// Kernel C: compact keys >= Tc[b] into selbuf. Block-local LDS staging +
// ONE padded global atomic per block. grid (32, BATCH) x 256.
// ---------------------------------------------------------------------------
__global__ __launch_bounds__(256)
void compact_kernel(const float* __restrict__ rpn_probs,
                    const u32* __restrict__ Tc,
                    ull* __restrict__ selbuf, u32* __restrict__ cntp)
{
    __shared__ ull kbuf[KCAP];
    __shared__ u32 s_n;
    __shared__ u32 s_base;
    const int t    = threadIdx.x;
    const int lane = t & 63;
    const int b    = blockIdx.y;
    const u32 T = Tc[b];
    if (t == 0) s_n = 0u;
    __syncthreads();

    const float4* p4 = reinterpret_cast<const float4*>(rpn_probs + (size_t)b * NANCH * 2);
    ull* sb = selbuf + (size_t)b * SORTN;
    const int p0 = blockIdx.x * CPAIR;

    for (int i = t; i < CPAIR; i += 256) {
        float4 v = p4[p0 + i];
        const int n0 = (p0 + i) << 1;
        #pragma unroll
        for (int e = 0; e < 2; ++e) {
            u32 k = __float_as_uint(e ? v.w : v.y);
            bool s0 = (k >= T);
            ull m = __ballot(s0 ? 1 : 0);
            if (!m) continue;                                  // wave-uniform
            int ldr = __ffsll(m) - 1;
            u32 base = 0;
            if (lane == ldr) base = atomicAdd(&s_n, (u32)__popcll(m));
            base = __shfl(base, ldr);
            u32 off = base + (u32)__popcll(m & ((1ull << lane) - 1ull));
            bool fit = s0 && (off < KCAP);
            if (fit) kbuf[off] = ((ull)(~k) << 32) | (ull)(u32)(n0 + e);
            ull sp = __ballot((s0 && !fit) ? 1 : 0);           // exact spill (unreachable)
            if (sp) {
                int l2 = __ffsll(sp) - 1;
                u32 gb = 0;
                if (lane == l2) gb = atomicAdd(&cntp[b << 6], (u32)__popcll(sp));
                gb = __shfl(gb, l2);
                if (s0 && !fit) {
                    u32 go = gb + (u32)__popcll(sp & ((1ull << lane) - 1ull));
                    if (go < SORTN) sb[go] = ((ull)(~k) << 32) | (ull)(u32)(n0 + e);
                }
            }
        }
    }
    __syncthreads();
    const u32 nn = min(s_n, (u32)KCAP);
    if (t == 0) s_base = atomicAdd(&cntp[b << 6], nn);
    __syncthreads();
    const u32 bs = s_base;
    for (u32 j = t; j < nn; j += 256) {
        u32 off = bs + j;
        if (off < SORTN) sb[off] = kbuf[j];
    }
}

// ---------------------------------------------------------------------------
// Kernel D: rank-scatter. slot(i) = #{j : comp_j < comp_i} — identical to
// ascending sort of the unique composite keys. Decode + scatter + area +
// alive atomicOr fused. grid (32, BATCH) x 256.
// ---------------------------------------------------------------------------
__global__ __launch_bounds__(256)
void rank_decode_kernel(const float* __restrict__ rpn_bbox,
                        const float* __restrict__ anchors,
                        const ull* __restrict__ selbuf,
                        const u32* __restrict__ cntp,
                        float4* __restrict__ boxes_ws,
                        float* __restrict__ area_ws,
                        ull* __restrict__ alive_ws)
{
    __shared__ ull tile[2048];   // 16 KB
    const int t = threadIdx.x;
    const int b = blockIdx.y;
    const u32 C = min(cntp[b << 6], (u32)SORTN);
    const ull* sb = selbuf + (size_t)b * SORTN;

    const int i = (blockIdx.x << 8) + t;
    const ull mykey = (i < (int)C) ? sb[i] : ~0ull;

    int rank = 0;
    for (u32 tb = 0; tb < C; tb += 2048) {
        const int m = (int)min((u32)2048, C - tb);
        __syncthreads();
        for (int j = t; j < m; j += 256) tile[j] = sb[tb + j];
        __syncthreads();
        int j = 0;
        for (; j + 8 <= m; j += 8) {
            #pragma unroll
            for (int u = 0; u < 8; ++u) rank += (tile[j + u] < mykey) ? 1 : 0;
        }
        for (; j < m; ++j) rank += (tile[j] < mykey) ? 1 : 0;
    }

    if (i < (int)C && rank < PRE_NMS) {
        const u32 key = ~(u32)(mykey >> 32);
        const u32 n   = (u32)(mykey & 0xFFFFFFFFull);
        const float4* bbox4 = reinterpret_cast<const float4*>(rpn_bbox + (size_t)b * NANCH * 4);
        const float4* anc4  = reinterpret_cast<const float4*>(anchors  + (size_t)b * NANCH * 4);
        float4 a = anc4[n];
        float4 d = bbox4[n];
        float dy = d.x * 0.1f, dx = d.y * 0.1f, dh = d.z * 0.2f, dw = d.w * 0.2f;
        float h  = a.z - a.x;
        float w  = a.w - a.y;
        float cy = a.x + 0.5f * h;
        float cx = a.y + 0.5f * w;
        cy = cy + dy * h;
        cx = cx + dx * w;
        h  = h * expf(dh);
        w  = w * expf(dw);
        float y1 = cy - 0.5f * h;
        float x1 = cx - 0.5f * w;
        float y2 = y1 + h;
        float x2 = x1 + w;
        y1 = fminf(fmaxf(y1, 0.f), 1.f);
        x1 = fminf(fmaxf(x1, 0.f), 1.f);
        y2 = fminf(fmaxf(y2, 0.f), 1.f);
        x2 = fminf(fmaxf(x2, 0.f), 1.f);
        boxes_ws[(size_t)b * NSLOT + rank] = make_float4(y1, x1, y2, x2);
        area_ws[(size_t)b * NSLOT + rank]  = (y2 - y1) * (x2 - x1);
        if (key >= SCORE_THRES_BITS) {
            atomicOr(&alive_ws[(size_t)b * MROW + (rank >> 6)], 1ull << (rank & 63));
        }
    }
}

// ---------------------------------------------------------------------------
// Kernel E (R12): chunked suppression bit-matrix, 4 rows per wave.
// One block = one 64-row word-block j of one batch (16 waves x 4 rows).
// Each column (box,area) LDS read is shared by 4 rows (4x less LDS traffic
// than R8's 1-row-per-wave version).
// Fast pass (flags==nullptr): grid (CHUNK_W, BATCH), computes rows 0..2047
//   over words j..CHUNK_W-1 only (8.5x less work than the full matrix; the
//   scan on this data terminates by word ~17).
// Guarded rest pass (flags!=nullptr): grid (NW, BATCH), exits per-batch if
//   the capped scan already finished; otherwise completes rows 0..2047
//   (words CHUNK_W..93) and rows 2048..5999 (words j..93).
// ---------------------------------------------------------------------------
__global__ __launch_bounds__(1024)
void iou_chunk_kernel(const float4* __restrict__ boxes_ws,
                      const float* __restrict__ area_ws,
                      ull* __restrict__ mat,
                      const u32* __restrict__ flags,
                      int kend)
{
    const int b = blockIdx.y;
    if (flags && flags[b]) return;        // fast-scan already finished this batch

    __shared__ float4 sbox[NSLOT];    // 96 KB
    __shared__ float  sarea[NSLOT];   // 24 KB

    const int j    = blockIdx.x;
    const int t    = threadIdx.x;
    const int lane = t & 63;
    const int wv   = t >> 6;

    const int kbeg = flags ? max(j, CHUNK_W) : j;
    const int base = j << 6;
    const int nst  = (kend << 6) - base;   // staged cols cover words kbeg..kend-1 (+rows)

    const float4* bws = boxes_ws + (size_t)b * NSLOT + base;
    const float*  aws = area_ws  + (size_t)b * NSLOT + base;
    for (int i = t; i < nst; i += 1024) { sbox[i] = bws[i]; sarea[i] = aws[i]; }
    __syncthreads();

    const int r0 = base + (wv << 2);       // first of this wave's 4 rows
    if (r0 >= PRE_NMS) return;             // only word-block 93's tail waves

    float4 P[4];
    float  PA[4];
    #pragma unroll
    for (int qi = 0; qi < 4; ++qi) { P[qi] = sbox[(wv << 2) + qi]; PA[qi] = sarea[(wv << 2) + qi]; }

    ull* rowp = mat + ((size_t)b * PRE_NMS + r0) * MROW;

    for (int k = kbeg; k < kend; ++k) {
        const int ci = ((k - j) << 6) + lane;
        const float4 qb = sbox[ci];
        const float  qa = sarea[ci];
        ull m[4];
        #pragma unroll
        for (int qi = 0; qi < 4; ++qi) {
            float yy1 = fmaxf(P[qi].x, qb.x);
            float xx1 = fmaxf(P[qi].y, qb.y);
            float yy2 = fminf(P[qi].z, qb.z);
            float xx2 = fminf(P[qi].w, qb.w);
            float inter = fmaxf(yy2 - yy1, 0.f) * fmaxf(xx2 - xx1, 0.f);
            float denom = ((PA[qi] + qa) - inter) + EPS_F;
            m[qi] = __ballot(((double)inter > M_D * (double)denom) ? 1 : 0);
        }
        if (k == j) {                       // diagonal word: mask away c <= r
            #pragma unroll
            for (int qi = 0; qi < 4; ++qi) {
                int sh = (wv << 2) + qi;
                ull keep = (sh == 63) ? 0ull : ((~0ull) << (sh + 1));
                m[qi] &= keep;
            }
        }
        if (lane == 0) {
            #pragma unroll
            for (int qi = 0; qi < 4; ++qi) rowp[(size_t)qi * MROW + k] = m[qi];
        }
    }
}

// ---------------------------------------------------------------------------
// Kernel F (R11/R12): word-walk greedy scan, lane-parallel pick resolution,
// LDS streaming prefetch. Templated:
//   nms_scan_t<CHUNK_W,true>  : capped scan over words 0..CHUNK_W-1; if it
//     reaches PROP picks it writes the output and sets flags[b]=1; otherwise
//     it returns silently (state discarded).
//   nms_scan_t<NW,false>      : guarded full re-scan (runs only if !flags[b]).
// vmcnt accounting: exactly ONE 48-load group per iteration (36 only for the
// ragged last word of the FULL scan); waits count precisely what may remain.
// ---------------------------------------------------------------------------
template<int NLOAD>
__device__ __forceinline__ void stream_word_n(const char* gbase, char* dst, int g, int lane)
{
    // rows g*64 .. g*64+63 are contiguous: 48 KB starting at gbase + g*49152.
    const char* src = gbase + (size_t)g * 49152 + (unsigned)(lane << 4);
    #pragma unroll
    for (int i = 0; i < NLOAD; ++i) {
        __builtin_amdgcn_global_load_lds(
            (const __attribute__((address_space(1))) void*)(src + (i << 10)),
            (__attribute__((address_space(3))) void*)(dst + (i << 10)),
            16, 0, 0);
    }
}

__device__ __forceinline__ ull shfl_xor64(ull x, int s)
{
    return (ull)__shfl_xor((long long)x, s, 64);
}

template<int CW, bool FIRST>
__global__ __launch_bounds__(64)
__attribute__((amdgpu_waves_per_eu(1, 1)))
void nms_scan_t(const float4* __restrict__ boxes_ws,
                const ull* __restrict__ alive_ws,
                const ull* __restrict__ mat,
                float* __restrict__ out,
                u32* __restrict__ flags)
{
    const int b    = blockIdx.x;
    if (!FIRST && flags[b]) return;        // fast pass already produced output

    const int lane = threadIdx.x;
    const int lc   = min(lane, 47);

    __shared__ ull sbuf[3][6144];    // 3 x 48 KB stream buffers
    __shared__ int picks[PROP];      // 4 KB   (total 147.9 KB < 160 KB)

    // lane l (<48) holds alive words 2l, 2l+1 (words 94,95 zero by construction)
    ull aw0 = 0, aw1 = 0;
    if (lane < 48) {
        const ull* aw = alive_ws + (size_t)b * MROW + 2 * lane;
        aw0 = aw[0]; aw1 = aw[1];
    }

    const ull* mb = mat + (size_t)b * PRE_NMS * MROW;
    const char* gbase = (const char*)mb;

    // prologue: stream words 0 and 1
    stream_word_n<48>(gbase, (char*)&sbuf[0][0], 0, lane);
    stream_word_n<48>(gbase, (char*)&sbuf[1][0], 1, lane);

    int cnt = 0;
    for (int k = 0; k < CW; ++k) {
        // wait for buffer k (exact count: newer-than-P(k) = P(k+1) only)
        if (k == CW - 1)                    asm volatile("s_waitcnt vmcnt(0)" ::: "memory");
        else if (CW == NW && k == NW - 2)   asm volatile("s_waitcnt vmcnt(36)" ::: "memory");
        else                                asm volatile("s_waitcnt vmcnt(48)" ::: "memory");
        __builtin_amdgcn_sched_barrier(0);

        const ull* dbuf = &sbuf[k % 3][0];

        // diag word for row k*64+lane, from the prefetched buffer (LDS).
        // Garbage bits (beyond-kend words, rank>=C rows) appear only at
        // positions of never-alive candidates; all uses mask by alive sets.
        ull diag_cur = dbuf[lane * 96 + k];

        // issue stream for word k+2 (the ONLY VMEM in the loop body)
        if (k + 2 < CW) {
            char* dst = (char*)&sbuf[(k + 2) % 3][0];
            if (CW == NW && k + 2 == NW - 1) stream_word_n<36>(gbase, dst, k + 2, lane);
            else                             stream_word_n<48>(gbase, dst, k + 2, lane);
        }

        const int src = k >> 1;
        const ull awk = (k & 1) ? aw1 : aw0;
        u32 wlo = (u32)__builtin_amdgcn_readlane((int)(u32)awk, src);
        u32 whi = (u32)__builtin_amdgcn_readlane((int)(u32)(awk >> 32), src);
        ull wval = ((ull)whi << 32) | (ull)wlo;

        if (wval != 0ull) {
            // ---- lane-parallel pick resolution for word k
            const bool rowAlive = (wval >> lane) & 1ull;
            ull P;  // picked set (uniform)
            // fast path: no alive candidate suppresses another alive candidate
            ull conflict = __ballot((rowAlive && ((diag_cur & wval) != 0ull)) ? 1 : 0);
            if (conflict == 0ull) {
                P = wval;
            } else {
                // transpose the 64x64 intra tile: T = "who suppresses me"
                ull T = diag_cur;
                {
                    ull y;
                    y = shfl_xor64(T, 32);
                    T = (lane & 32) ? ((T & 0xFFFFFFFF00000000ull) | ((y & 0xFFFFFFFF00000000ull) >> 32))
                                    : ((T & 0x00000000FFFFFFFFull) | ((y & 0x00000000FFFFFFFFull) << 32));
                    y = shfl_xor64(T, 16);
                    T = (lane & 16) ? ((T & 0xFFFF0000FFFF0000ull) | ((y & 0xFFFF0000FFFF0000ull) >> 16))
                                    : ((T & 0x0000FFFF0000FFFFull) | ((y & 0x0000FFFF0000FFFFull) << 16));
                    y = shfl_xor64(T, 8);
                    T = (lane & 8)  ? ((T & 0xFF00FF00FF00FF00ull) | ((y & 0xFF00FF00FF00FF00ull) >> 8))
                                    : ((T & 0x00FF00FF00FF00FFull) | ((y & 0x00FF00FF00FF00FFull) << 8));
                    y = shfl_xor64(T, 4);
                    T = (lane & 4)  ? ((T & 0xF0F0F0F0F0F0F0F0ull) | ((y & 0xF0F0F0F0F0F0F0F0ull) >> 4))
                                    : ((T & 0x0F0F0F0F0F0F0F0Full) | ((y & 0x0F0F0F0F0F0F0F0Full) << 4));
                    y = shfl_xor64(T, 2);
                    T = (lane & 2)  ? ((T & 0xCCCCCCCCCCCCCCCCull) | ((y & 0xCCCCCCCCCCCCCCCCull) >> 2))
                                    : ((T & 0x3333333333333333ull) | ((y & 0x3333333333333333ull) << 2));
                    y = shfl_xor64(T, 1);
                    T = (lane & 1)  ? ((T & 0xAAAAAAAAAAAAAAAAull) | ((y & 0xAAAAAAAAAAAAAAAAull) >> 1))
                                    : ((T & 0x5555555555555555ull) | ((y & 0x5555555555555555ull) << 1));
                }
                // iterative closure: accept all with no live suppressor,
                // kill their victims; repeat. Equals sequential greedy.
                ull A = wval;
                P = 0ull;
                while (A) {
                    const bool inA = (A >> lane) & 1ull;
                    ull D = __ballot((inA && ((T & A) == 0ull)) ? 1 : 0);
                    P |= D;
                    ull kill = __ballot((inA && ((T & D) != 0ull)) ? 1 : 0);
                    A &= ~(D | kill);
                }
            }

            // ---- ordered, PROP-capped parallel pick write
            const int total = __popcll(P);
            const int room  = PROP - cnt;
            const bool lanePicked = (P >> lane) & 1ull;
            const int myrank = __popcll(P & ((1ull << lane) - 1ull));
            if (lanePicked && myrank < room) picks[cnt + myrank] = (k << 6) + lane;
            cnt = (total >= room) ? PROP : (cnt + total);

            // ---- OR picked rows into alive regs, reading from the LDS buffer.
            // (skipped when cnt hit PROP: alive state is never used again)
            if (cnt < PROP) {
                const ulonglong2* bufv = reinterpret_cast<const ulonglong2*>(dbuf);
                ull tm = P;
                const int p0 = __ffsll(tm) - 1;     // pad slot (idempotent OR)
                while (tm) {
                    int idx[16];
                    #pragma unroll
                    for (int q = 0; q < 16; ++q) {
                        if (tm) { int p = __ffsll(tm) - 1; tm &= tm - 1ull; idx[q] = p; }
                        else idx[q] = p0;
                    }
                    ulonglong2 v[16];
                    #pragma unroll
                    for (int q = 0; q < 16; ++q) v[q] = bufv[idx[q] * 48 + lc];
                    ull rx = 0, ry = 0;
                    #pragma unroll
                    for (int q = 0; q < 16; ++q) { rx |= v[q].x; ry |= v[q].y; }
                    aw0 &= ~rx; aw1 &= ~ry;
                }
            }
        }

        // word k fully consumed
        if (lane == (k >> 1)) { if (k & 1) aw1 = 0ull; else aw0 = 0ull; }
        if (cnt == PROP) break;
    }

    // drain any outstanding LDS-DMA before workgroup teardown
    asm volatile("s_waitcnt vmcnt(0)" ::: "memory");
    __syncthreads();

    if (FIRST) {
        if (cnt != PROP) return;           // fallback passes will handle this batch
        if (lane == 0) flags[b] = 1u;
    }

    const float4* bws = boxes_ws + (size_t)b * NSLOT;
    float4* ob = reinterpret_cast<float4*>(out + (size_t)b * PROP * 4);
    for (int i = lane; i < PROP; i += 64) {
        float4 v = make_float4(0.f, 0.f, 0.f, 0.f);
        if (i < cnt) v = bws[picks[i]];
        ob[i] = v;
    }
}

// ---------------------------------------------------------------------------
// Fallback: round-1 monolithic kernel (used if ws too small). Verified exact.
// ---------------------------------------------------------------------------
__device__ __forceinline__ void hist_add_f(unsigned int* hist, unsigned int bin, bool valid) {
    const int lane = threadIdx.x & 63;
    ull todo = __ballot(valid ? 1 : 0);
    #pragma unroll
    for (int it = 0; it < 3; ++it) {
        if (!todo) return;
        int leader = __ffsll(todo) - 1;
        unsigned int lbin = __shfl(bin, leader);
        ull grp = __ballot((valid && (bin == lbin)) ? 1 : 0);
        if (lane == leader) atomicAdd(&hist[lbin], (unsigned int)__popcll(grp));
        todo &= ~grp;
    }
    if ((todo >> lane) & 1ull) atomicAdd(&hist[bin], 1u);
}

__global__ __launch_bounds__(1024)
void proposal_fallback(const float* __restrict__ rpn_probs,
                       const float* __restrict__ rpn_bbox,
                       const float* __restrict__ anchors,
                       float* __restrict__ out)
{
    const int b    = blockIdx.x;
    const int t    = threadIdx.x;
    const int lane = t & 63;
    const int wv   = t >> 6;

    const float2* __restrict__ probs2 = reinterpret_cast<const float2*>(rpn_probs + (size_t)b * NANCH * 2);
    const float4* __restrict__ bbox4  = reinterpret_cast<const float4*>(rpn_bbox  + (size_t)b * NANCH * 4);
    const float4* __restrict__ anc4   = reinterpret_cast<const float4*>(anchors   + (size_t)b * NANCH * 4);
    float* __restrict__ outb = out + (size_t)b * PROP * 4;

    __shared__ __align__(16) char s_big[NSLOT * 16];
    __shared__ ull          s_alive[96];
    __shared__ unsigned int s_hist[256];
    __shared__ unsigned int s_pref;
    __shared__ unsigned int s_targ;
    __shared__ unsigned int s_cnt;

    ull*    sel   = reinterpret_cast<ull*>(s_big);
    float4* boxes = reinterpret_cast<float4*>(s_big);

    const int ITER = (NANCH + 1023) >> 10;

    if (t == 0) { s_pref = 0u; s_targ = PRE_NMS; s_cnt = 0u; }

    for (int p = 0; p < 4; ++p) {
        if (t < 256) s_hist[t] = 0u;
        __syncthreads();
        const unsigned int pref  = s_pref;
        const int          shift = 8 * (3 - p);
        const unsigned int pmask = (p == 0) ? 0u : (0xFFFFFFFFu << (shift + 8));
        for (int i = 0; i < ITER; ++i) {
            int  n     = (i << 10) + t;
            bool valid = (n < NANCH);
            unsigned int key = 0u;
            if (valid) key = __float_as_uint(probs2[n].y);
            bool match = valid && ((key & pmask) == (pref & pmask));
            hist_add_f(s_hist, (key >> shift) & 0xFFu, match);
        }
        __syncthreads();
        if (t == 0) {
            unsigned int target = s_targ;
            unsigned int acc = 0u;
            int v = 255;
            for (; v >= 0; --v) {
                unsigned int h = s_hist[v];
                if (acc + h >= target) break;
                acc += h;
            }
            if (v < 0) v = 0;
            s_pref = pref | ((unsigned int)v << shift);
            s_targ = target - acc;
        }
        __syncthreads();
    }

    const unsigned int T = s_pref;
    __syncthreads();

    for (int i = 0; i < ITER; ++i) {
        int  n     = (i << 10) + t;
        bool valid = (n < NANCH);
        unsigned int key = 0u;
        if (valid) key = __float_as_uint(probs2[n].y);
        bool selp = valid && (key >= T);
        ull  m    = __ballot(selp ? 1 : 0);
        if (m) {
            int leader = __ffsll(m) - 1;
            unsigned int base = 0u;
            if (lane == leader) base = atomicAdd(&s_cnt, (unsigned int)__popcll(m));
            base = __shfl(base, leader);
            if (selp) {
                unsigned int off = base + (unsigned int)__popcll(m & ((1ull << lane) - 1ull));
                if (off < SORTN) sel[off] = ((ull)(~key) << 32) | (ull)(unsigned int)n;
            }
        }
    }
    __syncthreads();
    const unsigned int C = s_cnt;
    for (int s = (int)C + t; s < SORTN; s += 1024) sel[s] = ~0ull;
    __syncthreads();

    for (unsigned int k = 2; k <= SORTN; k <<= 1) {
        for (unsigned int j = k >> 1; j > 0; j >>= 1) {
            #pragma unroll
            for (int r = 0; r < SORTN / 1024; ++r) {
                int i = (r << 10) + t;
                int l = i ^ (int)j;
                if (l > i) {
                    ull a  = sel[i];
                    ull bq = sel[l];
                    bool up = ((i & (int)k) == 0);
                    if ((a > bq) == up) { sel[i] = bq; sel[l] = a; }
                }
            }
            __syncthreads();
        }
    }

    ull ss[6];
    #pragma unroll
    for (int e = 0; e < 6; ++e) ss[e] = sel[(e << 10) + t];
    __syncthreads();

    float4 rbox[6];
    float  rarea[6];
    #pragma unroll
    for (int e = 0; e < 6; ++e) {
        int s = (e << 10) + t;
        float4 bx = make_float4(0.f, 0.f, 0.f, 0.f);
        bool ok = false;
        if (s < PRE_NMS) {
            unsigned int key = ~(unsigned int)(ss[e] >> 32);
            unsigned int n   = (unsigned int)(ss[e] & 0xFFFFFFFFull);
            float4 a = anc4[n];
            float4 d = bbox4[n];
            float dy = d.x * 0.1f, dx = d.y * 0.1f, dh = d.z * 0.2f, dw = d.w * 0.2f;
            float h  = a.z - a.x;
            float w  = a.w - a.y;
            float cy = a.x + 0.5f * h;
            float cx = a.y + 0.5f * w;
            cy = cy + dy * h;
            cx = cx + dx * w;
            h  = h * expf(dh);
            w  = w * expf(dw);
            float y1 = cy - 0.5f * h;
            float x1 = cx - 0.5f * w;
            float y2 = y1 + h;
            float x2 = x1 + w;
            y1 = fminf(fmaxf(y1, 0.f), 1.f);
            x1 = fminf(fmaxf(x1, 0.f), 1.f);
            y2 = fminf(fmaxf(y2, 0.f), 1.f);
            x2 = fminf(fmaxf(x2, 0.f), 1.f);
            bx = make_float4(y1, x1, y2, x2);
            ok = (key >= SCORE_THRES_BITS);
        }
        rbox[e]  = bx;
        rarea[e] = (bx.z - bx.x) * (bx.w - bx.y);
        boxes[s] = bx;
        ull am = __ballot(ok ? 1 : 0);
        if (lane == 0) s_alive[wv + (e << 4)] = am;
    }

    int emitted = 0;
    for (;;) {
        __syncthreads();
        if (emitted == PROP) break;
        ull w0 = s_alive[lane];
        ull w1 = (lane < 32) ? s_alive[64 + lane] : 0ull;
        ull nz0 = __ballot(w0 != 0ull ? 1 : 0);
        ull nz1 = __ballot(w1 != 0ull ? 1 : 0);
        int pick = -1;
        if (nz0) {
            int wd = __ffsll(nz0) - 1;
            ull wvv = __shfl(w0, wd);
            pick = (wd << 6) + __ffsll(wvv) - 1;
        } else if (nz1) {
            int wd = __ffsll(nz1) - 1;
            ull wvv = __shfl(w1, wd);
            pick = ((wd + 64) << 6) + __ffsll(wvv) - 1;
        }
        if (pick < 0) break;
        __syncthreads();

        if (t < 4) outb[(emitted << 2) + t] = reinterpret_cast<const float*>(s_big)[(pick << 2) + t];

        float4 p = boxes[pick];
        float parea = (p.z - p.x) * (p.w - p.y);
        #pragma unroll
        for (int e = 0; e < 6; ++e) {
            float4 bb  = rbox[e];
            float yy1 = fmaxf(p.x, bb.x);
            float xx1 = fmaxf(p.y, bb.y);
            float yy2 = fminf(p.z, bb.z);
            float xx2 = fminf(p.w, bb.w);
            float ih  = fmaxf(yy2 - yy1, 0.f);
            float iw  = fmaxf(xx2 - xx1, 0.f);
            float inter = ih * iw;
            float denom = ((parea + rarea[e]) - inter) + EPS_F;
            bool  sup   = ((double)inter > M_D * (double)denom);
            ull m = __ballot(sup ? 1 : 0);
            int word = wv + (e << 4);
            if (word == (pick >> 6)) m |= (1ull << (pick & 63));
            if (lane == 0) s_alive[word] &= ~m;
        }
        ++emitted;
    }

    for (int i = (emitted << 2) + t; i < PROP * 4; i += 1024) outb[i] = 0.f;
}

extern "C" void kernel_launch(void* const* d_in, const int* in_sizes, int n_in,
                              void* d_out, int out_size, void* d_ws, size_t ws_size,
                              hipStream_t stream) {
    const float* rpn_probs = (const float*)d_in[0];
    const float* rpn_bbox  = (const float*)d_in[1];
    const float* anchors   = (const float*)d_in[2];
    float* out = (float*)d_out;

    // ws layout:
    //   [0)        boxes   8*6144*16 = 786432
    //   [786432)   areas   8*6144*4  = 196608   -> ends 983040
    //   [983040)   ZERO region (one memset to MAT_OFF):
    //       alive  8*96*8 = 6144   @983040
    //       Tc     32 B            @989184
    //       done   32 B            @989440
    //       cntp   8*64*4 = 2048   @989696
    //       ghist  8*256*4 = 8192  @991744   -> ends 999936
    //       flags  8*4 = 32 B      @999936   (fast-scan done flags)
    //   [1MiB)     mat (selbuf aliased at its head, consumed before mat write)
    const size_t BOX_OFF   = 0;
    const size_t AREA_OFF  = 786432;
    const size_t ZERO_OFF  = 983040;
    const size_t ALIVE_OFF = 983040;
    const size_t TC_OFF    = 989184;
    const size_t DONE_OFF  = 989440;
    const size_t CNT_OFF   = 989696;
    const size_t GHIST_OFF = 991744;
    const size_t FLAG_OFF  = 999936;
    const size_t MAT_OFF   = 1u << 20;
    const size_t SELB_OFF  = MAT_OFF;
    const size_t WS_NEED   = MAT_OFF + (size_t)BATCH * PRE_NMS * MROW * 8;     // ~37.9 MB

    if (d_ws != nullptr && ws_size >= WS_NEED) {
        char* ws = (char*)d_ws;
        float4* boxes_ws = (float4*)(ws + BOX_OFF);
        float*  area_ws  = (float*)(ws + AREA_OFF);
        ull*    alive_ws = (ull*)(ws + ALIVE_OFF);
        u32*    Tc       = (u32*)(ws + TC_OFF);
        u32*    done     = (u32*)(ws + DONE_OFF);
        u32*    cntp     = (u32*)(ws + CNT_OFF);
        u32*    ghist    = (u32*)(ws + GHIST_OFF);
        u32*    flags    = (u32*)(ws + FLAG_OFF);
        ull*    selbuf   = (ull*)(ws + SELB_OFF);
        ull*    mat      = (ull*)(ws + MAT_OFF);

        hipMemsetAsync(ws + ZERO_OFF, 0, MAT_OFF - ZERO_OFF, stream);  // alive..flags
        hipLaunchKernelGGL(hist_kernel, dim3(CBLK, BATCH), dim3(256), 0, stream,
                           rpn_probs, ghist, done, Tc);
        hipLaunchKernelGGL(compact_kernel, dim3(CBLK, BATCH), dim3(256), 0, stream,
                           rpn_probs, Tc, selbuf, cntp);
        hipLaunchKernelGGL(rank_decode_kernel, dim3(SORTN / 256, BATCH), dim3(256), 0, stream,
                           rpn_bbox, anchors, selbuf, cntp, boxes_ws, area_ws, alive_ws);
        // fast pass: words 0..CHUNK_W-1 of rows 0..CHUNK_W*64-1, then capped scan
        hipLaunchKernelGGL(iou_chunk_kernel, dim3(CHUNK_W, BATCH), dim3(1024), 0, stream,
                           boxes_ws, area_ws, mat, (const u32*)nullptr, CHUNK_W);
        hipLaunchKernelGGL((nms_scan_t<CHUNK_W, true>), dim3(BATCH), dim3(64), 0, stream,
                           boxes_ws, alive_ws, mat, out, flags);
        // guarded completion (expected no-op): rest of the matrix + full re-scan
        hipLaunchKernelGGL(iou_chunk_kernel, dim3(NW, BATCH), dim3(1024), 0, stream,
                           boxes_ws, area_ws, mat, (const u32*)flags, NW);
        hipLaunchKernelGGL((nms_scan_t<NW, false>), dim3(BATCH), dim3(64), 0, stream,
                           boxes_ws, alive_ws, mat, out, flags);
    } else {
        hipLaunchKernelGGL(proposal_fallback, dim3(BATCH), dim3(1024), 0, stream,
                           rpn_probs, rpn_bbox, anchors, out);
    }
}

// Round 4
// 280.955 us; speedup vs baseline: 1.7407x; 1.0935x over previous
//
#include <hip/hip_runtime.h>
#include <cstdint>
#include <cstddef>

#pragma clang fp contract(off)

#define BATCH    8
#define NANCH    261888
#define PRE_NMS  6000
#define PROP     1000
#define SORTN    8192
#define NSLOT    6144          /* 6 * 1024 */
#define MROW     96            /* u64 words per suppression row (94 used + 2 pad) */
#define NW       94            /* suppression words per batch (6000/64 rounded up) */
#define CHUNK_W  32            /* words computed+scanned in the fast first pass */
#define NPAIR    130944        /* NANCH / 2 */
#define CBLK     32            /* blocks per batch for hist/compact */
#define CPAIR    4092          /* NPAIR / CBLK */
#define SCORE_THRES_BITS 0x3F000000u   /* bits of 0.5f */
#define EPS_F    1e-8f
/* midpoint between pred(0.7f) and 0.7f = 23488101 * 2^-25, exact in double.
   RN(inter/denom) >= 0.7f  <=>  inter > M_D * denom  (exact: 25b x 24b product;
   tie rounds to even = pred(0.7f), so strict > is correct). */
#define M_D      0.6999999582767486572265625

typedef unsigned long long ull;
typedef unsigned int u32;

// ---------------------------------------------------------------------------
// Kernel A (fused hist + findT + binbase): fine histogram of scores >= 0.5
// into 129 bins; the LAST block per batch (done-counter) computes the coarse
// threshold, the per-bin rank bases (suffix sums), and the total count C.
// grid (32, BATCH) x 256.
// ---------------------------------------------------------------------------
__global__ __launch_bounds__(256)
void hist_kernel(const float* __restrict__ rpn_probs, u32* __restrict__ ghist,
                 u32* __restrict__ done, u32* __restrict__ Tc,
                 u32* __restrict__ binbase, u32* __restrict__ cntp)
{
    __shared__ u32 h[129];
    __shared__ u32 s_old;
    const int t = threadIdx.x;
    const int b = blockIdx.y;
    if (t < 129) h[t] = 0u;
    __syncthreads();

    const float4* p4 = reinterpret_cast<const float4*>(rpn_probs + (size_t)b * NANCH * 2);
    const int p0 = blockIdx.x * CPAIR;
    for (int i = t; i < CPAIR; i += 256) {
        float4 v = p4[p0 + i];                 // scores of anchors 2p, 2p+1 in .y/.w
        u32 k0 = __float_as_uint(v.y);
        u32 k1 = __float_as_uint(v.w);
        if (k0 >= 0x3F000000u) atomicAdd(&h[min((k0 >> 16) - 0x3F00u, 128u)], 1u);
        if (k1 >= 0x3F000000u) atomicAdd(&h[min((k1 >> 16) - 0x3F00u, 128u)], 1u);
    }
    __syncthreads();
    if (t < 129 && h[t]) atomicAdd(&ghist[(b << 8) + t], h[t]);

    __threadfence();
    if (t == 0) s_old = atomicAdd(&done[b], 1u);
    __syncthreads();
    if (s_old == CBLK - 1) {
        // last block for this batch: all flushes are globally visible
        if (t < 129) h[t] = atomicAdd(&ghist[(b << 8) + t], 0u);   // coherent read
        __syncthreads();
        if (t == 0) {
            u32* bb = binbase + b * 132;
            u32 run = 0; int binT = -1; u32 Cv = 0;
            for (int i = 128; i >= 0; --i) {
                bb[i] = run;                    // # keys in bins strictly above i
                run += h[i];
                if (binT < 0 && run >= PRE_NMS) { binT = i; Cv = run; }
            }
            u32 T;
            if (binT < 0)         { T = 0x3F000000u; Cv = run; }  // all >=0.5 (unreachable)
            else if (binT == 128)   T = 0x3F800000u;
            else                    T = 0x3F000000u + ((u32)binT << 16);
            Tc[b] = T;
            cntp[b << 6] = Cv;
        }
    }
}

// ---------------------------------------------------------------------------
// Kernel C (R13): bucketed compact. Each key >= Tc[b] scatters directly into
// its score-bin's segment of selbuf: pos = binbase[bin] + atomic(bincnt[bin]).
// selbuf becomes bin-partitioned (bins in descending-score = ascending-rank
// order), enabling within-bin-only ranking. grid (32, BATCH) x 256.
// ---------------------------------------------------------------------------
__global__ __launch_bounds__(256)
void compact_kernel(const float* __restrict__ rpn_probs,
                    const u32* __restrict__ Tc,
                    const u32* __restrict__ binbase,
                    u32* __restrict__ bincnt,
                    ull* __restrict__ selbuf)
{
    const int t = threadIdx.x;
    const int b = blockIdx.y;
    const u32 T = Tc[b];
    const u32* bb = binbase + b * 132;
    u32* bc = bincnt + b * 132;

    const float4* p4 = reinterpret_cast<const float4*>(rpn_probs + (size_t)b * NANCH * 2);
    ull* sb = selbuf + (size_t)b * SORTN;
    const int p0 = blockIdx.x * CPAIR;

    for (int i = t; i < CPAIR; i += 256) {
        float4 v = p4[p0 + i];
        const int n0 = (p0 + i) << 1;
        #pragma unroll
        for (int e = 0; e < 2; ++e) {
            u32 k = __float_as_uint(e ? v.w : v.y);
            if (k >= T) {
                u32 bin = min((k >> 16) - 0x3F00u, 128u);
                u32 pos = bb[bin] + atomicAdd(&bc[bin], 1u);
                if (pos < SORTN) sb[pos] = ((ull)(~k) << 32) | (ull)(u32)(n0 + e);
            }
        }
    }
}

// ---------------------------------------------------------------------------
// Kernel D (R13): bucketed rank + decode + scatter. rank = binbase[bin] +
// #{y in same bin : key_y < key_x}; within-bin slice is ~50-700 keys (vs C ~
// 6500 all-pairs before) and the slice reads are wave-uniform (broadcast L1).
// grid (32, BATCH) x 256.
// ---------------------------------------------------------------------------
__global__ __launch_bounds__(256)
void rank_decode_kernel(const float* __restrict__ rpn_bbox,
                        const float* __restrict__ anchors,
                        const ull* __restrict__ selbuf,
                        const u32* __restrict__ cntp,
                        const u32* __restrict__ binbase,
                        const u32* __restrict__ ghist,
                        float4* __restrict__ boxes_ws,
                        float* __restrict__ area_ws,
                        ull* __restrict__ alive_ws)
{
    const int t = threadIdx.x;
    const int b = blockIdx.y;
    const u32 C = min(cntp[b << 6], (u32)SORTN);
    const ull* sb = selbuf + (size_t)b * SORTN;

    const int i = (blockIdx.x << 8) + t;
    if (i >= (int)C) return;

    const ull mykey = sb[i];
    const u32 key = ~(u32)(mykey >> 32);
    const u32 n   = (u32)(mykey & 0xFFFFFFFFull);
    const u32 bin = min((key >> 16) - 0x3F00u, 128u);
    const u32 lo  = binbase[b * 132 + bin];
    const u32 cb  = min(ghist[(b << 8) + bin], (u32)SORTN - lo);  // bin size (clamped)

    const ull* base = sb + lo;
    int local = 0;
    u32 j = 0;
    for (; j + 8 <= cb; j += 8) {
        #pragma unroll
        for (int u = 0; u < 8; ++u) local += (base[j + u] < mykey) ? 1 : 0;
    }
    for (; j < cb; ++j) local += (base[j] < mykey) ? 1 : 0;
    const int rank = (int)lo + local;

    if (rank < PRE_NMS) {
        const float4* bbox4 = reinterpret_cast<const float4*>(rpn_bbox + (size_t)b * NANCH * 4);
        const float4* anc4  = reinterpret_cast<const float4*>(anchors  + (size_t)b * NANCH * 4);
        float4 a = anc4[n];
        float4 d = bbox4[n];
        float dy = d.x * 0.1f, dx = d.y * 0.1f, dh = d.z * 0.2f, dw = d.w * 0.2f;
        float h  = a.z - a.x;
        float w  = a.w - a.y;
        float cy = a.x + 0.5f * h;
        float cx = a.y + 0.5f * w;
        cy = cy + dy * h;
        cx = cx + dx * w;
        h  = h * expf(dh);
        w  = w * expf(dw);
        float y1 = cy - 0.5f * h;
        float x1 = cx - 0.5f * w;
        float y2 = y1 + h;
        float x2 = x1 + w;
        y1 = fminf(fmaxf(y1, 0.f), 1.f);
        x1 = fminf(fmaxf(x1, 0.f), 1.f);
        y2 = fminf(fmaxf(y2, 0.f), 1.f);
        x2 = fminf(fmaxf(x2, 0.f), 1.f);
        boxes_ws[(size_t)b * NSLOT + rank] = make_float4(y1, x1, y2, x2);
        area_ws[(size_t)b * NSLOT + rank]  = (y2 - y1) * (x2 - x1);
        if (key >= SCORE_THRES_BITS) {
            atomicOr(&alive_ws[(size_t)b * MROW + (rank >> 6)], 1ull << (rank & 63));
        }
    }
}

// ---------------------------------------------------------------------------
// Kernel E (R12): chunked suppression bit-matrix, 4 rows per wave.
// Fast pass (flags==nullptr): grid (CHUNK_W, BATCH), rows 0..2047 over words
//   j..CHUNK_W-1 only. Guarded rest pass (flags!=nullptr): grid (NW, BATCH),
//   per-batch early exit when the capped scan already finished.
// ---------------------------------------------------------------------------
__global__ __launch_bounds__(1024)
void iou_chunk_kernel(const float4* __restrict__ boxes_ws,
                      const float* __restrict__ area_ws,
                      ull* __restrict__ mat,
                      const u32* __restrict__ flags,
                      int kend)
{
    const int b = blockIdx.y;
    if (flags && flags[b]) return;        // fast-scan already finished this batch

    __shared__ float4 sbox[NSLOT];    // 96 KB
    __shared__ float  sarea[NSLOT];   // 24 KB

    const int j    = blockIdx.x;
    const int t    = threadIdx.x;
    const int lane = t & 63;
    const int wv   = t >> 6;

    const int kbeg = flags ? max(j, CHUNK_W) : j;
    const int base = j << 6;
    const int nst  = (kend << 6) - base;   // staged cols cover words kbeg..kend-1 (+rows)

    const float4* bws = boxes_ws + (size_t)b * NSLOT + base;
    const float*  aws = area_ws  + (size_t)b * NSLOT + base;
    for (int i = t; i < nst; i += 1024) { sbox[i] = bws[i]; sarea[i] = aws[i]; }
    __syncthreads();

    const int r0 = base + (wv << 2);       // first of this wave's 4 rows
    if (r0 >= PRE_NMS) return;             // only word-block 93's tail waves

    float4 P[4];
    float  PA[4];
    #pragma unroll
    for (int qi = 0; qi < 4; ++qi) { P[qi] = sbox[(wv << 2) + qi]; PA[qi] = sarea[(wv << 2) + qi]; }

    ull* rowp = mat + ((size_t)b * PRE_NMS + r0) * MROW;

    for (int k = kbeg; k < kend; ++k) {
        const int ci = ((k - j) << 6) + lane;
        const float4 qb = sbox[ci];
        const float  qa = sarea[ci];
        ull m[4];
        #pragma unroll
        for (int qi = 0; qi < 4; ++qi) {
            float yy1 = fmaxf(P[qi].x, qb.x);
            float xx1 = fmaxf(P[qi].y, qb.y);
            float yy2 = fminf(P[qi].z, qb.z);
            float xx2 = fminf(P[qi].w, qb.w);
            float inter = fmaxf(yy2 - yy1, 0.f) * fmaxf(xx2 - xx1, 0.f);
            float denom = ((PA[qi] + qa) - inter) + EPS_F;
            m[qi] = __ballot(((double)inter > M_D * (double)denom) ? 1 : 0);
        }
        if (k == j) {                       // diagonal word: mask away c <= r
            #pragma unroll
            for (int qi = 0; qi < 4; ++qi) {
                int sh = (wv << 2) + qi;
                ull keep = (sh == 63) ? 0ull : ((~0ull) << (sh + 1));
                m[qi] &= keep;
            }
        }
        if (lane == 0) {
            #pragma unroll
            for (int qi = 0; qi < 4; ++qi) rowp[(size_t)qi * MROW + k] = m[qi];
        }
    }
}

// ---------------------------------------------------------------------------
// Kernel F (R11/R12): word-walk greedy scan, lane-parallel pick resolution,
// LDS streaming prefetch. Templated:
//   nms_scan_t<CHUNK_W,true>  : capped scan; on success writes output + flag.
//   nms_scan_t<NW,false>      : guarded full re-scan (runs only if !flags[b]).
// ---------------------------------------------------------------------------
template<int NLOAD>
__device__ __forceinline__ void stream_word_n(const char* gbase, char* dst, int g, int lane)
{
    // rows g*64 .. g*64+63 are contiguous: 48 KB starting at gbase + g*49152.
    const char* src = gbase + (size_t)g * 49152 + (unsigned)(lane << 4);
    #pragma unroll
    for (int i = 0; i < NLOAD; ++i) {
        __builtin_amdgcn_global_load_lds(
            (const __attribute__((address_space(1))) void*)(src + (i << 10)),
            (__attribute__((address_space(3))) void*)(dst + (i << 10)),
            16, 0, 0);
    }
}

__device__ __forceinline__ ull shfl_xor64(ull x, int s)
{
    return (ull)__shfl_xor((long long)x, s, 64);
}

template<int CW, bool FIRST>
__global__ __launch_bounds__(64)
__attribute__((amdgpu_waves_per_eu(1, 1)))
void nms_scan_t(const float4* __restrict__ boxes_ws,
                const ull* __restrict__ alive_ws,
                const ull* __restrict__ mat,
                float* __restrict__ out,
                u32* __restrict__ flags)
{
    const int b    = blockIdx.x;
    if (!FIRST && flags[b]) return;        // fast pass already produced output

    const int lane = threadIdx.x;
    const int lc   = min(lane, 47);

    __shared__ ull sbuf[3][6144];    // 3 x 48 KB stream buffers
    __shared__ int picks[PROP];      // 4 KB   (total 147.9 KB < 160 KB)

    // lane l (<48) holds alive words 2l, 2l+1 (words 94,95 zero by construction)
    ull aw0 = 0, aw1 = 0;
    if (lane < 48) {
        const ull* aw = alive_ws + (size_t)b * MROW + 2 * lane;
        aw0 = aw[0]; aw1 = aw[1];
    }

    const ull* mb = mat + (size_t)b * PRE_NMS * MROW;
    const char* gbase = (const char*)mb;

    // prologue: stream words 0 and 1
    stream_word_n<48>(gbase, (char*)&sbuf[0][0], 0, lane);
    stream_word_n<48>(gbase, (char*)&sbuf[1][0], 1, lane);

    int cnt = 0;
    for (int k = 0; k < CW; ++k) {
        // wait for buffer k (exact count: newer-than-P(k) = P(k+1) only)
        if (k == CW - 1)                    asm volatile("s_waitcnt vmcnt(0)" ::: "memory");
        else if (CW == NW && k == NW - 2)   asm volatile("s_waitcnt vmcnt(36)" ::: "memory");
        else                                asm volatile("s_waitcnt vmcnt(48)" ::: "memory");
        __builtin_amdgcn_sched_barrier(0);

        const ull* dbuf = &sbuf[k % 3][0];

        // diag word for row k*64+lane, from the prefetched buffer (LDS).
        // Garbage bits (beyond-kend words, rank>=C rows) appear only at
        // positions of never-alive candidates; all uses mask by alive sets.
        ull diag_cur = dbuf[lane * 96 + k];

        // issue stream for word k+2 (the ONLY VMEM in the loop body)
        if (k + 2 < CW) {
            char* dst = (char*)&sbuf[(k + 2) % 3][0];
            if (CW == NW && k + 2 == NW - 1) stream_word_n<36>(gbase, dst, k + 2, lane);
            else                             stream_word_n<48>(gbase, dst, k + 2, lane);
        }

        const int src = k >> 1;
        const ull awk = (k & 1) ? aw1 : aw0;
        u32 wlo = (u32)__builtin_amdgcn_readlane((int)(u32)awk, src);
        u32 whi = (u32)__builtin_amdgcn_readlane((int)(u32)(awk >> 32), src);
        ull wval = ((ull)whi << 32) | (ull)wlo;

        if (wval != 0ull) {
            // ---- lane-parallel pick resolution for word k
            const bool rowAlive = (wval >> lane) & 1ull;
            ull P;  // picked set (uniform)
            // fast path: no alive candidate suppresses another alive candidate
            ull conflict = __ballot((rowAlive && ((diag_cur & wval) != 0ull)) ? 1 : 0);
            if (conflict == 0ull) {
                P = wval;
            } else {
                // transpose the 64x64 intra tile: T = "who suppresses me"
                ull T = diag_cur;
                {
                    ull y;
                    y = shfl_xor64(T, 32);
                    T = (lane & 32) ? ((T & 0xFFFFFFFF00000000ull) | ((y & 0xFFFFFFFF00000000ull) >> 32))
                                    : ((T & 0x00000000FFFFFFFFull) | ((y & 0x00000000FFFFFFFFull) << 32));
                    y = shfl_xor64(T, 16);
                    T = (lane & 16) ? ((T & 0xFFFF0000FFFF0000ull) | ((y & 0xFFFF0000FFFF0000ull) >> 16))
                                    : ((T & 0x0000FFFF0000FFFFull) | ((y & 0x0000FFFF0000FFFFull) << 16));
                    y = shfl_xor64(T, 8);
                    T = (lane & 8)  ? ((T & 0xFF00FF00FF00FF00ull) | ((y & 0xFF00FF00FF00FF00ull) >> 8))
                                    : ((T & 0x00FF00FF00FF00FFull) | ((y & 0x00FF00FF00FF00FFull) << 8));
                    y = shfl_xor64(T, 4);
                    T = (lane & 4)  ? ((T & 0xF0F0F0F0F0F0F0F0ull) | ((y & 0xF0F0F0F0F0F0F0F0ull) >> 4))
                                    : ((T & 0x0F0F0F0F0F0F0F0Full) | ((y & 0x0F0F0F0F0F0F0F0Full) << 4));
                    y = shfl_xor64(T, 2);
                    T = (lane & 2)  ? ((T & 0xCCCCCCCCCCCCCCCCull) | ((y & 0xCCCCCCCCCCCCCCCCull) >> 2))
                                    : ((T & 0x3333333333333333ull) | ((y & 0x3333333333333333ull) << 2));
                    y = shfl_xor64(T, 1);
                    T = (lane & 1)  ? ((T & 0xAAAAAAAAAAAAAAAAull) | ((y & 0xAAAAAAAAAAAAAAAAull) >> 1))
                                    : ((T & 0x5555555555555555ull) | ((y & 0x5555555555555555ull) << 1));
                }
                // iterative closure: accept all with no live suppressor,
                // kill their victims; repeat. Equals sequential greedy.
                ull A = wval;
                P = 0ull;
                while (A) {
                    const bool inA = (A >> lane) & 1ull;
                    ull D = __ballot((inA && ((T & A) == 0ull)) ? 1 : 0);
                    P |= D;
                    ull kill = __ballot((inA && ((T & D) != 0ull)) ? 1 : 0);
                    A &= ~(D | kill);
                }
            }

            // ---- ordered, PROP-capped parallel pick write
            const int total = __popcll(P);
            const int room  = PROP - cnt;
            const bool lanePicked = (P >> lane) & 1ull;
            const int myrank = __popcll(P & ((1ull << lane) - 1ull));
            if (lanePicked && myrank < room) picks[cnt + myrank] = (k << 6) + lane;
            cnt = (total >= room) ? PROP : (cnt + total);

            // ---- OR picked rows into alive regs, reading from the LDS buffer.
            // (skipped when cnt hit PROP: alive state is never used again)
            if (cnt < PROP) {
                const ulonglong2* bufv = reinterpret_cast<const ulonglong2*>(dbuf);
                ull tm = P;
                const int p0 = __ffsll(tm) - 1;     // pad slot (idempotent OR)
                while (tm) {
                    int idx[16];
                    #pragma unroll
                    for (int q = 0; q < 16; ++q) {
                        if (tm) { int p = __ffsll(tm) - 1; tm &= tm - 1ull; idx[q] = p; }
                        else idx[q] = p0;
                    }
                    ulonglong2 v[16];
                    #pragma unroll
                    for (int q = 0; q < 16; ++q) v[q] = bufv[idx[q] * 48 + lc];
                    ull rx = 0, ry = 0;
                    #pragma unroll
                    for (int q = 0; q < 16; ++q) { rx |= v[q].x; ry |= v[q].y; }
                    aw0 &= ~rx; aw1 &= ~ry;
                }
            }
        }

        // word k fully consumed
        if (lane == (k >> 1)) { if (k & 1) aw1 = 0ull; else aw0 = 0ull; }
        if (cnt == PROP) break;
    }

    // drain any outstanding LDS-DMA before workgroup teardown
    asm volatile("s_waitcnt vmcnt(0)" ::: "memory");
    __syncthreads();

    if (FIRST) {
        if (cnt != PROP) return;           // fallback passes will handle this batch
        if (lane == 0) flags[b] = 1u;
    }

    const float4* bws = boxes_ws + (size_t)b * NSLOT;
    float4* ob = reinterpret_cast<float4*>(out + (size_t)b * PROP * 4);
    for (int i = lane; i < PROP; i += 64) {
        float4 v = make_float4(0.f, 0.f, 0.f, 0.f);
        if (i < cnt) v = bws[picks[i]];
        ob[i] = v;
    }
}

// ---------------------------------------------------------------------------
// Fallback: round-1 monolithic kernel (used if ws too small). Verified exact.
// ---------------------------------------------------------------------------
__device__ __forceinline__ void hist_add_f(unsigned int* hist, unsigned int bin, bool valid) {
    const int lane = threadIdx.x & 63;
    ull todo = __ballot(valid ? 1 : 0);
    #pragma unroll
    for (int it = 0; it < 3; ++it) {
        if (!todo) return;
        int leader = __ffsll(todo) - 1;
        unsigned int lbin = __shfl(bin, leader);
        ull grp = __ballot((valid && (bin == lbin)) ? 1 : 0);
        if (lane == leader) atomicAdd(&hist[lbin], (unsigned int)__popcll(grp));
        todo &= ~grp;
    }
    if ((todo >> lane) & 1ull) atomicAdd(&hist[bin], 1u);
}

__global__ __launch_bounds__(1024)
void proposal_fallback(const float* __restrict__ rpn_probs,
                       const float* __restrict__ rpn_bbox,
                       const float* __restrict__ anchors,
                       float* __restrict__ out)
{
    const int b    = blockIdx.x;
    const int t    = threadIdx.x;
    const int lane = t & 63;
    const int wv   = t >> 6;

    const float2* __restrict__ probs2 = reinterpret_cast<const float2*>(rpn_probs + (size_t)b * NANCH * 2);
    const float4* __restrict__ bbox4  = reinterpret_cast<const float4*>(rpn_bbox  + (size_t)b * NANCH * 4);
    const float4* __restrict__ anc4   = reinterpret_cast<const float4*>(anchors   + (size_t)b * NANCH * 4);
    float* __restrict__ outb = out + (size_t)b * PROP * 4;

    __shared__ __align__(16) char s_big[NSLOT * 16];
    __shared__ ull          s_alive[96];
    __shared__ unsigned int s_hist[256];
    __shared__ unsigned int s_pref;
    __shared__ unsigned int s_targ;
    __shared__ unsigned int s_cnt;

    ull*    sel   = reinterpret_cast<ull*>(s_big);
    float4* boxes = reinterpret_cast<float4*>(s_big);

    const int ITER = (NANCH + 1023) >> 10;

    if (t == 0) { s_pref = 0u; s_targ = PRE_NMS; s_cnt = 0u; }

    for (int p = 0; p < 4; ++p) {
        if (t < 256) s_hist[t] = 0u;
        __syncthreads();
        const unsigned int pref  = s_pref;
        const int          shift = 8 * (3 - p);
        const unsigned int pmask = (p == 0) ? 0u : (0xFFFFFFFFu << (shift + 8));
        for (int i = 0; i < ITER; ++i) {
            int  n     = (i << 10) + t;
            bool valid = (n < NANCH);
            unsigned int key = 0u;
            if (valid) key = __float_as_uint(probs2[n].y);
            bool match = valid && ((key & pmask) == (pref & pmask));
            hist_add_f(s_hist, (key >> shift) & 0xFFu, match);
        }
        __syncthreads();
        if (t == 0) {
            unsigned int target = s_targ;
            unsigned int acc = 0u;
            int v = 255;
            for (; v >= 0; --v) {
                unsigned int h = s_hist[v];
                if (acc + h >= target) break;
                acc += h;
            }
            if (v < 0) v = 0;
            s_pref = pref | ((unsigned int)v << shift);
            s_targ = target - acc;
        }
        __syncthreads();
    }

    const unsigned int T = s_pref;
    __syncthreads();

    for (int i = 0; i < ITER; ++i) {
        int  n     = (i << 10) + t;
        bool valid = (n < NANCH);
        unsigned int key = 0u;
        if (valid) key = __float_as_uint(probs2[n].y);
        bool selp = valid && (key >= T);
        ull  m    = __ballot(selp ? 1 : 0);
        if (m) {
            int leader = __ffsll(m) - 1;
            unsigned int base = 0u;
            if (lane == leader) base = atomicAdd(&s_cnt, (unsigned int)__popcll(m));
            base = __shfl(base, leader);
            if (selp) {
                unsigned int off = base + (unsigned int)__popcll(m & ((1ull << lane) - 1ull));
                if (off < SORTN) sel[off] = ((ull)(~key) << 32) | (ull)(unsigned int)n;
            }
        }
    }
    __syncthreads();
    const unsigned int C = s_cnt;
    for (int s = (int)C + t; s < SORTN; s += 1024) sel[s] = ~0ull;
    __syncthreads();

    for (unsigned int k = 2; k <= SORTN; k <<= 1) {
        for (unsigned int j = k >> 1; j > 0; j >>= 1) {
            #pragma unroll
            for (int r = 0; r < SORTN / 1024; ++r) {
                int i = (r << 10) + t;
                int l = i ^ (int)j;
                if (l > i) {
                    ull a  = sel[i];
                    ull bq = sel[l];
                    bool up = ((i & (int)k) == 0);
                    if ((a > bq) == up) { sel[i] = bq; sel[l] = a; }
                }
            }
            __syncthreads();
        }
    }

    ull ss[6];
    #pragma unroll
    for (int e = 0; e < 6; ++e) ss[e] = sel[(e << 10) + t];
    __syncthreads();

    float4 rbox[6];
    float  rarea[6];
    #pragma unroll
    for (int e = 0; e < 6; ++e) {
        int s = (e << 10) + t;
        float4 bx = make_float4(0.f, 0.f, 0.f, 0.f);
        bool ok = false;
        if (s < PRE_NMS) {
            unsigned int key = ~(unsigned int)(ss[e] >> 32);
            unsigned int n   = (unsigned int)(ss[e] & 0xFFFFFFFFull);
            float4 a = anc4[n];
            float4 d = bbox4[n];
            float dy = d.x * 0.1f, dx = d.y * 0.1f, dh = d.z * 0.2f, dw = d.w * 0.2f;
            float h  = a.z - a.x;
            float w  = a.w - a.y;
            float cy = a.x + 0.5f * h;
            float cx = a.y + 0.5f * w;
            cy = cy + dy * h;
            cx = cx + dx * w;
            h  = h * expf(dh);
            w  = w * expf(dw);
            float y1 = cy - 0.5f * h;
            float x1 = cx - 0.5f * w;
            float y2 = y1 + h;
            float x2 = x1 + w;
            y1 = fminf(fmaxf(y1, 0.f), 1.f);
            x1 = fminf(fmaxf(x1, 0.f), 1.f);
            y2 = fminf(fmaxf(y2, 0.f), 1.f);
            x2 = fminf(fmaxf(x2, 0.f), 1.f);
            bx = make_float4(y1, x1, y2, x2);
            ok = (key >= SCORE_THRES_BITS);
        }
        rbox[e]  = bx;
        rarea[e] = (bx.z - bx.x) * (bx.w - bx.y);
        boxes[s] = bx;
        ull am = __ballot(ok ? 1 : 0);
        if (lane == 0) s_alive[wv + (e << 4)] = am;
    }

    int emitted = 0;
    for (;;) {
        __syncthreads();
        if (emitted == PROP) break;
        ull w0 = s_alive[lane];
        ull w1 = (lane < 32) ? s_alive[64 + lane] : 0ull;
        ull nz0 = __ballot(w0 != 0ull ? 1 : 0);
        ull nz1 = __ballot(w1 != 0ull ? 1 : 0);
        int pick = -1;
        if (nz0) {
            int wd = __ffsll(nz0) - 1;
            ull wvv = __shfl(w0, wd);
            pick = (wd << 6) + __ffsll(wvv) - 1;
        } else if (nz1) {
            int wd = __ffsll(nz1) - 1;
            ull wvv = __shfl(w1, wd);
            pick = ((wd + 64) << 6) + __ffsll(wvv) - 1;
        }
        if (pick < 0) break;
        __syncthreads();

        if (t < 4) outb[(emitted << 2) + t] = reinterpret_cast<const float*>(s_big)[(pick << 2) + t];

        float4 p = boxes[pick];
        float parea = (p.z - p.x) * (p.w - p.y);
        #pragma unroll
        for (int e = 0; e < 6; ++e) {
            float4 bb  = rbox[e];
            float yy1 = fmaxf(p.x, bb.x);
            float xx1 = fmaxf(p.y, bb.y);
            float yy2 = fminf(p.z, bb.z);
            float xx2 = fminf(p.w, bb.w);
            float ih  = fmaxf(yy2 - yy1, 0.f);
            float iw  = fmaxf(xx2 - xx1, 0.f);
            float inter = ih * iw;
            float denom = ((parea + rarea[e]) - inter) + EPS_F;
            bool  sup   = ((double)inter > M_D * (double)denom);
            ull m = __ballot(sup ? 1 : 0);
            int word = wv + (e << 4);
            if (word == (pick >> 6)) m |= (1ull << (pick & 63));
            if (lane == 0) s_alive[word] &= ~m;
        }
        ++emitted;
    }

    for (int i = (emitted << 2) + t; i < PROP * 4; i += 1024) outb[i] = 0.f;
}

extern "C" void kernel_launch(void* const* d_in, const int* in_sizes, int n_in,
                              void* d_out, int out_size, void* d_ws, size_t ws_size,
                              hipStream_t stream) {
    const float* rpn_probs = (const float*)d_in[0];
    const float* rpn_bbox  = (const float*)d_in[1];
    const float* anchors   = (const float*)d_in[2];
    float* out = (float*)d_out;

    // ws layout:
    //   [0)        boxes   8*6144*16 = 786432
    //   [786432)   areas   8*6144*4  = 196608   -> ends 983040
    //   [983040)   ZERO region (one memset to MAT_OFF):
    //       alive   8*96*8 = 6144   @983040
    //       Tc      32 B            @989184
    //       done    32 B            @989440
    //       cntp    8*64*4 = 2048   @989696
    //       ghist   8*256*4 = 8192  @991744   -> ends 999936
    //       flags   8*4 = 32 B      @999936
    //       binbase 8*132*4 = 4224  @1000448
    //       bincnt  8*132*4 = 4224  @1004672  -> ends 1008896
    //   [1MiB)     mat (selbuf aliased at its head, consumed before mat write)
    const size_t BOX_OFF   = 0;
    const size_t AREA_OFF  = 786432;
    const size_t ZERO_OFF  = 983040;
    const size_t ALIVE_OFF = 983040;
    const size_t TC_OFF    = 989184;
    const size_t DONE_OFF  = 989440;
    const size_t CNT_OFF   = 989696;
    const size_t GHIST_OFF = 991744;
    const size_t FLAG_OFF  = 999936;
    const size_t BINB_OFF  = 1000448;
    const size_t BINC_OFF  = 1004672;
    const size_t MAT_OFF   = 1u << 20;
    const size_t SELB_OFF  = MAT_OFF;
    const size_t WS_NEED   = MAT_OFF + (size_t)BATCH * PRE_NMS * MROW * 8;     // ~37.9 MB

    if (d_ws != nullptr && ws_size >= WS_NEED) {
        char* ws = (char*)d_ws;
        float4* boxes_ws = (float4*)(ws + BOX_OFF);
        float*  area_ws  = (float*)(ws + AREA_OFF);
        ull*    alive_ws = (ull*)(ws + ALIVE_OFF);
        u32*    Tc       = (u32*)(ws + TC_OFF);
        u32*    done     = (u32*)(ws + DONE_OFF);
        u32*    cntp     = (u32*)(ws + CNT_OFF);
        u32*    ghist    = (u32*)(ws + GHIST_OFF);
        u32*    flags    = (u32*)(ws + FLAG_OFF);
        u32*    binbase  = (u32*)(ws + BINB_OFF);
        u32*    bincnt   = (u32*)(ws + BINC_OFF);
        ull*    selbuf   = (ull*)(ws + SELB_OFF);
        ull*    mat      = (ull*)(ws + MAT_OFF);

        hipMemsetAsync(ws + ZERO_OFF, 0, MAT_OFF - ZERO_OFF, stream);  // alive..bincnt
        hipLaunchKernelGGL(hist_kernel, dim3(CBLK, BATCH), dim3(256), 0, stream,
                           rpn_probs, ghist, done, Tc, binbase, cntp);
        hipLaunchKernelGGL(compact_kernel, dim3(CBLK, BATCH), dim3(256), 0, stream,
                           rpn_probs, Tc, binbase, bincnt, selbuf);
        hipLaunchKernelGGL(rank_decode_kernel, dim3(SORTN / 256, BATCH), dim3(256), 0, stream,
                           rpn_bbox, anchors, selbuf, cntp, binbase, ghist,
                           boxes_ws, area_ws, alive_ws);
        // fast pass: words 0..CHUNK_W-1 of rows 0..CHUNK_W*64-1, then capped scan
        hipLaunchKernelGGL(iou_chunk_kernel, dim3(CHUNK_W, BATCH), dim3(1024), 0, stream,
                           boxes_ws, area_ws, mat, (const u32*)nullptr, CHUNK_W);
        hipLaunchKernelGGL((nms_scan_t<CHUNK_W, true>), dim3(BATCH), dim3(64), 0, stream,
                           boxes_ws, alive_ws, mat, out, flags);
        // guarded completion (expected no-op): rest of the matrix + full re-scan
        hipLaunchKernelGGL(iou_chunk_kernel, dim3(NW, BATCH), dim3(1024), 0, stream,
                           boxes_ws, area_ws, mat, (const u32*)flags, NW);
        hipLaunchKernelGGL((nms_scan_t<NW, false>), dim3(BATCH), dim3(64), 0, stream,
                           boxes_ws, alive_ws, mat, out, flags);
    } else {
        hipLaunchKernelGGL(proposal_fallback, dim3(BATCH), dim3(1024), 0, stream,
                           rpn_probs, rpn_bbox, anchors, out);
    }
}

// Round 5
// 257.600 us; speedup vs baseline: 1.8985x; 1.0907x over previous
//
#include <hip/hip_runtime.h>
#include <cstdint>
#include <cstddef>

#pragma clang fp contract(off)

#define BATCH    8
#define NANCH    261888
#define PRE_NMS  6000
#define PROP     1000
#define SORTN    8192
#define NSLOT    6144          /* 6 * 1024 */
#define MROW     96            /* u64 words per suppression row (94 used + 2 pad) */
#define NW       94            /* suppression words per batch (6000/64 rounded up) */
#define CHUNK_W  32            /* words computed+scanned in the fast first pass */
#define NZCAP    128           /* LDS-stashed nonzero rows (capped scan) */
#define NPAIR    130944        /* NANCH / 2 */
#define CBLK     32            /* blocks per batch for hist/compact */
#define CPAIR    4092          /* NPAIR / CBLK */
#define SCORE_THRES_BITS 0x3F000000u   /* bits of 0.5f */
#define EPS_F    1e-8f
/* midpoint between pred(0.7f) and 0.7f = 23488101 * 2^-25, exact in double.
   RN(inter/denom) >= 0.7f  <=>  inter > M_D * denom  (exact: 25b x 24b product;
   tie rounds to even = pred(0.7f), so strict > is correct). */
#define M_D      0.6999999582767486572265625

typedef unsigned long long ull;
typedef unsigned int u32;

// ---------------------------------------------------------------------------
// Kernel A (fused hist + findT + binbase): fine histogram of scores >= 0.5
// into 129 bins; the LAST block per batch (done-counter) computes the coarse
// threshold, the per-bin rank bases (suffix sums), and the total count C.
// grid (32, BATCH) x 256.
// ---------------------------------------------------------------------------
__global__ __launch_bounds__(256)
void hist_kernel(const float* __restrict__ rpn_probs, u32* __restrict__ ghist,
                 u32* __restrict__ done, u32* __restrict__ Tc,
                 u32* __restrict__ binbase, u32* __restrict__ cntp)
{
    __shared__ u32 h[129];
    __shared__ u32 s_old;
    const int t = threadIdx.x;
    const int b = blockIdx.y;
    if (t < 129) h[t] = 0u;
    __syncthreads();

    const float4* p4 = reinterpret_cast<const float4*>(rpn_probs + (size_t)b * NANCH * 2);
    const int p0 = blockIdx.x * CPAIR;
    for (int i = t; i < CPAIR; i += 256) {
        float4 v = p4[p0 + i];                 // scores of anchors 2p, 2p+1 in .y/.w
        u32 k0 = __float_as_uint(v.y);
        u32 k1 = __float_as_uint(v.w);
        if (k0 >= 0x3F000000u) atomicAdd(&h[min((k0 >> 16) - 0x3F00u, 128u)], 1u);
        if (k1 >= 0x3F000000u) atomicAdd(&h[min((k1 >> 16) - 0x3F00u, 128u)], 1u);
    }
    __syncthreads();
    if (t < 129 && h[t]) atomicAdd(&ghist[(b << 8) + t], h[t]);

    __threadfence();
    if (t == 0) s_old = atomicAdd(&done[b], 1u);
    __syncthreads();
    if (s_old == CBLK - 1) {
        // last block for this batch: all flushes are globally visible
        if (t < 129) h[t] = atomicAdd(&ghist[(b << 8) + t], 0u);   // coherent read
        __syncthreads();
        if (t == 0) {
            u32* bb = binbase + b * 132;
            u32 run = 0; int binT = -1; u32 Cv = 0;
            for (int i = 128; i >= 0; --i) {
                bb[i] = run;                    // # keys in bins strictly above i
                run += h[i];
                if (binT < 0 && run >= PRE_NMS) { binT = i; Cv = run; }
            }
            u32 T;
            if (binT < 0)         { T = 0x3F000000u; Cv = run; }  // all >=0.5 (unreachable)
            else if (binT == 128)   T = 0x3F800000u;
            else                    T = 0x3F000000u + ((u32)binT << 16);
            Tc[b] = T;
            cntp[b << 6] = Cv;
        }
    }
}

// ---------------------------------------------------------------------------
// Kernel C (R13): bucketed compact. Each key >= Tc[b] scatters directly into
// its score-bin's segment of selbuf: pos = binbase[bin] + atomic(bincnt[bin]).
// grid (32, BATCH) x 256.
// ---------------------------------------------------------------------------
__global__ __launch_bounds__(256)
void compact_kernel(const float* __restrict__ rpn_probs,
                    const u32* __restrict__ Tc,
                    const u32* __restrict__ binbase,
                    u32* __restrict__ bincnt,
                    ull* __restrict__ selbuf)
{
    const int t = threadIdx.x;
    const int b = blockIdx.y;
    const u32 T = Tc[b];
    const u32* bb = binbase + b * 132;
    u32* bc = bincnt + b * 132;

    const float4* p4 = reinterpret_cast<const float4*>(rpn_probs + (size_t)b * NANCH * 2);
    ull* sb = selbuf + (size_t)b * SORTN;
    const int p0 = blockIdx.x * CPAIR;

    for (int i = t; i < CPAIR; i += 256) {
        float4 v = p4[p0 + i];
        const int n0 = (p0 + i) << 1;
        #pragma unroll
        for (int e = 0; e < 2; ++e) {
            u32 k = __float_as_uint(e ? v.w : v.y);
            if (k >= T) {
                u32 bin = min((k >> 16) - 0x3F00u, 128u);
                u32 pos = bb[bin] + atomicAdd(&bc[bin], 1u);
                if (pos < SORTN) sb[pos] = ((ull)(~k) << 32) | (ull)(u32)(n0 + e);
            }
        }
    }
}

// ---------------------------------------------------------------------------
// Kernel D (R13): bucketed rank + decode + scatter. rank = binbase[bin] +
// #{y in same bin : key_y < key_x}. grid (32, BATCH) x 256.
// ---------------------------------------------------------------------------
__global__ __launch_bounds__(256)
void rank_decode_kernel(const float* __restrict__ rpn_bbox,
                        const float* __restrict__ anchors,
                        const ull* __restrict__ selbuf,
                        const u32* __restrict__ cntp,
                        const u32* __restrict__ binbase,
                        const u32* __restrict__ ghist,
                        float4* __restrict__ boxes_ws,
                        float* __restrict__ area_ws,
                        ull* __restrict__ alive_ws)
{
    const int t = threadIdx.x;
    const int b = blockIdx.y;
    const u32 C = min(cntp[b << 6], (u32)SORTN);
    const ull* sb = selbuf + (size_t)b * SORTN;

    const int i = (blockIdx.x << 8) + t;
    if (i >= (int)C) return;

    const ull mykey = sb[i];
    const u32 key = ~(u32)(mykey >> 32);
    const u32 n   = (u32)(mykey & 0xFFFFFFFFull);
    const u32 bin = min((key >> 16) - 0x3F00u, 128u);
    const u32 lo  = binbase[b * 132 + bin];
    const u32 cb  = min(ghist[(b << 8) + bin], (u32)SORTN - lo);  // bin size (clamped)

    const ull* base = sb + lo;
    int local = 0;
    u32 j = 0;
    for (; j + 8 <= cb; j += 8) {
        #pragma unroll
        for (int u = 0; u < 8; ++u) local += (base[j + u] < mykey) ? 1 : 0;
    }
    for (; j < cb; ++j) local += (base[j] < mykey) ? 1 : 0;
    const int rank = (int)lo + local;

    if (rank < PRE_NMS) {
        const float4* bbox4 = reinterpret_cast<const float4*>(rpn_bbox + (size_t)b * NANCH * 4);
        const float4* anc4  = reinterpret_cast<const float4*>(anchors  + (size_t)b * NANCH * 4);
        float4 a = anc4[n];
        float4 d = bbox4[n];
        float dy = d.x * 0.1f, dx = d.y * 0.1f, dh = d.z * 0.2f, dw = d.w * 0.2f;
        float h  = a.z - a.x;
        float w  = a.w - a.y;
        float cy = a.x + 0.5f * h;
        float cx = a.y + 0.5f * w;
        cy = cy + dy * h;
        cx = cx + dx * w;
        h  = h * expf(dh);
        w  = w * expf(dw);
        float y1 = cy - 0.5f * h;
        float x1 = cx - 0.5f * w;
        float y2 = y1 + h;
        float x2 = x1 + w;
        y1 = fminf(fmaxf(y1, 0.f), 1.f);
        x1 = fminf(fmaxf(x1, 0.f), 1.f);
        y2 = fminf(fmaxf(y2, 0.f), 1.f);
        x2 = fminf(fmaxf(x2, 0.f), 1.f);
        boxes_ws[(size_t)b * NSLOT + rank] = make_float4(y1, x1, y2, x2);
        area_ws[(size_t)b * NSLOT + rank]  = (y2 - y1) * (x2 - x1);
        if (key >= SCORE_THRES_BITS) {
            atomicOr(&alive_ws[(size_t)b * MROW + (rank >> 6)], 1ull << (rank & 63));
        }
    }
}

// ---------------------------------------------------------------------------
// Kernel E (R12/R14): chunked suppression bit-matrix, 4 rows per wave, PLUS
// per-row nonzero summary (nzmask, 1 bit/row grouped as ull per word-block)
// published via one atomicOr per wave. The scan uses nzmask to touch only
// nonzero rows (~90 of 6000).
// ---------------------------------------------------------------------------
__global__ __launch_bounds__(1024)
void iou_chunk_kernel(const float4* __restrict__ boxes_ws,
                      const float* __restrict__ area_ws,
                      ull* __restrict__ mat,
                      ull* __restrict__ nzmask,
                      const u32* __restrict__ flags,
                      int kend)
{
    const int b = blockIdx.y;
    if (flags && flags[b]) return;        // fast-scan already finished this batch

    __shared__ float4 sbox[NSLOT];    // 96 KB
    __shared__ float  sarea[NSLOT];   // 24 KB

    const int j    = blockIdx.x;
    const int t    = threadIdx.x;
    const int lane = t & 63;
    const int wv   = t >> 6;

    const int kbeg = flags ? max(j, CHUNK_W) : j;
    const int base = j << 6;
    const int nst  = (kend << 6) - base;   // staged cols cover words kbeg..kend-1 (+rows)

    const float4* bws = boxes_ws + (size_t)b * NSLOT + base;
    const float*  aws = area_ws  + (size_t)b * NSLOT + base;
    for (int i = t; i < nst; i += 1024) { sbox[i] = bws[i]; sarea[i] = aws[i]; }
    __syncthreads();

    const int r0 = base + (wv << 2);       // first of this wave's 4 rows
    if (r0 >= PRE_NMS) return;             // only word-block 93's tail waves

    float4 P[4];
    float  PA[4];
    #pragma unroll
    for (int qi = 0; qi < 4; ++qi) { P[qi] = sbox[(wv << 2) + qi]; PA[qi] = sarea[(wv << 2) + qi]; }

    ull* rowp = mat + ((size_t)b * PRE_NMS + r0) * MROW;
    ull acc[4] = {0ull, 0ull, 0ull, 0ull};

    for (int k = kbeg; k < kend; ++k) {
        const int ci = ((k - j) << 6) + lane;
        const float4 qb = sbox[ci];
        const float  qa = sarea[ci];
        ull m[4];
        #pragma unroll
        for (int qi = 0; qi < 4; ++qi) {
            float yy1 = fmaxf(P[qi].x, qb.x);
            float xx1 = fmaxf(P[qi].y, qb.y);
            float yy2 = fminf(P[qi].z, qb.z);
            float xx2 = fminf(P[qi].w, qb.w);
            float inter = fmaxf(yy2 - yy1, 0.f) * fmaxf(xx2 - xx1, 0.f);
            float denom = ((PA[qi] + qa) - inter) + EPS_F;
            m[qi] = __ballot(((double)inter > M_D * (double)denom) ? 1 : 0);
        }
        if (k == j) {                       // diagonal word: mask away c <= r
            #pragma unroll
            for (int qi = 0; qi < 4; ++qi) {
                int sh = (wv << 2) + qi;
                ull keep = (sh == 63) ? 0ull : ((~0ull) << (sh + 1));
                m[qi] &= keep;
            }
        }
        #pragma unroll
        for (int qi = 0; qi < 4; ++qi) acc[qi] |= m[qi];
        if (lane == 0) {
            #pragma unroll
            for (int qi = 0; qi < 4; ++qi) rowp[(size_t)qi * MROW + k] = m[qi];
        }
    }

    if (lane == 0) {
        u32 bits = 0;
        #pragma unroll
        for (int qi = 0; qi < 4; ++qi) if (acc[qi]) bits |= 1u << qi;
        if (bits) atomicOr(&nzmask[(size_t)b * NW + j], (ull)bits << (wv << 2));
    }
}

// ---------------------------------------------------------------------------
// Kernel F (R14): word-walk greedy scan driven by nzmask — no bulk streaming.
//   FIRST=true : capped scan, words 0..CHUNK_W-1. Prologue stashes the ~90
//     nonzero rows (words 0..31 each, 256 B) into LDS via global_load_lds;
//     per word, if nzmask[k]==0 (common) the word resolves with zero memory
//     traffic (diag all-zero => P=wval). Overflow slots (>NZCAP) fall back to
//     exact on-demand global reads.
//   FIRST=false: guarded full re-scan, words 0..NW-1, no stash — diag and
//     OR-gather read nonzero rows on demand from global (exact; cold path).
// ---------------------------------------------------------------------------
__device__ __forceinline__ ull shfl_xor64(ull x, int s)
{
    return (ull)__shfl_xor((long long)x, s, 64);
}

__device__ __forceinline__ ull readlane64(ull x, int l)
{
    u32 lo = (u32)__builtin_amdgcn_readlane((int)(u32)x, l);
    u32 hi = (u32)__builtin_amdgcn_readlane((int)(u32)(x >> 32), l);
    return ((ull)hi << 32) | (ull)lo;
}

template<bool FIRST>
__global__ __launch_bounds__(64)
__attribute__((amdgpu_waves_per_eu(1, 1)))
void nms_scan_t(const float4* __restrict__ boxes_ws,
                const ull* __restrict__ alive_ws,
                const ull* __restrict__ mat,
                const ull* __restrict__ nzmask,
                float* __restrict__ out,
                u32* __restrict__ flags)
{
    const int b = blockIdx.x;
    if (!FIRST && flags[b]) return;        // fast pass already produced output

    const int lane = threadIdx.x;
    const int CW = FIRST ? CHUNK_W : NW;

    __shared__ int picks[PROP];                        // 4 KB
    __shared__ u32 nzrows[NZCAP];                      // 512 B
    __shared__ __align__(16) ull nzbuf[NZCAP * 32];    // 32 KB (capped only)

    // lane l (<48) holds alive words 2l, 2l+1 (words 94,95 zero by construction)
    ull aw0 = 0, aw1 = 0;
    if (lane < 48) {
        const ull* aw = alive_ws + (size_t)b * MROW + 2 * lane;
        aw0 = aw[0]; aw1 = aw[1];
    }

    const ull* mb  = mat    + (size_t)b * PRE_NMS * MROW;
    const ull* nzm = nzmask + (size_t)b * NW;

    // ---- load nz words; capped: lane k<32 holds word k; full: lane l<47 holds 2l,2l+1
    ull nzA = 0, nzB = 0;
    if (FIRST) { if (lane < CHUNK_W) nzA = nzm[lane]; }
    else       { if (lane < 47)      { nzA = nzm[2 * lane]; nzB = nzm[2 * lane + 1]; } }

    int excl = 0, NZ = 0;
    if (FIRST) {
        // exclusive prefix of per-word nz popcounts over lanes 0..31
        int c = (int)__popcll(nzA);
        int incl = c;
        for (int s = 1; s < 32; s <<= 1) {
            int y = __shfl_up(incl, s, 64);
            if (lane >= s) incl += y;
        }
        excl = incl - c;
        NZ = __builtin_amdgcn_readlane(incl, 31);

        // build compacted nonzero-row list (slots < NZCAP)
        {
            ull m = nzA; int r = excl;
            while (m) {
                int p = __ffsll(m) - 1; m &= m - 1ull;
                if (r < NZCAP) nzrows[r] = (u32)((lane << 6) + p);
                ++r;
            }
        }
        __syncthreads();

        // stash nonzero rows (words 0..31 = 256 B each) into LDS; 4 rows/load-instr
        const int NP = min(NZ, NZCAP);
        if (NP > 0) {
            u32 ridA = nzrows[lane];
            u32 ridB = nzrows[64 + lane];
            const int ninst = (NP + 3) >> 2;
            for (int i = 0; i < ninst; ++i) {
                int slot = 4 * i + (lane >> 4);
                if (slot >= NP) slot = NP - 1;
                int sel = (slot & 63) << 2;
                int ra = __builtin_amdgcn_ds_bpermute(sel, (int)ridA);
                int rb = __builtin_amdgcn_ds_bpermute(sel, (int)ridB);
                u32 rid = (u32)((slot < 64) ? ra : rb);
                const char* src = (const char*)(mb + (size_t)rid * MROW) + ((unsigned)(lane & 15) << 4);
                __builtin_amdgcn_global_load_lds(
                    (const __attribute__((address_space(1))) void*)src,
                    (__attribute__((address_space(3))) void*)((char*)&nzbuf[0] + i * 1024),
                    16, 0, 0);
            }
        }
        asm volatile("s_waitcnt vmcnt(0)" ::: "memory");
        __builtin_amdgcn_sched_barrier(0);
    }

    int cnt = 0;
    for (int k = 0; k < CW; ++k) {
        // nz word k (uniform)
        ull nzk;
        if (FIRST) nzk = readlane64(nzA, k);
        else       nzk = readlane64((k & 1) ? nzB : nzA, k >> 1);

        // alive word k (uniform)
        const int srcw = k >> 1;
        const ull awk = (k & 1) ? aw1 : aw0;
        ull wval = readlane64(awk, srcw);

        if (wval != 0ull) {
            const int slotbase_k = FIRST ? __builtin_amdgcn_readlane(excl, k) : 0;

            // per-lane diag word (zero rows => zero diag, no read)
            ull diag_cur = 0ull;
            if (nzk != 0ull) {
                bool mynz = (nzk >> lane) & 1ull;
                if (mynz) {
                    if (FIRST) {
                        int slot = slotbase_k + (int)__popcll(nzk & ((1ull << lane) - 1ull));
                        diag_cur = (slot < NZCAP) ? nzbuf[(size_t)slot * 32 + k]
                                                  : mb[(size_t)((k << 6) + lane) * MROW + k];
                    } else {
                        diag_cur = mb[(size_t)((k << 6) + lane) * MROW + k];
                    }
                }
            }

            // ---- lane-parallel pick resolution for word k
            const bool rowAlive = (wval >> lane) & 1ull;
            ull P;
            ull conflict = (nzk == 0ull) ? 0ull
                         : __ballot((rowAlive && ((diag_cur & wval) != 0ull)) ? 1 : 0);
            if (conflict == 0ull) {
                P = wval;
            } else {
                // transpose the 64x64 intra tile: T = "who suppresses me"
                ull T = diag_cur;
                {
                    ull y;
                    y = shfl_xor64(T, 32);
                    T = (lane & 32) ? ((T & 0xFFFFFFFF00000000ull) | ((y & 0xFFFFFFFF00000000ull) >> 32))
                                    : ((T & 0x00000000FFFFFFFFull) | ((y & 0x00000000FFFFFFFFull) << 32));
                    y = shfl_xor64(T, 16);
                    T = (lane & 16) ? ((T & 0xFFFF0000FFFF0000ull) | ((y & 0xFFFF0000FFFF0000ull) >> 16))
                                    : ((T & 0x0000FFFF0000FFFFull) | ((y & 0x0000FFFF0000FFFFull) << 16));
                    y = shfl_xor64(T, 8);
                    T = (lane & 8)  ? ((T & 0xFF00FF00FF00FF00ull) | ((y & 0xFF00FF00FF00FF00ull) >> 8))
                                    : ((T & 0x00FF00FF00FF00FFull) | ((y & 0x00FF00FF00FF00FFull) << 8));
                    y = shfl_xor64(T, 4);
                    T = (lane & 4)  ? ((T & 0xF0F0F0F0F0F0F0F0ull) | ((y & 0xF0F0F0F0F0F0F0F0ull) >> 4))
                                    : ((T & 0x0F0F0F0F0F0F0F0Full) | ((y & 0x0F0F0F0F0F0F0F0Full) << 4));
                    y = shfl_xor64(T, 2);
                    T = (lane & 2)  ? ((T & 0xCCCCCCCCCCCCCCCCull) | ((y & 0xCCCCCCCCCCCCCCCCull) >> 2))
                                    : ((T & 0x3333333333333333ull) | ((y & 0x3333333333333333ull) << 2));
                    y = shfl_xor64(T, 1);
                    T = (lane & 1)  ? ((T & 0xAAAAAAAAAAAAAAAAull) | ((y & 0xAAAAAAAAAAAAAAAAull) >> 1))
                                    : ((T & 0x5555555555555555ull) | ((y & 0x5555555555555555ull) << 1));
                }
                // iterative closure: accept all with no live suppressor,
                // kill their victims; repeat. Equals sequential greedy.
                ull A = wval;
                P = 0ull;
                while (A) {
                    const bool inA = (A >> lane) & 1ull;
                    ull D = __ballot((inA && ((T & A) == 0ull)) ? 1 : 0);
                    P |= D;
                    ull kill = __ballot((inA && ((T & D) != 0ull)) ? 1 : 0);
                    A &= ~(D | kill);
                }
            }

            // ---- ordered, PROP-capped parallel pick write
            const int total = __popcll(P);
            const int room  = PROP - cnt;
            const bool lanePicked = (P >> lane) & 1ull;
            const int myrank = __popcll(P & ((1ull << lane) - 1ull));
            if (lanePicked && myrank < room) picks[cnt + myrank] = (k << 6) + lane;
            cnt = (total >= room) ? PROP : (cnt + total);

            // ---- OR only NONZERO picked rows into alive regs
            if (cnt < PROP && nzk != 0ull) {
                ull orset = P & nzk;
                while (orset) {
                    int p = __ffsll(orset) - 1; orset &= orset - 1ull;
                    ulonglong2 v;
                    if (FIRST) {
                        int slot = slotbase_k + (int)__popcll(nzk & ((1ull << p) - 1ull));
                        if (slot < NZCAP) {
                            const ulonglong2* bv = reinterpret_cast<const ulonglong2*>(&nzbuf[(size_t)slot * 32]);
                            v = bv[lane & 15];      // words 0..31; lanes>=16 duplicate (aw unused)
                        } else {
                            const ulonglong2* gv = reinterpret_cast<const ulonglong2*>(mb + (size_t)((k << 6) + p) * MROW);
                            v = gv[lane & 15];
                        }
                    } else {
                        const ulonglong2* gv = reinterpret_cast<const ulonglong2*>(mb + (size_t)((k << 6) + p) * MROW);
                        v = gv[min(lane, 47)];
                    }
                    aw0 &= ~v.x; aw1 &= ~v.y;
                }
            }
        }

        // word k fully consumed
        if (lane == (k >> 1)) { if (k & 1) aw1 = 0ull; else aw0 = 0ull; }
        if (cnt == PROP) break;
    }

    __syncthreads();

    if (FIRST) {
        if (cnt != PROP) return;           // fallback passes will handle this batch
        if (lane == 0) flags[b] = 1u;
    }

    const float4* bws = boxes_ws + (size_t)b * NSLOT;
    float4* ob = reinterpret_cast<float4*>(out + (size_t)b * PROP * 4);
    for (int i = lane; i < PROP; i += 64) {
        float4 v = make_float4(0.f, 0.f, 0.f, 0.f);
        if (i < cnt) v = bws[picks[i]];
        ob[i] = v;
    }
}

// ---------------------------------------------------------------------------
// Fallback: round-1 monolithic kernel (used if ws too small). Verified exact.
// ---------------------------------------------------------------------------
__device__ __forceinline__ void hist_add_f(unsigned int* hist, unsigned int bin, bool valid) {
    const int lane = threadIdx.x & 63;
    ull todo = __ballot(valid ? 1 : 0);
    #pragma unroll
    for (int it = 0; it < 3; ++it) {
        if (!todo) return;
        int leader = __ffsll(todo) - 1;
        unsigned int lbin = __shfl(bin, leader);
        ull grp = __ballot((valid && (bin == lbin)) ? 1 : 0);
        if (lane == leader) atomicAdd(&hist[lbin], (unsigned int)__popcll(grp));
        todo &= ~grp;
    }
    if ((todo >> lane) & 1ull) atomicAdd(&hist[bin], 1u);
}

__global__ __launch_bounds__(1024)
void proposal_fallback(const float* __restrict__ rpn_probs,
                       const float* __restrict__ rpn_bbox,
                       const float* __restrict__ anchors,
                       float* __restrict__ out)
{
    const int b    = blockIdx.x;
    const int t    = threadIdx.x;
    const int lane = t & 63;
    const int wv   = t >> 6;

    const float2* __restrict__ probs2 = reinterpret_cast<const float2*>(rpn_probs + (size_t)b * NANCH * 2);
    const float4* __restrict__ bbox4  = reinterpret_cast<const float4*>(rpn_bbox  + (size_t)b * NANCH * 4);
    const float4* __restrict__ anc4   = reinterpret_cast<const float4*>(anchors   + (size_t)b * NANCH * 4);
    float* __restrict__ outb = out + (size_t)b * PROP * 4;

    __shared__ __align__(16) char s_big[NSLOT * 16];
    __shared__ ull          s_alive[96];
    __shared__ unsigned int s_hist[256];
    __shared__ unsigned int s_pref;
    __shared__ unsigned int s_targ;
    __shared__ unsigned int s_cnt;

    ull*    sel   = reinterpret_cast<ull*>(s_big);
    float4* boxes = reinterpret_cast<float4*>(s_big);

    const int ITER = (NANCH + 1023) >> 10;

    if (t == 0) { s_pref = 0u; s_targ = PRE_NMS; s_cnt = 0u; }

    for (int p = 0; p < 4; ++p) {
        if (t < 256) s_hist[t] = 0u;
        __syncthreads();
        const unsigned int pref  = s_pref;
        const int          shift = 8 * (3 - p);
        const unsigned int pmask = (p == 0) ? 0u : (0xFFFFFFFFu << (shift + 8));
        for (int i = 0; i < ITER; ++i) {
            int  n     = (i << 10) + t;
            bool valid = (n < NANCH);
            unsigned int key = 0u;
            if (valid) key = __float_as_uint(probs2[n].y);
            bool match = valid && ((key & pmask) == (pref & pmask));
            hist_add_f(s_hist, (key >> shift) & 0xFFu, match);
        }
        __syncthreads();
        if (t == 0) {
            unsigned int target = s_targ;
            unsigned int acc = 0u;
            int v = 255;
            for (; v >= 0; --v) {
                unsigned int h = s_hist[v];
                if (acc + h >= target) break;
                acc += h;
            }
            if (v < 0) v = 0;
            s_pref = pref | ((unsigned int)v << shift);
            s_targ = target - acc;
        }
        __syncthreads();
    }

    const unsigned int T = s_pref;
    __syncthreads();

    for (int i = 0; i < ITER; ++i) {
        int  n     = (i << 10) + t;
        bool valid = (n < NANCH);
        unsigned int key = 0u;
        if (valid) key = __float_as_uint(probs2[n].y);
        bool selp = valid && (key >= T);
        ull  m    = __ballot(selp ? 1 : 0);
        if (m) {
            int leader = __ffsll(m) - 1;
            unsigned int base = 0u;
            if (lane == leader) base = atomicAdd(&s_cnt, (unsigned int)__popcll(m));
            base = __shfl(base, leader);
            if (selp) {
                unsigned int off = base + (unsigned int)__popcll(m & ((1ull << lane) - 1ull));
                if (off < SORTN) sel[off] = ((ull)(~key) << 32) | (ull)(unsigned int)n;
            }
        }
    }
    __syncthreads();
    const unsigned int C = s_cnt;
    for (int s = (int)C + t; s < SORTN; s += 1024) sel[s] = ~0ull;
    __syncthreads();

    for (unsigned int k = 2; k <= SORTN; k <<= 1) {
        for (unsigned int j = k >> 1; j > 0; j >>= 1) {
            #pragma unroll
            for (int r = 0; r < SORTN / 1024; ++r) {
                int i = (r << 10) + t;
                int l = i ^ (int)j;
                if (l > i) {
                    ull a  = sel[i];
                    ull bq = sel[l];
                    bool up = ((i & (int)k) == 0);
                    if ((a > bq) == up) { sel[i] = bq; sel[l] = a; }
                }
            }
            __syncthreads();
        }
    }

    ull ss[6];
    #pragma unroll
    for (int e = 0; e < 6; ++e) ss[e] = sel[(e << 10) + t];
    __syncthreads();

    float4 rbox[6];
    float  rarea[6];
    #pragma unroll
    for (int e = 0; e < 6; ++e) {
        int s = (e << 10) + t;
        float4 bx = make_float4(0.f, 0.f, 0.f, 0.f);
        bool ok = false;
        if (s < PRE_NMS) {
            unsigned int key = ~(unsigned int)(ss[e] >> 32);
            unsigned int n   = (unsigned int)(ss[e] & 0xFFFFFFFFull);
            float4 a = anc4[n];
            float4 d = bbox4[n];
            float dy = d.x * 0.1f, dx = d.y * 0.1f, dh = d.z * 0.2f, dw = d.w * 0.2f;
            float h  = a.z - a.x;
            float w  = a.w - a.y;
            float cy = a.x + 0.5f * h;
            float cx = a.y + 0.5f * w;
            cy = cy + dy * h;
            cx = cx + dx * w;
            h  = h * expf(dh);
            w  = w * expf(dw);
            float y1 = cy - 0.5f * h;
            float x1 = cx - 0.5f * w;
            float y2 = y1 + h;
            float x2 = x1 + w;
            y1 = fminf(fmaxf(y1, 0.f), 1.f);
            x1 = fminf(fmaxf(x1, 0.f), 1.f);
            y2 = fminf(fmaxf(y2, 0.f), 1.f);
            x2 = fminf(fmaxf(x2, 0.f), 1.f);
            bx = make_float4(y1, x1, y2, x2);
            ok = (key >= SCORE_THRES_BITS);
        }
        rbox[e]  = bx;
        rarea[e] = (bx.z - bx.x) * (bx.w - bx.y);
        boxes[s] = bx;
        ull am = __ballot(ok ? 1 : 0);
        if (lane == 0) s_alive[wv + (e << 4)] = am;
    }

    int emitted = 0;
    for (;;) {
        __syncthreads();
        if (emitted == PROP) break;
        ull w0 = s_alive[lane];
        ull w1 = (lane < 32) ? s_alive[64 + lane] : 0ull;
        ull nz0 = __ballot(w0 != 0ull ? 1 : 0);
        ull nz1 = __ballot(w1 != 0ull ? 1 : 0);
        int pick = -1;
        if (nz0) {
            int wd = __ffsll(nz0) - 1;
            ull wvv = __shfl(w0, wd);
            pick = (wd << 6) + __ffsll(wvv) - 1;
        } else if (nz1) {
            int wd = __ffsll(nz1) - 1;
            ull wvv = __shfl(w1, wd);
            pick = ((wd + 64) << 6) + __ffsll(wvv) - 1;
        }
        if (pick < 0) break;
        __syncthreads();

        if (t < 4) outb[(emitted << 2) + t] = reinterpret_cast<const float*>(s_big)[(pick << 2) + t];

        float4 p = boxes[pick];
        float parea = (p.z - p.x) * (p.w - p.y);
        #pragma unroll
        for (int e = 0; e < 6; ++e) {
            float4 bb  = rbox[e];
            float yy1 = fmaxf(p.x, bb.x);
            float xx1 = fmaxf(p.y, bb.y);
            float yy2 = fminf(p.z, bb.z);
            float xx2 = fminf(p.w, bb.w);
            float ih  = fmaxf(yy2 - yy1, 0.f);
            float iw  = fmaxf(xx2 - xx1, 0.f);
            float inter = ih * iw;
            float denom = ((parea + rarea[e]) - inter) + EPS_F;
            bool  sup   = ((double)inter > M_D * (double)denom);
            ull m = __ballot(sup ? 1 : 0);
            int word = wv + (e << 4);
            if (word == (pick >> 6)) m |= (1ull << (pick & 63));
            if (lane == 0) s_alive[word] &= ~m;
        }
        ++emitted;
    }

    for (int i = (emitted << 2) + t; i < PROP * 4; i += 1024) outb[i] = 0.f;
}

extern "C" void kernel_launch(void* const* d_in, const int* in_sizes, int n_in,
                              void* d_out, int out_size, void* d_ws, size_t ws_size,
                              hipStream_t stream) {
    const float* rpn_probs = (const float*)d_in[0];
    const float* rpn_bbox  = (const float*)d_in[1];
    const float* anchors   = (const float*)d_in[2];
    float* out = (float*)d_out;

    // ws layout:
    //   [0)        boxes   8*6144*16 = 786432
    //   [786432)   areas   8*6144*4  = 196608   -> ends 983040
    //   [983040)   ZERO region (one memset to MAT_OFF):
    //       alive   8*96*8 = 6144   @983040
    //       Tc      32 B            @989184
    //       done    32 B            @989440
    //       cntp    8*64*4 = 2048   @989696
    //       ghist   8*256*4 = 8192  @991744   -> ends 999936
    //       flags   8*4 = 32 B      @999936
    //       binbase 8*132*4 = 4224  @1000448
    //       bincnt  8*132*4 = 4224  @1004672
    //       nzmask  8*94*8 = 6016   @1008896  -> ends 1014912
    //   [1MiB)     mat (selbuf aliased at its head, consumed before mat write)
    const size_t BOX_OFF   = 0;
    const size_t AREA_OFF  = 786432;
    const size_t ZERO_OFF  = 983040;
    const size_t ALIVE_OFF = 983040;
    const size_t TC_OFF    = 989184;
    const size_t DONE_OFF  = 989440;
    const size_t CNT_OFF   = 989696;
    const size_t GHIST_OFF = 991744;
    const size_t FLAG_OFF  = 999936;
    const size_t BINB_OFF  = 1000448;
    const size_t BINC_OFF  = 1004672;
    const size_t NZ_OFF    = 1008896;
    const size_t MAT_OFF   = 1u << 20;
    const size_t SELB_OFF  = MAT_OFF;
    const size_t WS_NEED   = MAT_OFF + (size_t)BATCH * PRE_NMS * MROW * 8;     // ~37.9 MB

    if (d_ws != nullptr && ws_size >= WS_NEED) {
        char* ws = (char*)d_ws;
        float4* boxes_ws = (float4*)(ws + BOX_OFF);
        float*  area_ws  = (float*)(ws + AREA_OFF);
        ull*    alive_ws = (ull*)(ws + ALIVE_OFF);
        u32*    Tc       = (u32*)(ws + TC_OFF);
        u32*    done     = (u32*)(ws + DONE_OFF);
        u32*    cntp     = (u32*)(ws + CNT_OFF);
        u32*    ghist    = (u32*)(ws + GHIST_OFF);
        u32*    flags    = (u32*)(ws + FLAG_OFF);
        u32*    binbase  = (u32*)(ws + BINB_OFF);
        u32*    bincnt   = (u32*)(ws + BINC_OFF);
        ull*    nzmask   = (ull*)(ws + NZ_OFF);
        ull*    selbuf   = (ull*)(ws + SELB_OFF);
        ull*    mat      = (ull*)(ws + MAT_OFF);

        hipMemsetAsync(ws + ZERO_OFF, 0, MAT_OFF - ZERO_OFF, stream);  // alive..nzmask
        hipLaunchKernelGGL(hist_kernel, dim3(CBLK, BATCH), dim3(256), 0, stream,
                           rpn_probs, ghist, done, Tc, binbase, cntp);
        hipLaunchKernelGGL(compact_kernel, dim3(CBLK, BATCH), dim3(256), 0, stream,
                           rpn_probs, Tc, binbase, bincnt, selbuf);
        hipLaunchKernelGGL(rank_decode_kernel, dim3(SORTN / 256, BATCH), dim3(256), 0, stream,
                           rpn_bbox, anchors, selbuf, cntp, binbase, ghist,
                           boxes_ws, area_ws, alive_ws);
        // fast pass: words 0..CHUNK_W-1 of rows 0..CHUNK_W*64-1, then capped scan
        hipLaunchKernelGGL(iou_chunk_kernel, dim3(CHUNK_W, BATCH), dim3(1024), 0, stream,
                           boxes_ws, area_ws, mat, nzmask, (const u32*)nullptr, CHUNK_W);
        hipLaunchKernelGGL((nms_scan_t<true>), dim3(BATCH), dim3(64), 0, stream,
                           boxes_ws, alive_ws, mat, nzmask, out, flags);
        // guarded completion (expected no-op): rest of the matrix + full re-scan
        hipLaunchKernelGGL(iou_chunk_kernel, dim3(NW, BATCH), dim3(1024), 0, stream,
                           boxes_ws, area_ws, mat, nzmask, (const u32*)flags, NW);
        hipLaunchKernelGGL((nms_scan_t<false>), dim3(BATCH), dim3(64), 0, stream,
                           boxes_ws, alive_ws, mat, nzmask, out, flags);
    } else {
        hipLaunchKernelGGL(proposal_fallback, dim3(BATCH), dim3(1024), 0, stream,
                           rpn_probs, rpn_bbox, anchors, out);
    }
}

// Round 6
// 230.405 us; speedup vs baseline: 2.1226x; 1.1180x over previous
//
#include <hip/hip_runtime.h>
#include <cstdint>
#include <cstddef>

#pragma clang fp contract(off)

#define BATCH    8
#define NANCH    261888
#define PRE_NMS  6000
#define PROP     1000
#define SORTN    8192
#define NSLOT    6144          /* 6 * 1024 */
#define MROW     96            /* u64 words per suppression row (94 used + 2 pad) */
#define NW       94            /* suppression words per batch (6000/64 rounded up) */
#define CHUNK_W  32            /* words computed+scanned in the fast first pass */
#define NZCAP    128           /* LDS-stashed nonzero rows (capped scan) */
#define NPAIR    130944        /* NANCH / 2 */
#define CBLK     64            /* blocks per batch for hist/compact (R15: 32->64) */
#define CPAIR    2046          /* NPAIR / CBLK */
#define KCAP     1024          /* compact LDS staging capacity */
#define SCORE_THRES_BITS 0x3F000000u   /* bits of 0.5f */
#define EPS_F    1e-8f
/* midpoint between pred(0.7f) and 0.7f = 23488101 * 2^-25, exact in double.
   RN(inter/denom) >= 0.7f  <=>  inter > M_D * denom  (exact: 25b x 24b product;
   tie rounds to even = pred(0.7f), so strict > is correct). */
#define M_D      0.6999999582767486572265625

typedef unsigned long long ull;
typedef unsigned int u32;

// ---------------------------------------------------------------------------
// Kernel A (fused hist + findT + binbase): fine histogram of scores >= 0.5
// into 129 bins; the LAST block per batch (done-counter) computes the coarse
// threshold, the per-bin rank bases (suffix sums), and the total count C.
// grid (CBLK, BATCH) x 256.
// ---------------------------------------------------------------------------
__global__ __launch_bounds__(256)
void hist_kernel(const float* __restrict__ rpn_probs, u32* __restrict__ ghist,
                 u32* __restrict__ done, u32* __restrict__ Tc,
                 u32* __restrict__ binbase, u32* __restrict__ cntp)
{
    __shared__ u32 h[129];
    __shared__ u32 s_old;
    const int t = threadIdx.x;
    const int b = blockIdx.y;
    if (t < 129) h[t] = 0u;
    __syncthreads();

    const float4* p4 = reinterpret_cast<const float4*>(rpn_probs + (size_t)b * NANCH * 2);
    const int p0 = blockIdx.x * CPAIR;
    for (int i = t; i < CPAIR; i += 256) {
        float4 v = p4[p0 + i];                 // scores of anchors 2p, 2p+1 in .y/.w
        u32 k0 = __float_as_uint(v.y);
        u32 k1 = __float_as_uint(v.w);
        if (k0 >= 0x3F000000u) atomicAdd(&h[min((k0 >> 16) - 0x3F00u, 128u)], 1u);
        if (k1 >= 0x3F000000u) atomicAdd(&h[min((k1 >> 16) - 0x3F00u, 128u)], 1u);
    }
    __syncthreads();
    if (t < 129 && h[t]) atomicAdd(&ghist[(b << 8) + t], h[t]);

    __threadfence();
    if (t == 0) s_old = atomicAdd(&done[b], 1u);
    __syncthreads();
    if (s_old == CBLK - 1) {
        // last block for this batch: all flushes are globally visible
        if (t < 129) h[t] = atomicAdd(&ghist[(b << 8) + t], 0u);   // coherent read
        __syncthreads();
        if (t == 0) {
            u32* bb = binbase + b * 132;
            u32 run = 0; int binT = -1; u32 Cv = 0;
            for (int i = 128; i >= 0; --i) {
                bb[i] = run;                    // # keys in bins strictly above i
                run += h[i];
                if (binT < 0 && run >= PRE_NMS) { binT = i; Cv = run; }
            }
            u32 T;
            if (binT < 0)         { T = 0x3F000000u; Cv = run; }  // all >=0.5 (unreachable)
            else if (binT == 128)   T = 0x3F800000u;
            else                    T = 0x3F000000u + ((u32)binT << 16);
            Tc[b] = T;
            cntp[b << 6] = Cv;
        }
    }
}

// ---------------------------------------------------------------------------
// Kernel C (R15): bucketed compact with two-level atomic aggregation.
// R14's version did one contended GLOBAL atomicAdd per selected key (~52k,
// dependent-return) -> 47us latency-bound. Now:
//   phase 1: ballot-aggregated LDS staging of selected (key,n) pairs
//            (exact per-key global spill if >KCAP staged; never on this data)
//   phase 2: per-block bin histogram in LDS
//   phase 3: ONE global atomicAdd per (block, active bin) reserves the range
//   phase 4: scatter from LDS with block-local offsets
// Within-bin order is irrelevant (rank_decode orders by value) => exact.
// grid (CBLK, BATCH) x 256.
// ---------------------------------------------------------------------------
__global__ __launch_bounds__(256)
void compact_kernel(const float* __restrict__ rpn_probs,
                    const u32* __restrict__ Tc,
                    const u32* __restrict__ binbase,
                    u32* __restrict__ bincnt,
                    ull* __restrict__ selbuf)
{
    __shared__ ull kbuf[KCAP];
    __shared__ u32 s_n;
    __shared__ u32 s_hist[132];
    __shared__ u32 s_base[132];
    const int t    = threadIdx.x;
    const int lane = t & 63;
    const int b    = blockIdx.y;
    const u32 T = Tc[b];
    const u32* bb = binbase + b * 132;
    u32* bc = bincnt + b * 132;
    if (t == 0) s_n = 0u;
    if (t < 132) s_hist[t] = 0u;
    __syncthreads();

    const float4* p4 = reinterpret_cast<const float4*>(rpn_probs + (size_t)b * NANCH * 2);
    ull* sb = selbuf + (size_t)b * SORTN;
    const int p0 = blockIdx.x * CPAIR;

    // ---- phase 1: stage selected keys in LDS (one LDS atomic per wave-group)
    for (int i = t; i < CPAIR; i += 256) {
        float4 v = p4[p0 + i];
        const int n0 = (p0 + i) << 1;
        #pragma unroll
        for (int e = 0; e < 2; ++e) {
            u32 k = __float_as_uint(e ? v.w : v.y);
            bool s0 = (k >= T);
            ull m = __ballot(s0 ? 1 : 0);
            if (!m) continue;                                  // wave-uniform
            int ldr = __ffsll(m) - 1;
            u32 base = 0;
            if (lane == ldr) base = atomicAdd(&s_n, (u32)__popcll(m));
            base = __shfl(base, ldr);
            u32 off = base + (u32)__popcll(m & ((1ull << lane) - 1ull));
            if (s0) {
                ull pk = ((ull)(~k) << 32) | (ull)(u32)(n0 + e);
                if (off < KCAP) {
                    kbuf[off] = pk;
                } else {
                    // exact spill (unreachable at ~100 staged/block): per-key scatter
                    u32 bin = min((k >> 16) - 0x3F00u, 128u);
                    u32 pos = bb[bin] + atomicAdd(&bc[bin], 1u);
                    if (pos < SORTN) sb[pos] = pk;
                }
            }
        }
    }
    __syncthreads();
    const u32 nn = min(s_n, (u32)KCAP);

    // ---- phase 2: per-block bin histogram
    for (u32 j = t; j < nn; j += 256) {
        u32 k = ~(u32)(kbuf[j] >> 32);
        atomicAdd(&s_hist[min((k >> 16) - 0x3F00u, 128u)], 1u);
    }
    __syncthreads();

    // ---- phase 3: reserve this block's range in each active bin
    if (t < 132 && s_hist[t]) s_base[t] = atomicAdd(&bc[t], s_hist[t]);
    __syncthreads();
    if (t < 132) s_hist[t] = 0u;      // reuse as local position counters
    __syncthreads();

    // ---- phase 4: scatter
    for (u32 j = t; j < nn; j += 256) {
        ull kv = kbuf[j];
        u32 k = ~(u32)(kv >> 32);
        u32 bin = min((k >> 16) - 0x3F00u, 128u);
        u32 local = atomicAdd(&s_hist[bin], 1u);
        u32 pos = bb[bin] + s_base[bin] + local;
        if (pos < SORTN) sb[pos] = kv;
    }
}

// ---------------------------------------------------------------------------
// Kernel D (R13): bucketed rank + decode + scatter. rank = binbase[bin] +
// #{y in same bin : key_y < key_x}. grid (32, BATCH) x 256.
// ---------------------------------------------------------------------------
__global__ __launch_bounds__(256)
void rank_decode_kernel(const float* __restrict__ rpn_bbox,
                        const float* __restrict__ anchors,
                        const ull* __restrict__ selbuf,
                        const u32* __restrict__ cntp,
                        const u32* __restrict__ binbase,
                        const u32* __restrict__ ghist,
                        float4* __restrict__ boxes_ws,
                        float* __restrict__ area_ws,
                        ull* __restrict__ alive_ws)
{
    const int t = threadIdx.x;
    const int b = blockIdx.y;
    const u32 C = min(cntp[b << 6], (u32)SORTN);
    const ull* sb = selbuf + (size_t)b * SORTN;

    const int i = (blockIdx.x << 8) + t;
    if (i >= (int)C) return;

    const ull mykey = sb[i];
    const u32 key = ~(u32)(mykey >> 32);
    const u32 n   = (u32)(mykey & 0xFFFFFFFFull);
    const u32 bin = min((key >> 16) - 0x3F00u, 128u);
    const u32 lo  = binbase[b * 132 + bin];
    const u32 cb  = min(ghist[(b << 8) + bin], (u32)SORTN - lo);  // bin size (clamped)

    const ull* base = sb + lo;
    int local = 0;
    u32 j = 0;
    for (; j + 8 <= cb; j += 8) {
        #pragma unroll
        for (int u = 0; u < 8; ++u) local += (base[j + u] < mykey) ? 1 : 0;
    }
    for (; j < cb; ++j) local += (base[j] < mykey) ? 1 : 0;
    const int rank = (int)lo + local;

    if (rank < PRE_NMS) {
        const float4* bbox4 = reinterpret_cast<const float4*>(rpn_bbox + (size_t)b * NANCH * 4);
        const float4* anc4  = reinterpret_cast<const float4*>(anchors  + (size_t)b * NANCH * 4);
        float4 a = anc4[n];
        float4 d = bbox4[n];
        float dy = d.x * 0.1f, dx = d.y * 0.1f, dh = d.z * 0.2f, dw = d.w * 0.2f;
        float h  = a.z - a.x;
        float w  = a.w - a.y;
        float cy = a.x + 0.5f * h;
        float cx = a.y + 0.5f * w;
        cy = cy + dy * h;
        cx = cx + dx * w;
        h  = h * expf(dh);
        w  = w * expf(dw);
        float y1 = cy - 0.5f * h;
        float x1 = cx - 0.5f * w;
        float y2 = y1 + h;
        float x2 = x1 + w;
        y1 = fminf(fmaxf(y1, 0.f), 1.f);
        x1 = fminf(fmaxf(x1, 0.f), 1.f);
        y2 = fminf(fmaxf(y2, 0.f), 1.f);
        x2 = fminf(fmaxf(x2, 0.f), 1.f);
        boxes_ws[(size_t)b * NSLOT + rank] = make_float4(y1, x1, y2, x2);
        area_ws[(size_t)b * NSLOT + rank]  = (y2 - y1) * (x2 - x1);
        if (key >= SCORE_THRES_BITS) {
            atomicOr(&alive_ws[(size_t)b * MROW + (rank >> 6)], 1ull << (rank & 63));
        }
    }
}

// ---------------------------------------------------------------------------
// Kernel E (R12/R14): chunked suppression bit-matrix, 4 rows per wave, PLUS
// per-row nonzero summary (nzmask, 1 bit/row grouped as ull per word-block)
// published via one atomicOr per wave. The scan uses nzmask to touch only
// nonzero rows (~90 of 6000).
// ---------------------------------------------------------------------------
__global__ __launch_bounds__(1024)
void iou_chunk_kernel(const float4* __restrict__ boxes_ws,
                      const float* __restrict__ area_ws,
                      ull* __restrict__ mat,
                      ull* __restrict__ nzmask,
                      const u32* __restrict__ flags,
                      int kend)
{
    const int b = blockIdx.y;
    if (flags && flags[b]) return;        // fast-scan already finished this batch

    __shared__ float4 sbox[NSLOT];    // 96 KB
    __shared__ float  sarea[NSLOT];   // 24 KB

    const int j    = blockIdx.x;
    const int t    = threadIdx.x;
    const int lane = t & 63;
    const int wv   = t >> 6;

    const int kbeg = flags ? max(j, CHUNK_W) : j;
    const int base = j << 6;
    const int nst  = (kend << 6) - base;   // staged cols cover words kbeg..kend-1 (+rows)

    const float4* bws = boxes_ws + (size_t)b * NSLOT + base;
    const float*  aws = area_ws  + (size_t)b * NSLOT + base;
    for (int i = t; i < nst; i += 1024) { sbox[i] = bws[i]; sarea[i] = aws[i]; }
    __syncthreads();

    const int r0 = base + (wv << 2);       // first of this wave's 4 rows
    if (r0 >= PRE_NMS) return;             // only word-block 93's tail waves

    float4 P[4];
    float  PA[4];
    #pragma unroll
    for (int qi = 0; qi < 4; ++qi) { P[qi] = sbox[(wv << 2) + qi]; PA[qi] = sarea[(wv << 2) + qi]; }

    ull* rowp = mat + ((size_t)b * PRE_NMS + r0) * MROW;
    ull acc[4] = {0ull, 0ull, 0ull, 0ull};

    for (int k = kbeg; k < kend; ++k) {
        const int ci = ((k - j) << 6) + lane;
        const float4 qb = sbox[ci];
        const float  qa = sarea[ci];
        ull m[4];
        #pragma unroll
        for (int qi = 0; qi < 4; ++qi) {
            float yy1 = fmaxf(P[qi].x, qb.x);
            float xx1 = fmaxf(P[qi].y, qb.y);
            float yy2 = fminf(P[qi].z, qb.z);
            float xx2 = fminf(P[qi].w, qb.w);
            float inter = fmaxf(yy2 - yy1, 0.f) * fmaxf(xx2 - xx1, 0.f);
            float denom = ((PA[qi] + qa) - inter) + EPS_F;
            m[qi] = __ballot(((double)inter > M_D * (double)denom) ? 1 : 0);
        }
        if (k == j) {                       // diagonal word: mask away c <= r
            #pragma unroll
            for (int qi = 0; qi < 4; ++qi) {
                int sh = (wv << 2) + qi;
                ull keep = (sh == 63) ? 0ull : ((~0ull) << (sh + 1));
                m[qi] &= keep;
            }
        }
        #pragma unroll
        for (int qi = 0; qi < 4; ++qi) acc[qi] |= m[qi];
        if (lane == 0) {
            #pragma unroll
            for (int qi = 0; qi < 4; ++qi) rowp[(size_t)qi * MROW + k] = m[qi];
        }
    }

    if (lane == 0) {
        u32 bits = 0;
        #pragma unroll
        for (int qi = 0; qi < 4; ++qi) if (acc[qi]) bits |= 1u << qi;
        if (bits) atomicOr(&nzmask[(size_t)b * NW + j], (ull)bits << (wv << 2));
    }
}

// ---------------------------------------------------------------------------
// Kernel F (R14): word-walk greedy scan driven by nzmask — no bulk streaming.
//   FIRST=true : capped scan, words 0..CHUNK_W-1. Prologue stashes the ~90
//     nonzero rows (words 0..31 each, 256 B) into LDS via global_load_lds;
//     per word, if nzmask[k]==0 (common) the word resolves with zero memory
//     traffic (diag all-zero => P=wval). Overflow slots (>NZCAP) fall back to
//     exact on-demand global reads.
//   FIRST=false: guarded full re-scan, words 0..NW-1, no stash — diag and
//     OR-gather read nonzero rows on demand from global (exact; cold path).
// ---------------------------------------------------------------------------
__device__ __forceinline__ ull shfl_xor64(ull x, int s)
{
    return (ull)__shfl_xor((long long)x, s, 64);
}

__device__ __forceinline__ ull readlane64(ull x, int l)
{
    u32 lo = (u32)__builtin_amdgcn_readlane((int)(u32)x, l);
    u32 hi = (u32)__builtin_amdgcn_readlane((int)(u32)(x >> 32), l);
    return ((ull)hi << 32) | (ull)lo;
}

template<bool FIRST>
__global__ __launch_bounds__(64)
__attribute__((amdgpu_waves_per_eu(1, 1)))
void nms_scan_t(const float4* __restrict__ boxes_ws,
                const ull* __restrict__ alive_ws,
                const ull* __restrict__ mat,
                const ull* __restrict__ nzmask,
                float* __restrict__ out,
                u32* __restrict__ flags)
{
    const int b = blockIdx.x;
    if (!FIRST && flags[b]) return;        // fast pass already produced output

    const int lane = threadIdx.x;
    const int CW = FIRST ? CHUNK_W : NW;

    __shared__ int picks[PROP];                        // 4 KB
    __shared__ u32 nzrows[NZCAP];                      // 512 B
    __shared__ __align__(16) ull nzbuf[NZCAP * 32];    // 32 KB (capped only)

    // lane l (<48) holds alive words 2l, 2l+1 (words 94,95 zero by construction)
    ull aw0 = 0, aw1 = 0;
    if (lane < 48) {
        const ull* aw = alive_ws + (size_t)b * MROW + 2 * lane;
        aw0 = aw[0]; aw1 = aw[1];
    }

    const ull* mb  = mat    + (size_t)b * PRE_NMS * MROW;
    const ull* nzm = nzmask + (size_t)b * NW;

    // ---- load nz words; capped: lane k<32 holds word k; full: lane l<47 holds 2l,2l+1
    ull nzA = 0, nzB = 0;
    if (FIRST) { if (lane < CHUNK_W) nzA = nzm[lane]; }
    else       { if (lane < 47)      { nzA = nzm[2 * lane]; nzB = nzm[2 * lane + 1]; } }

    int excl = 0, NZ = 0;
    if (FIRST) {
        // exclusive prefix of per-word nz popcounts over lanes 0..31
        int c = (int)__popcll(nzA);
        int incl = c;
        for (int s = 1; s < 32; s <<= 1) {
            int y = __shfl_up(incl, s, 64);
            if (lane >= s) incl += y;
        }
        excl = incl - c;
        NZ = __builtin_amdgcn_readlane(incl, 31);

        // build compacted nonzero-row list (slots < NZCAP)
        {
            ull m = nzA; int r = excl;
            while (m) {
                int p = __ffsll(m) - 1; m &= m - 1ull;
                if (r < NZCAP) nzrows[r] = (u32)((lane << 6) + p);
                ++r;
            }
        }
        __syncthreads();

        // stash nonzero rows (words 0..31 = 256 B each) into LDS; 4 rows/load-instr
        const int NP = min(NZ, NZCAP);
        if (NP > 0) {
            u32 ridA = nzrows[lane];
            u32 ridB = nzrows[64 + lane];
            const int ninst = (NP + 3) >> 2;
            for (int i = 0; i < ninst; ++i) {
                int slot = 4 * i + (lane >> 4);
                if (slot >= NP) slot = NP - 1;
                int sel = (slot & 63) << 2;
                int ra = __builtin_amdgcn_ds_bpermute(sel, (int)ridA);
                int rb = __builtin_amdgcn_ds_bpermute(sel, (int)ridB);
                u32 rid = (u32)((slot < 64) ? ra : rb);
                const char* src = (const char*)(mb + (size_t)rid * MROW) + ((unsigned)(lane & 15) << 4);
                __builtin_amdgcn_global_load_lds(
                    (const __attribute__((address_space(1))) void*)src,
                    (__attribute__((address_space(3))) void*)((char*)&nzbuf[0] + i * 1024),
                    16, 0, 0);
            }
        }
        asm volatile("s_waitcnt vmcnt(0)" ::: "memory");
        __builtin_amdgcn_sched_barrier(0);
    }

    int cnt = 0;
    for (int k = 0; k < CW; ++k) {
        // nz word k (uniform)
        ull nzk;
        if (FIRST) nzk = readlane64(nzA, k);
        else       nzk = readlane64((k & 1) ? nzB : nzA, k >> 1);

        // alive word k (uniform)
        const int srcw = k >> 1;
        const ull awk = (k & 1) ? aw1 : aw0;
        ull wval = readlane64(awk, srcw);

        if (wval != 0ull) {
            const int slotbase_k = FIRST ? __builtin_amdgcn_readlane(excl, k) : 0;

            // per-lane diag word (zero rows => zero diag, no read)
            ull diag_cur = 0ull;
            if (nzk != 0ull) {
                bool mynz = (nzk >> lane) & 1ull;
                if (mynz) {
                    if (FIRST) {
                        int slot = slotbase_k + (int)__popcll(nzk & ((1ull << lane) - 1ull));
                        diag_cur = (slot < NZCAP) ? nzbuf[(size_t)slot * 32 + k]
                                                  : mb[(size_t)((k << 6) + lane) * MROW + k];
                    } else {
                        diag_cur = mb[(size_t)((k << 6) + lane) * MROW + k];
                    }
                }
            }

            // ---- lane-parallel pick resolution for word k
            const bool rowAlive = (wval >> lane) & 1ull;
            ull P;
            ull conflict = (nzk == 0ull) ? 0ull
                         : __ballot((rowAlive && ((diag_cur & wval) != 0ull)) ? 1 : 0);
            if (conflict == 0ull) {
                P = wval;
            } else {
                // transpose the 64x64 intra tile: T = "who suppresses me"
                ull T = diag_cur;
                {
                    ull y;
                    y = shfl_xor64(T, 32);
                    T = (lane & 32) ? ((T & 0xFFFFFFFF00000000ull) | ((y & 0xFFFFFFFF00000000ull) >> 32))
                                    : ((T & 0x00000000FFFFFFFFull) | ((y & 0x00000000FFFFFFFFull) << 32));
                    y = shfl_xor64(T, 16);
                    T = (lane & 16) ? ((T & 0xFFFF0000FFFF0000ull) | ((y & 0xFFFF0000FFFF0000ull) >> 16))
                                    : ((T & 0x0000FFFF0000FFFFull) | ((y & 0x0000FFFF0000FFFFull) << 16));
                    y = shfl_xor64(T, 8);
                    T = (lane & 8)  ? ((T & 0xFF00FF00FF00FF00ull) | ((y & 0xFF00FF00FF00FF00ull) >> 8))
                                    : ((T & 0x00FF00FF00FF00FFull) | ((y & 0x00FF00FF00FF00FFull) << 8));
                    y = shfl_xor64(T, 4);
                    T = (lane & 4)  ? ((T & 0xF0F0F0F0F0F0F0F0ull) | ((y & 0xF0F0F0F0F0F0F0F0ull) >> 4))
                                    : ((T & 0x0F0F0F0F0F0F0F0Full) | ((y & 0x0F0F0F0F0F0F0F0Full) << 4));
                    y = shfl_xor64(T, 2);
                    T = (lane & 2)  ? ((T & 0xCCCCCCCCCCCCCCCCull) | ((y & 0xCCCCCCCCCCCCCCCCull) >> 2))
                                    : ((T & 0x3333333333333333ull) | ((y & 0x3333333333333333ull) << 2));
                    y = shfl_xor64(T, 1);
                    T = (lane & 1)  ? ((T & 0xAAAAAAAAAAAAAAAAull) | ((y & 0xAAAAAAAAAAAAAAAAull) >> 1))
                                    : ((T & 0x5555555555555555ull) | ((y & 0x5555555555555555ull) << 1));
                }
                // iterative closure: accept all with no live suppressor,
                // kill their victims; repeat. Equals sequential greedy.
                ull A = wval;
                P = 0ull;
                while (A) {
                    const bool inA = (A >> lane) & 1ull;
                    ull D = __ballot((inA && ((T & A) == 0ull)) ? 1 : 0);
                    P |= D;
                    ull kill = __ballot((inA && ((T & D) != 0ull)) ? 1 : 0);
                    A &= ~(D | kill);
                }
            }

            // ---- ordered, PROP-capped parallel pick write
            const int total = __popcll(P);
            const int room  = PROP - cnt;
            const bool lanePicked = (P >> lane) & 1ull;
            const int myrank = __popcll(P & ((1ull << lane) - 1ull));
            if (lanePicked && myrank < room) picks[cnt + myrank] = (k << 6) + lane;
            cnt = (total >= room) ? PROP : (cnt + total);

            // ---- OR only NONZERO picked rows into alive regs
            if (cnt < PROP && nzk != 0ull) {
                ull orset = P & nzk;
                while (orset) {
                    int p = __ffsll(orset) - 1; orset &= orset - 1ull;
                    ulonglong2 v;
                    if (FIRST) {
                        int slot = slotbase_k + (int)__popcll(nzk & ((1ull << p) - 1ull));
                        if (slot < NZCAP) {
                            const ulonglong2* bv = reinterpret_cast<const ulonglong2*>(&nzbuf[(size_t)slot * 32]);
                            v = bv[lane & 15];      // words 0..31; lanes>=16 duplicate (aw unused)
                        } else {
                            const ulonglong2* gv = reinterpret_cast<const ulonglong2*>(mb + (size_t)((k << 6) + p) * MROW);
                            v = gv[lane & 15];
                        }
                    } else {
                        const ulonglong2* gv = reinterpret_cast<const ulonglong2*>(mb + (size_t)((k << 6) + p) * MROW);
                        v = gv[min(lane, 47)];
                    }
                    aw0 &= ~v.x; aw1 &= ~v.y;
                }
            }
        }

        // word k fully consumed
        if (lane == (k >> 1)) { if (k & 1) aw1 = 0ull; else aw0 = 0ull; }
        if (cnt == PROP) break;
    }

    __syncthreads();

    if (FIRST) {
        if (cnt != PROP) return;           // fallback passes will handle this batch
        if (lane == 0) flags[b] = 1u;
    }

    const float4* bws = boxes_ws + (size_t)b * NSLOT;
    float4* ob = reinterpret_cast<float4*>(out + (size_t)b * PROP * 4);
    for (int i = lane; i < PROP; i += 64) {
        float4 v = make_float4(0.f, 0.f, 0.f, 0.f);
        if (i < cnt) v = bws[picks[i]];
        ob[i] = v;
    }
}

// ---------------------------------------------------------------------------
// Fallback: round-1 monolithic kernel (used if ws too small). Verified exact.
// ---------------------------------------------------------------------------
__device__ __forceinline__ void hist_add_f(unsigned int* hist, unsigned int bin, bool valid) {
    const int lane = threadIdx.x & 63;
    ull todo = __ballot(valid ? 1 : 0);
    #pragma unroll
    for (int it = 0; it < 3; ++it) {
        if (!todo) return;
        int leader = __ffsll(todo) - 1;
        unsigned int lbin = __shfl(bin, leader);
        ull grp = __ballot((valid && (bin == lbin)) ? 1 : 0);
        if (lane == leader) atomicAdd(&hist[lbin], (unsigned int)__popcll(grp));
        todo &= ~grp;
    }
    if ((todo >> lane) & 1ull) atomicAdd(&hist[bin], 1u);
}

__global__ __launch_bounds__(1024)
void proposal_fallback(const float* __restrict__ rpn_probs,
                       const float* __restrict__ rpn_bbox,
                       const float* __restrict__ anchors,
                       float* __restrict__ out)
{
    const int b    = blockIdx.x;
    const int t    = threadIdx.x;
    const int lane = t & 63;
    const int wv   = t >> 6;

    const float2* __restrict__ probs2 = reinterpret_cast<const float2*>(rpn_probs + (size_t)b * NANCH * 2);
    const float4* __restrict__ bbox4  = reinterpret_cast<const float4*>(rpn_bbox  + (size_t)b * NANCH * 4);
    const float4* __restrict__ anc4   = reinterpret_cast<const float4*>(anchors   + (size_t)b * NANCH * 4);
    float* __restrict__ outb = out + (size_t)b * PROP * 4;

    __shared__ __align__(16) char s_big[NSLOT * 16];
    __shared__ ull          s_alive[96];
    __shared__ unsigned int s_hist[256];
    __shared__ unsigned int s_pref;
    __shared__ unsigned int s_targ;
    __shared__ unsigned int s_cnt;

    ull*    sel   = reinterpret_cast<ull*>(s_big);
    float4* boxes = reinterpret_cast<float4*>(s_big);

    const int ITER = (NANCH + 1023) >> 10;

    if (t == 0) { s_pref = 0u; s_targ = PRE_NMS; s_cnt = 0u; }

    for (int p = 0; p < 4; ++p) {
        if (t < 256) s_hist[t] = 0u;
        __syncthreads();
        const unsigned int pref  = s_pref;
        const int          shift = 8 * (3 - p);
        const unsigned int pmask = (p == 0) ? 0u : (0xFFFFFFFFu << (shift + 8));
        for (int i = 0; i < ITER; ++i) {
            int  n     = (i << 10) + t;
            bool valid = (n < NANCH);
            unsigned int key = 0u;
            if (valid) key = __float_as_uint(probs2[n].y);
            bool match = valid && ((key & pmask) == (pref & pmask));
            hist_add_f(s_hist, (key >> shift) & 0xFFu, match);
        }
        __syncthreads();
        if (t == 0) {
            unsigned int target = s_targ;
            unsigned int acc = 0u;
            int v = 255;
            for (; v >= 0; --v) {
                unsigned int h = s_hist[v];
                if (acc + h >= target) break;
                acc += h;
            }
            if (v < 0) v = 0;
            s_pref = pref | ((unsigned int)v << shift);
            s_targ = target - acc;
        }
        __syncthreads();
    }

    const unsigned int T = s_pref;
    __syncthreads();

    for (int i = 0; i < ITER; ++i) {
        int  n     = (i << 10) + t;
        bool valid = (n < NANCH);
        unsigned int key = 0u;
        if (valid) key = __float_as_uint(probs2[n].y);
        bool selp = valid && (key >= T);
        ull  m    = __ballot(selp ? 1 : 0);
        if (m) {
            int leader = __ffsll(m) - 1;
            unsigned int base = 0u;
            if (lane == leader) base = atomicAdd(&s_cnt, (unsigned int)__popcll(m));
            base = __shfl(base, leader);
            if (selp) {
                unsigned int off = base + (unsigned int)__popcll(m & ((1ull << lane) - 1ull));
                if (off < SORTN) sel[off] = ((ull)(~key) << 32) | (ull)(unsigned int)n;
            }
        }
    }
    __syncthreads();
    const unsigned int C = s_cnt;
    for (int s = (int)C + t; s < SORTN; s += 1024) sel[s] = ~0ull;
    __syncthreads();

    for (unsigned int k = 2; k <= SORTN; k <<= 1) {
        for (unsigned int j = k >> 1; j > 0; j >>= 1) {
            #pragma unroll
            for (int r = 0; r < SORTN / 1024; ++r) {
                int i = (r << 10) + t;
                int l = i ^ (int)j;
                if (l > i) {
                    ull a  = sel[i];
                    ull bq = sel[l];
                    bool up = ((i & (int)k) == 0);
                    if ((a > bq) == up) { sel[i] = bq; sel[l] = a; }
                }
            }
            __syncthreads();
        }
    }

    ull ss[6];
    #pragma unroll
    for (int e = 0; e < 6; ++e) ss[e] = sel[(e << 10) + t];
    __syncthreads();

    float4 rbox[6];
    float  rarea[6];
    #pragma unroll
    for (int e = 0; e < 6; ++e) {
        int s = (e << 10) + t;
        float4 bx = make_float4(0.f, 0.f, 0.f, 0.f);
        bool ok = false;
        if (s < PRE_NMS) {
            unsigned int key = ~(unsigned int)(ss[e] >> 32);
            unsigned int n   = (unsigned int)(ss[e] & 0xFFFFFFFFull);
            float4 a = anc4[n];
            float4 d = bbox4[n];
            float dy = d.x * 0.1f, dx = d.y * 0.1f, dh = d.z * 0.2f, dw = d.w * 0.2f;
            float h  = a.z - a.x;
            float w  = a.w - a.y;
            float cy = a.x + 0.5f * h;
            float cx = a.y + 0.5f * w;
            cy = cy + dy * h;
            cx = cx + dx * w;
            h  = h * expf(dh);
            w  = w * expf(dw);
            float y1 = cy - 0.5f * h;
            float x1 = cx - 0.5f * w;
            float y2 = y1 + h;
            float x2 = x1 + w;
            y1 = fminf(fmaxf(y1, 0.f), 1.f);
            x1 = fminf(fmaxf(x1, 0.f), 1.f);
            y2 = fminf(fmaxf(y2, 0.f), 1.f);
            x2 = fminf(fmaxf(x2, 0.f), 1.f);
            bx = make_float4(y1, x1, y2, x2);
            ok = (key >= SCORE_THRES_BITS);
        }
        rbox[e]  = bx;
        rarea[e] = (bx.z - bx.x) * (bx.w - bx.y);
        boxes[s] = bx;
        ull am = __ballot(ok ? 1 : 0);
        if (lane == 0) s_alive[wv + (e << 4)] = am;
    }

    int emitted = 0;
    for (;;) {
        __syncthreads();
        if (emitted == PROP) break;
        ull w0 = s_alive[lane];
        ull w1 = (lane < 32) ? s_alive[64 + lane] : 0ull;
        ull nz0 = __ballot(w0 != 0ull ? 1 : 0);
        ull nz1 = __ballot(w1 != 0ull ? 1 : 0);
        int pick = -1;
        if (nz0) {
            int wd = __ffsll(nz0) - 1;
            ull wvv = __shfl(w0, wd);
            pick = (wd << 6) + __ffsll(wvv) - 1;
        } else if (nz1) {
            int wd = __ffsll(nz1) - 1;
            ull wvv = __shfl(w1, wd);
            pick = ((wd + 64) << 6) + __ffsll(wvv) - 1;
        }
        if (pick < 0) break;
        __syncthreads();

        if (t < 4) outb[(emitted << 2) + t] = reinterpret_cast<const float*>(s_big)[(pick << 2) + t];

        float4 p = boxes[pick];
        float parea = (p.z - p.x) * (p.w - p.y);
        #pragma unroll
        for (int e = 0; e < 6; ++e) {
            float4 bb  = rbox[e];
            float yy1 = fmaxf(p.x, bb.x);
            float xx1 = fmaxf(p.y, bb.y);
            float yy2 = fminf(p.z, bb.z);
            float xx2 = fminf(p.w, bb.w);
            float ih  = fmaxf(yy2 - yy1, 0.f);
            float iw  = fmaxf(xx2 - xx1, 0.f);
            float inter = ih * iw;
            float denom = ((parea + rarea[e]) - inter) + EPS_F;
            bool  sup   = ((double)inter > M_D * (double)denom);
            ull m = __ballot(sup ? 1 : 0);
            int word = wv + (e << 4);
            if (word == (pick >> 6)) m |= (1ull << (pick & 63));
            if (lane == 0) s_alive[word] &= ~m;
        }
        ++emitted;
    }

    for (int i = (emitted << 2) + t; i < PROP * 4; i += 1024) outb[i] = 0.f;
}

extern "C" void kernel_launch(void* const* d_in, const int* in_sizes, int n_in,
                              void* d_out, int out_size, void* d_ws, size_t ws_size,
                              hipStream_t stream) {
    const float* rpn_probs = (const float*)d_in[0];
    const float* rpn_bbox  = (const float*)d_in[1];
    const float* anchors   = (const float*)d_in[2];
    float* out = (float*)d_out;

    // ws layout:
    //   [0)        boxes   8*6144*16 = 786432
    //   [786432)   areas   8*6144*4  = 196608   -> ends 983040
    //   [983040)   ZERO region (one memset to MAT_OFF):
    //       alive   8*96*8 = 6144   @983040
    //       Tc      32 B            @989184
    //       done    32 B            @989440
    //       cntp    8*64*4 = 2048   @989696
    //       ghist   8*256*4 = 8192  @991744   -> ends 999936
    //       flags   8*4 = 32 B      @999936
    //       binbase 8*132*4 = 4224  @1000448
    //       bincnt  8*132*4 = 4224  @1004672
    //       nzmask  8*94*8 = 6016   @1008896  -> ends 1014912
    //   [1MiB)     mat (selbuf aliased at its head, consumed before mat write)
    const size_t BOX_OFF   = 0;
    const size_t AREA_OFF  = 786432;
    const size_t ZERO_OFF  = 983040;
    const size_t ALIVE_OFF = 983040;
    const size_t TC_OFF    = 989184;
    const size_t DONE_OFF  = 989440;
    const size_t CNT_OFF   = 989696;
    const size_t GHIST_OFF = 991744;
    const size_t FLAG_OFF  = 999936;
    const size_t BINB_OFF  = 1000448;
    const size_t BINC_OFF  = 1004672;
    const size_t NZ_OFF    = 1008896;
    const size_t MAT_OFF   = 1u << 20;
    const size_t SELB_OFF  = MAT_OFF;
    const size_t WS_NEED   = MAT_OFF + (size_t)BATCH * PRE_NMS * MROW * 8;     // ~37.9 MB

    if (d_ws != nullptr && ws_size >= WS_NEED) {
        char* ws = (char*)d_ws;
        float4* boxes_ws = (float4*)(ws + BOX_OFF);
        float*  area_ws  = (float*)(ws + AREA_OFF);
        ull*    alive_ws = (ull*)(ws + ALIVE_OFF);
        u32*    Tc       = (u32*)(ws + TC_OFF);
        u32*    done     = (u32*)(ws + DONE_OFF);
        u32*    cntp     = (u32*)(ws + CNT_OFF);
        u32*    ghist    = (u32*)(ws + GHIST_OFF);
        u32*    flags    = (u32*)(ws + FLAG_OFF);
        u32*    binbase  = (u32*)(ws + BINB_OFF);
        u32*    bincnt   = (u32*)(ws + BINC_OFF);
        ull*    nzmask   = (ull*)(ws + NZ_OFF);
        ull*    selbuf   = (ull*)(ws + SELB_OFF);
        ull*    mat      = (ull*)(ws + MAT_OFF);

        hipMemsetAsync(ws + ZERO_OFF, 0, MAT_OFF - ZERO_OFF, stream);  // alive..nzmask
        hipLaunchKernelGGL(hist_kernel, dim3(CBLK, BATCH), dim3(256), 0, stream,
                           rpn_probs, ghist, done, Tc, binbase, cntp);
        hipLaunchKernelGGL(compact_kernel, dim3(CBLK, BATCH), dim3(256), 0, stream,
                           rpn_probs, Tc, binbase, bincnt, selbuf);
        hipLaunchKernelGGL(rank_decode_kernel, dim3(SORTN / 256, BATCH), dim3(256), 0, stream,
                           rpn_bbox, anchors, selbuf, cntp, binbase, ghist,
                           boxes_ws, area_ws, alive_ws);
        // fast pass: words 0..CHUNK_W-1 of rows 0..CHUNK_W*64-1, then capped scan
        hipLaunchKernelGGL(iou_chunk_kernel, dim3(CHUNK_W, BATCH), dim3(1024), 0, stream,
                           boxes_ws, area_ws, mat, nzmask, (const u32*)nullptr, CHUNK_W);
        hipLaunchKernelGGL((nms_scan_t<true>), dim3(BATCH), dim3(64), 0, stream,
                           boxes_ws, alive_ws, mat, nzmask, out, flags);
        // guarded completion (expected no-op): rest of the matrix + full re-scan
        hipLaunchKernelGGL(iou_chunk_kernel, dim3(NW, BATCH), dim3(1024), 0, stream,
                           boxes_ws, area_ws, mat, nzmask, (const u32*)flags, NW);
        hipLaunchKernelGGL((nms_scan_t<false>), dim3(BATCH), dim3(64), 0, stream,
                           boxes_ws, alive_ws, mat, nzmask, out, flags);
    } else {
        hipLaunchKernelGGL(proposal_fallback, dim3(BATCH), dim3(1024), 0, stream,
                           rpn_probs, rpn_bbox, anchors, out);
    }
}

// Round 7
// 202.404 us; speedup vs baseline: 2.4163x; 1.1383x over previous
//
#include <hip/hip_runtime.h>
#include <cstdint>
#include <cstddef>

#pragma clang fp contract(off)

#define BATCH    8
#define NANCH    261888
#define PRE_NMS  6000
#define PROP     1000
#define SORTN    8192
#define NSLOT    6144          /* 6 * 1024 */
#define MROW     96            /* u64 words per suppression row (94 used + 2 pad) */
#define NW       94            /* suppression words per batch (6000/64 rounded up) */
#define CHUNK_W  32            /* words computed+scanned in the fast first pass */
#define NZCAP    128           /* LDS-stashed nonzero rows (capped scan) */
#define NPAIR    130944        /* NANCH / 2 */
#define CBLK     64            /* blocks per batch for hist/compact */
#define CPAIR    2046          /* NPAIR / CBLK */
#define KCAP     1024          /* compact LDS staging capacity */
#define SCORE_THRES_BITS 0x3F000000u   /* bits of 0.5f */
#define EPS_F    1e-8f
/* midpoint between pred(0.7f) and 0.7f = 23488101 * 2^-25, exact in double.
   RN(inter/denom) >= 0.7f  <=>  inter > M_D * denom  (exact: 25b x 24b product;
   tie rounds to even = pred(0.7f), so strict > is correct). */
#define M_D      0.6999999582767486572265625

typedef unsigned long long ull;
typedef unsigned int u32;

// ---------------------------------------------------------------------------
// Kernel A (fused hist + findT + binbase): fine histogram of scores >= 0.5
// into 129 bins; the LAST block per batch (done-counter) computes the coarse
// threshold, the per-bin rank bases (suffix sums), and the total count C.
// R16: __threadfence() (agent fence => s_waitcnt + buffer_inv, an L2
// invalidate per block, 512 per launch) replaced by s_waitcnt vmcnt(0).
// All cross-block data here flows through ATOMICS (ghist adds, done++ ticket,
// final atomic reads), which are performed at the device-coherent point —
// only ISSUE ORDER must be enforced, not ordinary-store visibility.
// grid (CBLK, BATCH) x 256.
// ---------------------------------------------------------------------------
__global__ __launch_bounds__(256)
void hist_kernel(const float* __restrict__ rpn_probs, u32* __restrict__ ghist,
                 u32* __restrict__ done, u32* __restrict__ Tc,
                 u32* __restrict__ binbase, u32* __restrict__ cntp)
{
    __shared__ u32 h[129];
    __shared__ u32 s_old;
    const int t = threadIdx.x;
    const int b = blockIdx.y;
    if (t < 129) h[t] = 0u;
    __syncthreads();

    const float4* p4 = reinterpret_cast<const float4*>(rpn_probs + (size_t)b * NANCH * 2);
    const int p0 = blockIdx.x * CPAIR;
    for (int i = t; i < CPAIR; i += 256) {
        float4 v = p4[p0 + i];                 // scores of anchors 2p, 2p+1 in .y/.w
        u32 k0 = __float_as_uint(v.y);
        u32 k1 = __float_as_uint(v.w);
        if (k0 >= 0x3F000000u) atomicAdd(&h[min((k0 >> 16) - 0x3F00u, 128u)], 1u);
        if (k1 >= 0x3F000000u) atomicAdd(&h[min((k1 >> 16) - 0x3F00u, 128u)], 1u);
    }
    __syncthreads();
    if (t < 129 && h[t]) atomicAdd(&ghist[(b << 8) + t], h[t]);

    // order: this block's ghist atomics performed before the done++ ticket.
    // (atomics complete at the coherent point when vmcnt drains; no L2
    // writeback/invalidate needed, unlike __threadfence's buffer_inv.)
    asm volatile("s_waitcnt vmcnt(0)" ::: "memory");
    if (t == 0) s_old = atomicAdd(&done[b], 1u);
    __syncthreads();
    if (s_old == CBLK - 1) {
        // last block for this batch: all ghist atomics are globally performed
        if (t < 129) h[t] = atomicAdd(&ghist[(b << 8) + t], 0u);   // coherent read
        __syncthreads();
        if (t == 0) {
            u32* bb = binbase + b * 132;
            u32 run = 0; int binT = -1; u32 Cv = 0;
            for (int i = 128; i >= 0; --i) {
                bb[i] = run;                    // # keys in bins strictly above i
                run += h[i];
                if (binT < 0 && run >= PRE_NMS) { binT = i; Cv = run; }
            }
            u32 T;
            if (binT < 0)         { T = 0x3F000000u; Cv = run; }  // all >=0.5 (unreachable)
            else if (binT == 128)   T = 0x3F800000u;
            else                    T = 0x3F000000u + ((u32)binT << 16);
            Tc[b] = T;
            cntp[b << 6] = Cv;
        }
    }
}

// ---------------------------------------------------------------------------
// Kernel C (R15): bucketed compact with two-level atomic aggregation.
//   phase 1: ballot-aggregated LDS staging of selected (key,n) pairs
//            (exact per-key global spill if >KCAP staged; never on this data)
//   phase 2: per-block bin histogram in LDS
//   phase 3: ONE global atomicAdd per (block, active bin) reserves the range
//   phase 4: scatter from LDS with block-local offsets
// Within-bin order is irrelevant (rank_decode orders by value) => exact.
// grid (CBLK, BATCH) x 256.
// ---------------------------------------------------------------------------
__global__ __launch_bounds__(256)
void compact_kernel(const float* __restrict__ rpn_probs,
                    const u32* __restrict__ Tc,
                    const u32* __restrict__ binbase,
                    u32* __restrict__ bincnt,
                    ull* __restrict__ selbuf)
{
    __shared__ ull kbuf[KCAP];
    __shared__ u32 s_n;
    __shared__ u32 s_hist[132];
    __shared__ u32 s_base[132];
    const int t    = threadIdx.x;
    const int lane = t & 63;
    const int b    = blockIdx.y;
    const u32 T = Tc[b];
    const u32* bb = binbase + b * 132;
    u32* bc = bincnt + b * 132;
    if (t == 0) s_n = 0u;
    if (t < 132) s_hist[t] = 0u;
    __syncthreads();

    const float4* p4 = reinterpret_cast<const float4*>(rpn_probs + (size_t)b * NANCH * 2);
    ull* sb = selbuf + (size_t)b * SORTN;
    const int p0 = blockIdx.x * CPAIR;

    // ---- phase 1: stage selected keys in LDS (one LDS atomic per wave-group)
    for (int i = t; i < CPAIR; i += 256) {
        float4 v = p4[p0 + i];
        const int n0 = (p0 + i) << 1;
        #pragma unroll
        for (int e = 0; e < 2; ++e) {
            u32 k = __float_as_uint(e ? v.w : v.y);
            bool s0 = (k >= T);
            ull m = __ballot(s0 ? 1 : 0);
            if (!m) continue;                                  // wave-uniform
            int ldr = __ffsll(m) - 1;
            u32 base = 0;
            if (lane == ldr) base = atomicAdd(&s_n, (u32)__popcll(m));
            base = __shfl(base, ldr);
            u32 off = base + (u32)__popcll(m & ((1ull << lane) - 1ull));
            if (s0) {
                ull pk = ((ull)(~k) << 32) | (ull)(u32)(n0 + e);
                if (off < KCAP) {
                    kbuf[off] = pk;
                } else {
                    // exact spill (unreachable at ~100 staged/block): per-key scatter
                    u32 bin = min((k >> 16) - 0x3F00u, 128u);
                    u32 pos = bb[bin] + atomicAdd(&bc[bin], 1u);
                    if (pos < SORTN) sb[pos] = pk;
                }
            }
        }
    }
    __syncthreads();
    const u32 nn = min(s_n, (u32)KCAP);

    // ---- phase 2: per-block bin histogram
    for (u32 j = t; j < nn; j += 256) {
        u32 k = ~(u32)(kbuf[j] >> 32);
        atomicAdd(&s_hist[min((k >> 16) - 0x3F00u, 128u)], 1u);
    }
    __syncthreads();

    // ---- phase 3: reserve this block's range in each active bin
    if (t < 132 && s_hist[t]) s_base[t] = atomicAdd(&bc[t], s_hist[t]);
    __syncthreads();
    if (t < 132) s_hist[t] = 0u;      // reuse as local position counters
    __syncthreads();

    // ---- phase 4: scatter
    for (u32 j = t; j < nn; j += 256) {
        ull kv = kbuf[j];
        u32 k = ~(u32)(kv >> 32);
        u32 bin = min((k >> 16) - 0x3F00u, 128u);
        u32 local = atomicAdd(&s_hist[bin], 1u);
        u32 pos = bb[bin] + s_base[bin] + local;
        if (pos < SORTN) sb[pos] = kv;
    }
}

// ---------------------------------------------------------------------------
// Kernel D (R13): bucketed rank + decode + scatter. rank = binbase[bin] +
// #{y in same bin : key_y < key_x}. grid (32, BATCH) x 256.
// ---------------------------------------------------------------------------
__global__ __launch_bounds__(256)
void rank_decode_kernel(const float* __restrict__ rpn_bbox,
                        const float* __restrict__ anchors,
                        const ull* __restrict__ selbuf,
                        const u32* __restrict__ cntp,
                        const u32* __restrict__ binbase,
                        const u32* __restrict__ ghist,
                        float4* __restrict__ boxes_ws,
                        float* __restrict__ area_ws,
                        ull* __restrict__ alive_ws)
{
    const int t = threadIdx.x;
    const int b = blockIdx.y;
    const u32 C = min(cntp[b << 6], (u32)SORTN);
    const ull* sb = selbuf + (size_t)b * SORTN;

    const int i = (blockIdx.x << 8) + t;
    if (i >= (int)C) return;

    const ull mykey = sb[i];
    const u32 key = ~(u32)(mykey >> 32);
    const u32 n   = (u32)(mykey & 0xFFFFFFFFull);
    const u32 bin = min((key >> 16) - 0x3F00u, 128u);
    const u32 lo  = binbase[b * 132 + bin];
    const u32 cb  = min(ghist[(b << 8) + bin], (u32)SORTN - lo);  // bin size (clamped)

    const ull* base = sb + lo;
    int local = 0;
    u32 j = 0;
    for (; j + 8 <= cb; j += 8) {
        #pragma unroll
        for (int u = 0; u < 8; ++u) local += (base[j + u] < mykey) ? 1 : 0;
    }
    for (; j < cb; ++j) local += (base[j] < mykey) ? 1 : 0;
    const int rank = (int)lo + local;

    if (rank < PRE_NMS) {
        const float4* bbox4 = reinterpret_cast<const float4*>(rpn_bbox + (size_t)b * NANCH * 4);
        const float4* anc4  = reinterpret_cast<const float4*>(anchors  + (size_t)b * NANCH * 4);
        float4 a = anc4[n];
        float4 d = bbox4[n];
        float dy = d.x * 0.1f, dx = d.y * 0.1f, dh = d.z * 0.2f, dw = d.w * 0.2f;
        float h  = a.z - a.x;
        float w  = a.w - a.y;
        float cy = a.x + 0.5f * h;
        float cx = a.y + 0.5f * w;
        cy = cy + dy * h;
        cx = cx + dx * w;
        h  = h * expf(dh);
        w  = w * expf(dw);
        float y1 = cy - 0.5f * h;
        float x1 = cx - 0.5f * w;
        float y2 = y1 + h;
        float x2 = x1 + w;
        y1 = fminf(fmaxf(y1, 0.f), 1.f);
        x1 = fminf(fmaxf(x1, 0.f), 1.f);
        y2 = fminf(fmaxf(y2, 0.f), 1.f);
        x2 = fminf(fmaxf(x2, 0.f), 1.f);
        boxes_ws[(size_t)b * NSLOT + rank] = make_float4(y1, x1, y2, x2);
        area_ws[(size_t)b * NSLOT + rank]  = (y2 - y1) * (x2 - x1);
        if (key >= SCORE_THRES_BITS) {
            atomicOr(&alive_ws[(size_t)b * MROW + (rank >> 6)], 1ull << (rank & 63));
        }
    }
}

// ---------------------------------------------------------------------------
// Kernel E (R12/R14): chunked suppression bit-matrix, 4 rows per wave, PLUS
// per-row nonzero summary (nzmask, 1 bit/row grouped as ull per word-block)
// published via one atomicOr per wave. The scan uses nzmask to touch only
// nonzero rows (~90 of 6000).
// ---------------------------------------------------------------------------
__global__ __launch_bounds__(1024)
void iou_chunk_kernel(const float4* __restrict__ boxes_ws,
                      const float* __restrict__ area_ws,
                      ull* __restrict__ mat,
                      ull* __restrict__ nzmask,
                      const u32* __restrict__ flags,
                      int kend)
{
    const int b = blockIdx.y;
    if (flags && flags[b]) return;        // fast-scan already finished this batch

    __shared__ float4 sbox[NSLOT];    // 96 KB
    __shared__ float  sarea[NSLOT];   // 24 KB

    const int j    = blockIdx.x;
    const int t    = threadIdx.x;
    const int lane = t & 63;
    const int wv   = t >> 6;

    const int kbeg = flags ? max(j, CHUNK_W) : j;
    const int base = j << 6;
    const int nst  = (kend << 6) - base;   // staged cols cover words kbeg..kend-1 (+rows)

    const float4* bws = boxes_ws + (size_t)b * NSLOT + base;
    const float*  aws = area_ws  + (size_t)b * NSLOT + base;
    for (int i = t; i < nst; i += 1024) { sbox[i] = bws[i]; sarea[i] = aws[i]; }
    __syncthreads();

    const int r0 = base + (wv << 2);       // first of this wave's 4 rows
    if (r0 >= PRE_NMS) return;             // only word-block 93's tail waves

    float4 P[4];
    float  PA[4];
    #pragma unroll
    for (int qi = 0; qi < 4; ++qi) { P[qi] = sbox[(wv << 2) + qi]; PA[qi] = sarea[(wv << 2) + qi]; }

    ull* rowp = mat + ((size_t)b * PRE_NMS + r0) * MROW;
    ull acc[4] = {0ull, 0ull, 0ull, 0ull};

    for (int k = kbeg; k < kend; ++k) {
        const int ci = ((k - j) << 6) + lane;
        const float4 qb = sbox[ci];
        const float  qa = sarea[ci];
        ull m[4];
        #pragma unroll
        for (int qi = 0; qi < 4; ++qi) {
            float yy1 = fmaxf(P[qi].x, qb.x);
            float xx1 = fmaxf(P[qi].y, qb.y);
            float yy2 = fminf(P[qi].z, qb.z);
            float xx2 = fminf(P[qi].w, qb.w);
            float inter = fmaxf(yy2 - yy1, 0.f) * fmaxf(xx2 - xx1, 0.f);
            float denom = ((PA[qi] + qa) - inter) + EPS_F;
            m[qi] = __ballot(((double)inter > M_D * (double)denom) ? 1 : 0);
        }
        if (k == j) {                       // diagonal word: mask away c <= r
            #pragma unroll
            for (int qi = 0; qi < 4; ++qi) {
                int sh = (wv << 2) + qi;
                ull keep = (sh == 63) ? 0ull : ((~0ull) << (sh + 1));
                m[qi] &= keep;
            }
        }
        #pragma unroll
        for (int qi = 0; qi < 4; ++qi) acc[qi] |= m[qi];
        if (lane == 0) {
            #pragma unroll
            for (int qi = 0; qi < 4; ++qi) rowp[(size_t)qi * MROW + k] = m[qi];
        }
    }

    if (lane == 0) {
        u32 bits = 0;
        #pragma unroll
        for (int qi = 0; qi < 4; ++qi) if (acc[qi]) bits |= 1u << qi;
        if (bits) atomicOr(&nzmask[(size_t)b * NW + j], (ull)bits << (wv << 2));
    }
}

// ---------------------------------------------------------------------------
// Kernel F (R14): word-walk greedy scan driven by nzmask — no bulk streaming.
//   FIRST=true : capped scan, words 0..CHUNK_W-1. Prologue stashes the ~90
//     nonzero rows (words 0..31 each, 256 B) into LDS via global_load_lds;
//     per word, if nzmask[k]==0 (common) the word resolves with zero memory
//     traffic (diag all-zero => P=wval). Overflow slots (>NZCAP) fall back to
//     exact on-demand global reads.
//   FIRST=false: guarded full re-scan, words 0..NW-1, no stash — diag and
//     OR-gather read nonzero rows on demand from global (exact; cold path).
// ---------------------------------------------------------------------------
__device__ __forceinline__ ull shfl_xor64(ull x, int s)
{
    return (ull)__shfl_xor((long long)x, s, 64);
}

__device__ __forceinline__ ull readlane64(ull x, int l)
{
    u32 lo = (u32)__builtin_amdgcn_readlane((int)(u32)x, l);
    u32 hi = (u32)__builtin_amdgcn_readlane((int)(u32)(x >> 32), l);
    return ((ull)hi << 32) | (ull)lo;
}

template<bool FIRST>
__global__ __launch_bounds__(64)
__attribute__((amdgpu_waves_per_eu(1, 1)))
void nms_scan_t(const float4* __restrict__ boxes_ws,
                const ull* __restrict__ alive_ws,
                const ull* __restrict__ mat,
                const ull* __restrict__ nzmask,
                float* __restrict__ out,
                u32* __restrict__ flags)
{
    const int b = blockIdx.x;
    if (!FIRST && flags[b]) return;        // fast pass already produced output

    const int lane = threadIdx.x;
    const int CW = FIRST ? CHUNK_W : NW;

    __shared__ int picks[PROP];                        // 4 KB
    __shared__ u32 nzrows[NZCAP];                      // 512 B
    __shared__ __align__(16) ull nzbuf[NZCAP * 32];    // 32 KB (capped only)

    // lane l (<48) holds alive words 2l, 2l+1 (words 94,95 zero by construction)
    ull aw0 = 0, aw1 = 0;
    if (lane < 48) {
        const ull* aw = alive_ws + (size_t)b * MROW + 2 * lane;
        aw0 = aw[0]; aw1 = aw[1];
    }

    const ull* mb  = mat    + (size_t)b * PRE_NMS * MROW;
    const ull* nzm = nzmask + (size_t)b * NW;

    // ---- load nz words; capped: lane k<32 holds word k; full: lane l<47 holds 2l,2l+1
    ull nzA = 0, nzB = 0;
    if (FIRST) { if (lane < CHUNK_W) nzA = nzm[lane]; }
    else       { if (lane < 47)      { nzA = nzm[2 * lane]; nzB = nzm[2 * lane + 1]; } }

    int excl = 0, NZ = 0;
    if (FIRST) {
        // exclusive prefix of per-word nz popcounts over lanes 0..31
        int c = (int)__popcll(nzA);
        int incl = c;
        for (int s = 1; s < 32; s <<= 1) {
            int y = __shfl_up(incl, s, 64);
            if (lane >= s) incl += y;
        }
        excl = incl - c;
        NZ = __builtin_amdgcn_readlane(incl, 31);

        // build compacted nonzero-row list (slots < NZCAP)
        {
            ull m = nzA; int r = excl;
            while (m) {
                int p = __ffsll(m) - 1; m &= m - 1ull;
                if (r < NZCAP) nzrows[r] = (u32)((lane << 6) + p);
                ++r;
            }
        }
        __syncthreads();

        // stash nonzero rows (words 0..31 = 256 B each) into LDS; 4 rows/load-instr
        const int NP = min(NZ, NZCAP);
        if (NP > 0) {
            u32 ridA = nzrows[lane];
            u32 ridB = nzrows[64 + lane];
            const int ninst = (NP + 3) >> 2;
            for (int i = 0; i < ninst; ++i) {
                int slot = 4 * i + (lane >> 4);
                if (slot >= NP) slot = NP - 1;
                int sel = (slot & 63) << 2;
                int ra = __builtin_amdgcn_ds_bpermute(sel, (int)ridA);
                int rb = __builtin_amdgcn_ds_bpermute(sel, (int)ridB);
                u32 rid = (u32)((slot < 64) ? ra : rb);
                const char* src = (const char*)(mb + (size_t)rid * MROW) + ((unsigned)(lane & 15) << 4);
                __builtin_amdgcn_global_load_lds(
                    (const __attribute__((address_space(1))) void*)src,
                    (__attribute__((address_space(3))) void*)((char*)&nzbuf[0] + i * 1024),
                    16, 0, 0);
            }
        }
        asm volatile("s_waitcnt vmcnt(0)" ::: "memory");
        __builtin_amdgcn_sched_barrier(0);
    }

    int cnt = 0;
    for (int k = 0; k < CW; ++k) {
        // nz word k (uniform)
        ull nzk;
        if (FIRST) nzk = readlane64(nzA, k);
        else       nzk = readlane64((k & 1) ? nzB : nzA, k >> 1);

        // alive word k (uniform)
        const int srcw = k >> 1;
        const ull awk = (k & 1) ? aw1 : aw0;
        ull wval = readlane64(awk, srcw);

        if (wval != 0ull) {
            const int slotbase_k = FIRST ? __builtin_amdgcn_readlane(excl, k) : 0;

            // per-lane diag word (zero rows => zero diag, no read)
            ull diag_cur = 0ull;
            if (nzk != 0ull) {
                bool mynz = (nzk >> lane) & 1ull;
                if (mynz) {
                    if (FIRST) {
                        int slot = slotbase_k + (int)__popcll(nzk & ((1ull << lane) - 1ull));
                        diag_cur = (slot < NZCAP) ? nzbuf[(size_t)slot * 32 + k]
                                                  : mb[(size_t)((k << 6) + lane) * MROW + k];
                    } else {
                        diag_cur = mb[(size_t)((k << 6) + lane) * MROW + k];
                    }
                }
            }

            // ---- lane-parallel pick resolution for word k
            const bool rowAlive = (wval >> lane) & 1ull;
            ull P;
            ull conflict = (nzk == 0ull) ? 0ull
                         : __ballot((rowAlive && ((diag_cur & wval) != 0ull)) ? 1 : 0);
            if (conflict == 0ull) {
                P = wval;
            } else {
                // transpose the 64x64 intra tile: T = "who suppresses me"
                ull T = diag_cur;
                {
                    ull y;
                    y = shfl_xor64(T, 32);
                    T = (lane & 32) ? ((T & 0xFFFFFFFF00000000ull) | ((y & 0xFFFFFFFF00000000ull) >> 32))
                                    : ((T & 0x00000000FFFFFFFFull) | ((y & 0x00000000FFFFFFFFull) << 32));
                    y = shfl_xor64(T, 16);
                    T = (lane & 16) ? ((T & 0xFFFF0000FFFF0000ull) | ((y & 0xFFFF0000FFFF0000ull) >> 16))
                                    : ((T & 0x0000FFFF0000FFFFull) | ((y & 0x0000FFFF0000FFFFull) << 16));
                    y = shfl_xor64(T, 8);
                    T = (lane & 8)  ? ((T & 0xFF00FF00FF00FF00ull) | ((y & 0xFF00FF00FF00FF00ull) >> 8))
                                    : ((T & 0x00FF00FF00FF00FFull) | ((y & 0x00FF00FF00FF00FFull) << 8));
                    y = shfl_xor64(T, 4);
                    T = (lane & 4)  ? ((T & 0xF0F0F0F0F0F0F0F0ull) | ((y & 0xF0F0F0F0F0F0F0F0ull) >> 4))
                                    : ((T & 0x0F0F0F0F0F0F0F0Full) | ((y & 0x0F0F0F0F0F0F0F0Full) << 4));
                    y = shfl_xor64(T, 2);
                    T = (lane & 2)  ? ((T & 0xCCCCCCCCCCCCCCCCull) | ((y & 0xCCCCCCCCCCCCCCCCull) >> 2))
                                    : ((T & 0x3333333333333333ull) | ((y & 0x3333333333333333ull) << 2));
                    y = shfl_xor64(T, 1);
                    T = (lane & 1)  ? ((T & 0xAAAAAAAAAAAAAAAAull) | ((y & 0xAAAAAAAAAAAAAAAAull) >> 1))
                                    : ((T & 0x5555555555555555ull) | ((y & 0x5555555555555555ull) << 1));
                }
                // iterative closure: accept all with no live suppressor,
                // kill their victims; repeat. Equals sequential greedy.
                ull A = wval;
                P = 0ull;
                while (A) {
                    const bool inA = (A >> lane) & 1ull;
                    ull D = __ballot((inA && ((T & A) == 0ull)) ? 1 : 0);
                    P |= D;
                    ull kill = __ballot((inA && ((T & D) != 0ull)) ? 1 : 0);
                    A &= ~(D | kill);
                }
            }

            // ---- ordered, PROP-capped parallel pick write
            const int total = __popcll(P);
            const int room  = PROP - cnt;
            const bool lanePicked = (P >> lane) & 1ull;
            const int myrank = __popcll(P & ((1ull << lane) - 1ull));
            if (lanePicked && myrank < room) picks[cnt + myrank] = (k << 6) + lane;
            cnt = (total >= room) ? PROP : (cnt + total);

            // ---- OR only NONZERO picked rows into alive regs
            if (cnt < PROP && nzk != 0ull) {
                ull orset = P & nzk;
                while (orset) {
                    int p = __ffsll(orset) - 1; orset &= orset - 1ull;
                    ulonglong2 v;
                    if (FIRST) {
                        int slot = slotbase_k + (int)__popcll(nzk & ((1ull << p) - 1ull));
                        if (slot < NZCAP) {
                            const ulonglong2* bv = reinterpret_cast<const ulonglong2*>(&nzbuf[(size_t)slot * 32]);
                            v = bv[lane & 15];      // words 0..31; lanes>=16 duplicate (aw unused)
                        } else {
                            const ulonglong2* gv = reinterpret_cast<const ulonglong2*>(mb + (size_t)((k << 6) + p) * MROW);
                            v = gv[lane & 15];
                        }
                    } else {
                        const ulonglong2* gv = reinterpret_cast<const ulonglong2*>(mb + (size_t)((k << 6) + p) * MROW);
                        v = gv[min(lane, 47)];
                    }
                    aw0 &= ~v.x; aw1 &= ~v.y;
                }
            }
        }

        // word k fully consumed
        if (lane == (k >> 1)) { if (k & 1) aw1 = 0ull; else aw0 = 0ull; }
        if (cnt == PROP) break;
    }

    __syncthreads();

    if (FIRST) {
        if (cnt != PROP) return;           // fallback passes will handle this batch
        if (lane == 0) flags[b] = 1u;
    }

    const float4* bws = boxes_ws + (size_t)b * NSLOT;
    float4* ob = reinterpret_cast<float4*>(out + (size_t)b * PROP * 4);
    for (int i = lane; i < PROP; i += 64) {
        float4 v = make_float4(0.f, 0.f, 0.f, 0.f);
        if (i < cnt) v = bws[picks[i]];
        ob[i] = v;
    }
}

// ---------------------------------------------------------------------------
// Fallback: round-1 monolithic kernel (used if ws too small). Verified exact.
// ---------------------------------------------------------------------------
__device__ __forceinline__ void hist_add_f(unsigned int* hist, unsigned int bin, bool valid) {
    const int lane = threadIdx.x & 63;
    ull todo = __ballot(valid ? 1 : 0);
    #pragma unroll
    for (int it = 0; it < 3; ++it) {
        if (!todo) return;
        int leader = __ffsll(todo) - 1;
        unsigned int lbin = __shfl(bin, leader);
        ull grp = __ballot((valid && (bin == lbin)) ? 1 : 0);
        if (lane == leader) atomicAdd(&hist[lbin], (unsigned int)__popcll(grp));
        todo &= ~grp;
    }
    if ((todo >> lane) & 1ull) atomicAdd(&hist[bin], 1u);
}

__global__ __launch_bounds__(1024)
void proposal_fallback(const float* __restrict__ rpn_probs,
                       const float* __restrict__ rpn_bbox,
                       const float* __restrict__ anchors,
                       float* __restrict__ out)
{
    const int b    = blockIdx.x;
    const int t    = threadIdx.x;
    const int lane = t & 63;
    const int wv   = t >> 6;

    const float2* __restrict__ probs2 = reinterpret_cast<const float2*>(rpn_probs + (size_t)b * NANCH * 2);
    const float4* __restrict__ bbox4  = reinterpret_cast<const float4*>(rpn_bbox  + (size_t)b * NANCH * 4);
    const float4* __restrict__ anc4   = reinterpret_cast<const float4*>(anchors   + (size_t)b * NANCH * 4);
    float* __restrict__ outb = out + (size_t)b * PROP * 4;

    __shared__ __align__(16) char s_big[NSLOT * 16];
    __shared__ ull          s_alive[96];
    __shared__ unsigned int s_hist[256];
    __shared__ unsigned int s_pref;
    __shared__ unsigned int s_targ;
    __shared__ unsigned int s_cnt;

    ull*    sel   = reinterpret_cast<ull*>(s_big);
    float4* boxes = reinterpret_cast<float4*>(s_big);

    const int ITER = (NANCH + 1023) >> 10;

    if (t == 0) { s_pref = 0u; s_targ = PRE_NMS; s_cnt = 0u; }

    for (int p = 0; p < 4; ++p) {
        if (t < 256) s_hist[t] = 0u;
        __syncthreads();
        const unsigned int pref  = s_pref;
        const int          shift = 8 * (3 - p);
        const unsigned int pmask = (p == 0) ? 0u : (0xFFFFFFFFu << (shift + 8));
        for (int i = 0; i < ITER; ++i) {
            int  n     = (i << 10) + t;
            bool valid = (n < NANCH);
            unsigned int key = 0u;
            if (valid) key = __float_as_uint(probs2[n].y);
            bool match = valid && ((key & pmask) == (pref & pmask));
            hist_add_f(s_hist, (key >> shift) & 0xFFu, match);
        }
        __syncthreads();
        if (t == 0) {
            unsigned int target = s_targ;
            unsigned int acc = 0u;
            int v = 255;
            for (; v >= 0; --v) {
                unsigned int h = s_hist[v];
                if (acc + h >= target) break;
                acc += h;
            }
            if (v < 0) v = 0;
            s_pref = pref | ((unsigned int)v << shift);
            s_targ = target - acc;
        }
        __syncthreads();
    }

    const unsigned int T = s_pref;
    __syncthreads();

    for (int i = 0; i < ITER; ++i) {
        int  n     = (i << 10) + t;
        bool valid = (n < NANCH);
        unsigned int key = 0u;
        if (valid) key = __float_as_uint(probs2[n].y);
        bool selp = valid && (key >= T);
        ull  m    = __ballot(selp ? 1 : 0);
        if (m) {
            int leader = __ffsll(m) - 1;
            unsigned int base = 0u;
            if (lane == leader) base = atomicAdd(&s_cnt, (unsigned int)__popcll(m));
            base = __shfl(base, leader);
            if (selp) {
                unsigned int off = base + (unsigned int)__popcll(m & ((1ull << lane) - 1ull));
                if (off < SORTN) sel[off] = ((ull)(~key) << 32) | (ull)(unsigned int)n;
            }
        }
    }
    __syncthreads();
    const unsigned int C = s_cnt;
    for (int s = (int)C + t; s < SORTN; s += 1024) sel[s] = ~0ull;
    __syncthreads();

    for (unsigned int k = 2; k <= SORTN; k <<= 1) {
        for (unsigned int j = k >> 1; j > 0; j >>= 1) {
            #pragma unroll
            for (int r = 0; r < SORTN / 1024; ++r) {
                int i = (r << 10) + t;
                int l = i ^ (int)j;
                if (l > i) {
                    ull a  = sel[i];
                    ull bq = sel[l];
                    bool up = ((i & (int)k) == 0);
                    if ((a > bq) == up) { sel[i] = bq; sel[l] = a; }
                }
            }
            __syncthreads();
        }
    }

    ull ss[6];
    #pragma unroll
    for (int e = 0; e < 6; ++e) ss[e] = sel[(e << 10) + t];
    __syncthreads();

    float4 rbox[6];
    float  rarea[6];
    #pragma unroll
    for (int e = 0; e < 6; ++e) {
        int s = (e << 10) + t;
        float4 bx = make_float4(0.f, 0.f, 0.f, 0.f);
        bool ok = false;
        if (s < PRE_NMS) {
            unsigned int key = ~(unsigned int)(ss[e] >> 32);
            unsigned int n   = (unsigned int)(ss[e] & 0xFFFFFFFFull);
            float4 a = anc4[n];
            float4 d = bbox4[n];
            float dy = d.x * 0.1f, dx = d.y * 0.1f, dh = d.z * 0.2f, dw = d.w * 0.2f;
            float h  = a.z - a.x;
            float w  = a.w - a.y;
            float cy = a.x + 0.5f * h;
            float cx = a.y + 0.5f * w;
            cy = cy + dy * h;
            cx = cx + dx * w;
            h  = h * expf(dh);
            w  = w * expf(dw);
            float y1 = cy - 0.5f * h;
            float x1 = cx - 0.5f * w;
            float y2 = y1 + h;
            float x2 = x1 + w;
            y1 = fminf(fmaxf(y1, 0.f), 1.f);
            x1 = fminf(fmaxf(x1, 0.f), 1.f);
            y2 = fminf(fmaxf(y2, 0.f), 1.f);
            x2 = fminf(fmaxf(x2, 0.f), 1.f);
            bx = make_float4(y1, x1, y2, x2);
            ok = (key >= SCORE_THRES_BITS);
        }
        rbox[e]  = bx;
        rarea[e] = (bx.z - bx.x) * (bx.w - bx.y);
        boxes[s] = bx;
        ull am = __ballot(ok ? 1 : 0);
        if (lane == 0) s_alive[wv + (e << 4)] = am;
    }

    int emitted = 0;
    for (;;) {
        __syncthreads();
        if (emitted == PROP) break;
        ull w0 = s_alive[lane];
        ull w1 = (lane < 32) ? s_alive[64 + lane] : 0ull;
        ull nz0 = __ballot(w0 != 0ull ? 1 : 0);
        ull nz1 = __ballot(w1 != 0ull ? 1 : 0);
        int pick = -1;
        if (nz0) {
            int wd = __ffsll(nz0) - 1;
            ull wvv = __shfl(w0, wd);
            pick = (wd << 6) + __ffsll(wvv) - 1;
        } else if (nz1) {
            int wd = __ffsll(nz1) - 1;
            ull wvv = __shfl(w1, wd);
            pick = ((wd + 64) << 6) + __ffsll(wvv) - 1;
        }
        if (pick < 0) break;
        __syncthreads();

        if (t < 4) outb[(emitted << 2) + t] = reinterpret_cast<const float*>(s_big)[(pick << 2) + t];

        float4 p = boxes[pick];
        float parea = (p.z - p.x) * (p.w - p.y);
        #pragma unroll
        for (int e = 0; e < 6; ++e) {
            float4 bb  = rbox[e];
            float yy1 = fmaxf(p.x, bb.x);
            float xx1 = fmaxf(p.y, bb.y);
            float yy2 = fminf(p.z, bb.z);
            float xx2 = fminf(p.w, bb.w);
            float ih  = fmaxf(yy2 - yy1, 0.f);
            float iw  = fmaxf(xx2 - xx1, 0.f);
            float inter = ih * iw;
            float denom = ((parea + rarea[e]) - inter) + EPS_F;
            bool  sup   = ((double)inter > M_D * (double)denom);
            ull m = __ballot(sup ? 1 : 0);
            int word = wv + (e << 4);
            if (word == (pick >> 6)) m |= (1ull << (pick & 63));
            if (lane == 0) s_alive[word] &= ~m;
        }
        ++emitted;
    }

    for (int i = (emitted << 2) + t; i < PROP * 4; i += 1024) outb[i] = 0.f;
}

extern "C" void kernel_launch(void* const* d_in, const int* in_sizes, int n_in,
                              void* d_out, int out_size, void* d_ws, size_t ws_size,
                              hipStream_t stream) {
    const float* rpn_probs = (const float*)d_in[0];
    const float* rpn_bbox  = (const float*)d_in[1];
    const float* anchors   = (const float*)d_in[2];
    float* out = (float*)d_out;

    // ws layout:
    //   [0)        boxes   8*6144*16 = 786432
    //   [786432)   areas   8*6144*4  = 196608   -> ends 983040
    //   [983040)   ZERO region (one memset to MAT_OFF):
    //       alive   8*96*8 = 6144   @983040
    //       Tc      32 B            @989184
    //       done    32 B            @989440
    //       cntp    8*64*4 = 2048   @989696
    //       ghist   8*256*4 = 8192  @991744   -> ends 999936
    //       flags   8*4 = 32 B      @999936
    //       binbase 8*132*4 = 4224  @1000448
    //       bincnt  8*132*4 = 4224  @1004672
    //       nzmask  8*94*8 = 6016   @1008896  -> ends 1014912
    //   [1MiB)     mat (selbuf aliased at its head, consumed before mat write)
    const size_t BOX_OFF   = 0;
    const size_t AREA_OFF  = 786432;
    const size_t ZERO_OFF  = 983040;
    const size_t ALIVE_OFF = 983040;
    const size_t TC_OFF    = 989184;
    const size_t DONE_OFF  = 989440;
    const size_t CNT_OFF   = 989696;
    const size_t GHIST_OFF = 991744;
    const size_t FLAG_OFF  = 999936;
    const size_t BINB_OFF  = 1000448;
    const size_t BINC_OFF  = 1004672;
    const size_t NZ_OFF    = 1008896;
    const size_t MAT_OFF   = 1u << 20;
    const size_t SELB_OFF  = MAT_OFF;
    const size_t WS_NEED   = MAT_OFF + (size_t)BATCH * PRE_NMS * MROW * 8;     // ~37.9 MB

    if (d_ws != nullptr && ws_size >= WS_NEED) {
        char* ws = (char*)d_ws;
        float4* boxes_ws = (float4*)(ws + BOX_OFF);
        float*  area_ws  = (float*)(ws + AREA_OFF);
        ull*    alive_ws = (ull*)(ws + ALIVE_OFF);
        u32*    Tc       = (u32*)(ws + TC_OFF);
        u32*    done     = (u32*)(ws + DONE_OFF);
        u32*    cntp     = (u32*)(ws + CNT_OFF);
        u32*    ghist    = (u32*)(ws + GHIST_OFF);
        u32*    flags    = (u32*)(ws + FLAG_OFF);
        u32*    binbase  = (u32*)(ws + BINB_OFF);
        u32*    bincnt   = (u32*)(ws + BINC_OFF);
        ull*    nzmask   = (ull*)(ws + NZ_OFF);
        ull*    selbuf   = (ull*)(ws + SELB_OFF);
        ull*    mat      = (ull*)(ws + MAT_OFF);

        hipMemsetAsync(ws + ZERO_OFF, 0, MAT_OFF - ZERO_OFF, stream);  // alive..nzmask
        hipLaunchKernelGGL(hist_kernel, dim3(CBLK, BATCH), dim3(256), 0, stream,
                           rpn_probs, ghist, done, Tc, binbase, cntp);
        hipLaunchKernelGGL(compact_kernel, dim3(CBLK, BATCH), dim3(256), 0, stream,
                           rpn_probs, Tc, binbase, bincnt, selbuf);
        hipLaunchKernelGGL(rank_decode_kernel, dim3(SORTN / 256, BATCH), dim3(256), 0, stream,
                           rpn_bbox, anchors, selbuf, cntp, binbase, ghist,
                           boxes_ws, area_ws, alive_ws);
        // fast pass: words 0..CHUNK_W-1 of rows 0..CHUNK_W*64-1, then capped scan
        hipLaunchKernelGGL(iou_chunk_kernel, dim3(CHUNK_W, BATCH), dim3(1024), 0, stream,
                           boxes_ws, area_ws, mat, nzmask, (const u32*)nullptr, CHUNK_W);
        hipLaunchKernelGGL((nms_scan_t<true>), dim3(BATCH), dim3(64), 0, stream,
                           boxes_ws, alive_ws, mat, nzmask, out, flags);
        // guarded completion (expected no-op): rest of the matrix + full re-scan
        hipLaunchKernelGGL(iou_chunk_kernel, dim3(NW, BATCH), dim3(1024), 0, stream,
                           boxes_ws, area_ws, mat, nzmask, (const u32*)flags, NW);
        hipLaunchKernelGGL((nms_scan_t<false>), dim3(BATCH), dim3(64), 0, stream,
                           boxes_ws, alive_ws, mat, nzmask, out, flags);
    } else {
        hipLaunchKernelGGL(proposal_fallback, dim3(BATCH), dim3(1024), 0, stream,
                           rpn_probs, rpn_bbox, anchors, out);
    }
}